// Round 2
// baseline (7056.948 us; speedup 1.0000x reference)
//
#include <hip/hip_runtime.h>
#include <hip/hip_bf16.h>

// ---------------- problem constants ----------------
#define LTOK  32768   // D*H*W
#define CDIM  192
#define DD_   8
#define HH_   64
#define WW_   64
#define NHEAD 6
#define HDIM  32
#define NWIN  64      // (D/8)*(H/8)*(W/8)
#define NTOKW 512     // tokens per window
#define C3    64      // C/3
#define FCH   768     // 4*C

// ws layout (float offsets)
#define OFF_XN     0u
#define OFF_Q      6291456u
#define OFF_K      12582912u
#define OFF_V      18874368u
#define OFF_H1     25165824u
#define OFF_H2     27262976u
#define OFF_PART   33554432u
#define OFF_AMASK  33603584u
#define OFF_W1T    33603776u
#define OFF_W2T    33935552u
#define OFF_QKVT   34267328u
#define OFF_PROJT  34377920u
#define OFF_FC1T   34414784u
#define OFF_FC2T   34562240u
// total 34709696 floats = 138.8 MB

__device__ __forceinline__ float gelu_exact(float x) {
    return 0.5f * x * (1.0f + erff(x * 0.70710678118654752f));
}

// ---------------- LayerNorm: 1 wave per token (C=192 = 64*3) ----------------
__global__ __launch_bounds__(256) void k_ln(const float* __restrict__ in,
                                            const float* __restrict__ g,
                                            const float* __restrict__ b,
                                            float* __restrict__ out) {
    int wv = threadIdx.x >> 6, lane = threadIdx.x & 63;
    int t = blockIdx.x * 4 + wv;
    const float* row = in + (size_t)t * CDIM;
    float x0 = row[lane], x1 = row[lane + 64], x2 = row[lane + 128];
    float s = x0 + x1 + x2;
    for (int o = 32; o; o >>= 1) s += __shfl_xor(s, o);
    float m = s * (1.0f / 192.0f);
    float d0 = x0 - m, d1 = x1 - m, d2 = x2 - m;
    float vv = d0 * d0 + d1 * d1 + d2 * d2;
    for (int o = 32; o; o >>= 1) vv += __shfl_xor(vv, o);
    float inv = rsqrtf(vv * (1.0f / 192.0f) + 1e-5f);
    size_t base = (size_t)t * CDIM;
    out[base + lane]       = d0 * inv * g[lane]       + b[lane];
    out[base + lane + 64]  = d1 * inv * g[lane + 64]  + b[lane + 64];
    out[base + lane + 128] = d2 * inv * g[lane + 128] + b[lane + 128];
}

// ---------------- conv weight transpose: w[oc][ic][27] -> wt[(c*27+kk)*OC+oc] ----------------
__global__ void k_wtrans(const float* __restrict__ w, float* __restrict__ wt,
                         int OC, int IC) {
    int i = blockIdx.x * 256 + threadIdx.x;
    int total = OC * IC * 27;
    if (i >= total) return;
    int oc = i % OC; int rest = i / OC; int kk = rest % 27; int c = rest / 27;
    wt[i] = w[((size_t)oc * IC + c) * 27 + kk];
}

// ---------------- generic matrix transpose: in[R][C] -> out[C][R] ----------------
__global__ void k_mtrans(const float* __restrict__ in, float* __restrict__ out,
                         int R, int C) {
    int i = blockIdx.x * 256 + threadIdx.x;
    if (i >= R * C) return;
    int r = i % R, c = i / R;
    out[i] = in[(size_t)r * C + c];   // out[c*R + r]
}

// ---------------- conv1: xn[t][192] -> h1[t][64], gelu ----------------
__global__ __launch_bounds__(256) void k_conv1(const float* __restrict__ xn,
                                               const float* __restrict__ w1t,
                                               const float* __restrict__ b1,
                                               float* __restrict__ h1) {
    __shared__ int nb[8][27];
    int tid = threadIdx.x;
    int oc = tid & 63, sg = tid >> 6;
    int t0 = blockIdx.x * 8;
    if (tid < 8 * 27) {
        int sp = tid / 27, kk = tid % 27;
        int t = t0 + sp;
        int w = t & 63, h = (t >> 6) & 63, d = t >> 12;
        int kd = kk / 9 - 1, kh = (kk / 3) % 3 - 1, kw = kk % 3 - 1;
        int dd = d + kd, hh = h + kh, ww = w + kw;
        nb[sp][kk] = (dd >= 0 && dd < DD_ && hh >= 0 && hh < HH_ && ww >= 0 && ww < WW_)
                         ? ((dd << 12) | (hh << 6) | ww) : -1;
    }
    __syncthreads();
    int sp0 = sg * 2, sp1 = sg * 2 + 1;
    float acc0 = 0.f, acc1 = 0.f;
    for (int kk = 0; kk < 27; kk++) {
        int n0 = nb[sp0][kk], n1 = nb[sp1][kk];
        if (n0 < 0 && n1 < 0) continue;
        const float* wp = w1t + kk * 64 + oc;
        if (n0 >= 0 && n1 >= 0) {
            const float* p0 = xn + (size_t)n0 * CDIM;
            const float* p1 = xn + (size_t)n1 * CDIM;
            for (int c = 0; c < CDIM; c++) {
                float w = wp[(size_t)c * 27 * 64];
                acc0 += w * p0[c]; acc1 += w * p1[c];
            }
        } else if (n0 >= 0) {
            const float* p0 = xn + (size_t)n0 * CDIM;
            for (int c = 0; c < CDIM; c++) acc0 += wp[(size_t)c * 27 * 64] * p0[c];
        } else {
            const float* p1 = xn + (size_t)n1 * CDIM;
            for (int c = 0; c < CDIM; c++) acc1 += wp[(size_t)c * 27 * 64] * p1[c];
        }
    }
    float bb = b1[oc];
    h1[(size_t)(t0 + sp0) * C3 + oc] = gelu_exact(acc0 + bb);
    h1[(size_t)(t0 + sp1) * C3 + oc] = gelu_exact(acc1 + bb);
}

// ---------------- conv2: h1[t][64] -> h2[t][192] (+bias) ----------------
__global__ __launch_bounds__(192) void k_conv2(const float* __restrict__ h1,
                                               const float* __restrict__ w2t,
                                               const float* __restrict__ b2,
                                               float* __restrict__ h2) {
    __shared__ int nb[4][27];
    int tid = threadIdx.x;
    int oc = tid;
    int t0 = blockIdx.x * 4;
    if (tid < 4 * 27) {
        int sp = tid / 27, kk = tid % 27;
        int t = t0 + sp;
        int w = t & 63, h = (t >> 6) & 63, d = t >> 12;
        int kd = kk / 9 - 1, kh = (kk / 3) % 3 - 1, kw = kk % 3 - 1;
        int dd = d + kd, hh = h + kh, ww = w + kw;
        nb[sp][kk] = (dd >= 0 && dd < DD_ && hh >= 0 && hh < HH_ && ww >= 0 && ww < WW_)
                         ? ((dd << 12) | (hh << 6) | ww) : -1;
    }
    __syncthreads();
    float acc[4] = {0.f, 0.f, 0.f, 0.f};
    for (int kk = 0; kk < 27; kk++) {
        const float* wp = w2t + kk * CDIM + oc;
        int n0 = nb[0][kk], n1 = nb[1][kk], n2 = nb[2][kk], n3 = nb[3][kk];
        for (int c = 0; c < C3; c++) {
            float w = wp[(size_t)c * 27 * CDIM];
            if (n0 >= 0) acc[0] += w * h1[(size_t)n0 * C3 + c];
            if (n1 >= 0) acc[1] += w * h1[(size_t)n1 * C3 + c];
            if (n2 >= 0) acc[2] += w * h1[(size_t)n2 * C3 + c];
            if (n3 >= 0) acc[3] += w * h1[(size_t)n3 * C3 + c];
        }
    }
    float bb = b2[oc];
    for (int s = 0; s < 4; s++)
        h2[(size_t)(t0 + s) * CDIM + oc] = acc[s] + bb;
}

// ---------------- pooled partial sums: 256 blocks x 128 positions ----------------
__global__ __launch_bounds__(192) void k_pool(const float* __restrict__ h2,
                                              float* __restrict__ part) {
    int c = threadIdx.x, b = blockIdx.x;
    float s = 0.f;
    for (int i = 0; i < 128; i++) s += h2[(size_t)(b * 128 + i) * CDIM + c];
    part[b * CDIM + c] = s;
}

// ---------------- channel attention MLP -> amask[192] ----------------
__global__ __launch_bounds__(192) void k_ca(const float* __restrict__ part,
                                            const float* __restrict__ ca1w,
                                            const float* __restrict__ ca1b,
                                            const float* __restrict__ ca2w,
                                            const float* __restrict__ ca2b,
                                            float* __restrict__ amask) {
    __shared__ float pooled[CDIM];
    __shared__ float hid[6];
    int c = threadIdx.x;
    float s = 0.f;
    for (int b = 0; b < 256; b++) s += part[b * CDIM + c];
    pooled[c] = s * (1.0f / 32768.0f);
    __syncthreads();
    if (c < 6) {
        float a = ca1b[c];
        for (int j = 0; j < CDIM; j++) a += ca1w[c * CDIM + j] * pooled[j];
        hid[c] = fmaxf(a, 0.f);
    }
    __syncthreads();
    float a = ca2b[c];
    for (int j = 0; j < 6; j++) a += ca2w[c * 6 + j] * hid[j];
    amask[c] = 1.0f / (1.0f + expf(-a));
}

// ---------------- qkv: windowed gather + GEMM row; q scaled ----------------
__global__ __launch_bounds__(192) void k_qkv(const float* __restrict__ xn,
                                             const float* __restrict__ qkvT, // [192][576]
                                             const float* __restrict__ qkvb,
                                             float* __restrict__ q,
                                             float* __restrict__ k,
                                             float* __restrict__ v) {
    __shared__ float xr[4][CDIM];
    int tid = threadIdx.x;
    int wt0 = blockIdx.x * 4;
    int torig[4];
    for (int i = 0; i < 4; i++) {
        int wt = wt0 + i;
        int wi = wt >> 9, n = wt & 511;
        int wh = wi >> 3, ww = wi & 7;
        int nd = n >> 6, nh = (n >> 3) & 7, nw = n & 7;
        torig[i] = (nd << 12) | ((wh * 8 + nh) << 6) | (ww * 8 + nw);
    }
    for (int i = 0; i < 4; i++) xr[i][tid] = xn[(size_t)torig[i] * CDIM + tid];
    __syncthreads();
    float aq[4] = {0, 0, 0, 0}, ak[4] = {0, 0, 0, 0}, av[4] = {0, 0, 0, 0};
    for (int c = 0; c < CDIM; c++) {
        const float* wrow = qkvT + (size_t)c * 576;
        float wq = wrow[tid], wk = wrow[192 + tid], wv = wrow[384 + tid];
        for (int i = 0; i < 4; i++) {
            float xv = xr[i][c];
            aq[i] += wq * xv; ak[i] += wk * xv; av[i] += wv * xv;
        }
    }
    int head = tid >> 5, dd = tid & 31;
    float bq = qkvb[tid], bk = qkvb[192 + tid], bv = qkvb[384 + tid];
    for (int i = 0; i < 4; i++) {
        int wt = wt0 + i; int wi = wt >> 9, n = wt & 511;
        size_t base = ((size_t)(wi * NHEAD + head) * NTOKW + n) * HDIM + dd;
        q[base] = (aq[i] + bq) * 0.17677669529663687f;  // 1/sqrt(32)
        k[base] = ak[i] + bk;
        v[base] = av[i] + bv;
    }
}

// ---------------- attention: 1 wave per (win,head,row) ----------------
__global__ __launch_bounds__(256) void k_attn(const float* __restrict__ q,
                                              const float* __restrict__ k,
                                              const float* __restrict__ v,
                                              const float* __restrict__ rpb,
                                              const int* __restrict__ rpi,
                                              float* __restrict__ out) {
    __shared__ float sc[4][NTOKW];
    __shared__ float qr[4][HDIM];
    int wv = threadIdx.x >> 6, lane = threadIdx.x & 63;
    int R = blockIdx.x * 4 + wv;
    int n = R & 511, wh = R >> 9;     // wh = wi*6+head
    int head = wh % NHEAD;
    const float* qp = q + ((size_t)wh * NTOKW + n) * HDIM;
    const float* kp = k + (size_t)wh * NTOKW * HDIM;
    const float* vp = v + (size_t)wh * NTOKW * HDIM;
    if (lane < HDIM) qr[wv][lane] = qp[lane];
    __syncthreads();
    float mx = -1e30f;
    const int* rpin = rpi + (size_t)n * NTOKW;
    for (int mc = 0; mc < 8; mc++) {
        int m = mc * 64 + lane;
        const float* kr = kp + (size_t)m * HDIM;
        float s = 0.f;
        #pragma unroll
        for (int d2 = 0; d2 < HDIM; d2++) s += qr[wv][d2] * kr[d2];
        s += rpb[(size_t)rpin[m] * NHEAD + head];
        sc[wv][m] = s;
        mx = fmaxf(mx, s);
    }
    for (int o = 32; o; o >>= 1) mx = fmaxf(mx, __shfl_xor(mx, o));
    float sum = 0.f;
    for (int mc = 0; mc < 8; mc++) {
        int m = mc * 64 + lane;
        float e = __expf(sc[wv][m] - mx);
        sc[wv][m] = e;
        sum += e;
    }
    __syncthreads();   // sc fully written before cross-lane PV reads
    for (int o = 32; o; o >>= 1) sum += __shfl_xor(sum, o);
    float inv = 1.0f / sum;
    int half = lane >> 5, dd = lane & 31;
    const float* vb = vp + (size_t)half * 256 * HDIM + dd;
    const float* pb = &sc[wv][half * 256];
    float acc = 0.f;
    for (int m2 = 0; m2 < 256; m2++) acc += pb[m2] * vb[(size_t)m2 * HDIM];
    acc += __shfl_xor(acc, 32);
    if (lane < HDIM) {
        int wi = wh / NHEAD;
        out[((size_t)(wi * NTOKW + n)) * CDIM + head * HDIM + dd] = acc * inv;
    }
}

// ---------------- proj + residual + conv branch merge -> x2 (in d_out) ----------------
__global__ __launch_bounds__(192) void k_proj(const float* __restrict__ ao,
                                              const float* __restrict__ projT, // [192][192]
                                              const float* __restrict__ pb,
                                              const float* __restrict__ x,
                                              const float* __restrict__ h2,
                                              const float* __restrict__ amask,
                                              float* __restrict__ x2) {
    __shared__ float ar[4][CDIM];
    int tid = threadIdx.x;
    int wt0 = blockIdx.x * 4;
    for (int i = 0; i < 4; i++) ar[i][tid] = ao[(size_t)(wt0 + i) * CDIM + tid];
    __syncthreads();
    float acc[4] = {0, 0, 0, 0};
    for (int c = 0; c < CDIM; c++) {
        float w = projT[(size_t)c * CDIM + tid];
        for (int i = 0; i < 4; i++) acc[i] += w * ar[i][c];
    }
    float bb = pb[tid], am = amask[tid];
    for (int i = 0; i < 4; i++) {
        int wt = wt0 + i; int wi = wt >> 9, n = wt & 511;
        int wh = wi >> 3, ww = wi & 7;
        int nd = n >> 6, nh = (n >> 3) & 7, nw = n & 7;
        int t = (nd << 12) | ((wh * 8 + nh) << 6) | (ww * 8 + nw);
        size_t idx = (size_t)t * CDIM + tid;
        x2[idx] = x[idx] + acc[i] + bb + 0.01f * h2[idx] * am;
    }
}

// ---------------- fused MLP: y -> gelu(fc1) -> fc2, out += (in-place on x2) ----------------
__global__ __launch_bounds__(256) void k_mlp(const float* __restrict__ y,
                                             const float* __restrict__ w1T, // [192][768]
                                             const float* __restrict__ b1,
                                             const float* __restrict__ w2T, // [768][192]
                                             const float* __restrict__ b2,
                                             float* __restrict__ out) {
    __shared__ float yr[8][CDIM];
    __shared__ float hr[8][FCH];
    int tid = threadIdx.x;
    int t0 = blockIdx.x * 8;
    for (int i = tid; i < 8 * CDIM; i += 256) {
        int r = i / CDIM, c = i % CDIM;
        yr[r][c] = y[(size_t)(t0 + r) * CDIM + c];
    }
    __syncthreads();
    // fc1 + gelu: each thread -> hidden units tid, tid+256, tid+512
    {
        float a[3][8];
        for (int jj = 0; jj < 3; jj++)
            for (int r = 0; r < 8; r++) a[jj][r] = 0.f;
        for (int c0 = 0; c0 < CDIM; c0 += 4) {
            float4 yv[8];
            #pragma unroll
            for (int r = 0; r < 8; r++) yv[r] = *(const float4*)&yr[r][c0];
            #pragma unroll
            for (int jj = 0; jj < 3; jj++) {
                int j = tid + jj * 256;
                float w0 = w1T[(size_t)(c0 + 0) * FCH + j];
                float w1 = w1T[(size_t)(c0 + 1) * FCH + j];
                float w2 = w1T[(size_t)(c0 + 2) * FCH + j];
                float w3 = w1T[(size_t)(c0 + 3) * FCH + j];
                #pragma unroll
                for (int r = 0; r < 8; r++)
                    a[jj][r] += w0 * yv[r].x + w1 * yv[r].y + w2 * yv[r].z + w3 * yv[r].w;
            }
        }
        for (int jj = 0; jj < 3; jj++) {
            int j = tid + jj * 256;
            float bb = b1[j];
            for (int r = 0; r < 8; r++) hr[r][j] = gelu_exact(a[jj][r] + bb);
        }
    }
    __syncthreads();
    // fc2: threads 0..191 each own one output channel
    if (tid < CDIM) {
        float a[8] = {0, 0, 0, 0, 0, 0, 0, 0};
        for (int c0 = 0; c0 < FCH; c0 += 4) {
            float4 hv[8];
            #pragma unroll
            for (int r = 0; r < 8; r++) hv[r] = *(const float4*)&hr[r][c0];
            float w0 = w2T[(size_t)(c0 + 0) * CDIM + tid];
            float w1 = w2T[(size_t)(c0 + 1) * CDIM + tid];
            float w2 = w2T[(size_t)(c0 + 2) * CDIM + tid];
            float w3 = w2T[(size_t)(c0 + 3) * CDIM + tid];
            #pragma unroll
            for (int r = 0; r < 8; r++)
                a[r] += w0 * hv[r].x + w1 * hv[r].y + w2 * hv[r].z + w3 * hv[r].w;
        }
        float bb = b2[tid];
        for (int r = 0; r < 8; r++) {
            size_t idx = (size_t)(t0 + r) * CDIM + tid;
            out[idx] = out[idx] + a[r] + bb;
        }
    }
}

// ---------------- launcher ----------------
extern "C" void kernel_launch(void* const* d_in, const int* in_sizes, int n_in,
                              void* d_out, int out_size, void* d_ws, size_t ws_size,
                              hipStream_t stream) {
    const float* x     = (const float*)d_in[0];
    const float* n1g   = (const float*)d_in[1];
    const float* n1b   = (const float*)d_in[2];
    const float* qkvw  = (const float*)d_in[3];
    const float* qkvb  = (const float*)d_in[4];
    const float* rpb   = (const float*)d_in[5];
    const float* projw = (const float*)d_in[6];
    const float* projb = (const float*)d_in[7];
    const float* c1w   = (const float*)d_in[8];
    const float* c1b   = (const float*)d_in[9];
    const float* c2w   = (const float*)d_in[10];
    const float* c2b   = (const float*)d_in[11];
    const float* ca1w  = (const float*)d_in[12];
    const float* ca1b  = (const float*)d_in[13];
    const float* ca2w  = (const float*)d_in[14];
    const float* ca2b  = (const float*)d_in[15];
    const float* n2g   = (const float*)d_in[16];
    const float* n2b   = (const float*)d_in[17];
    const float* fc1w  = (const float*)d_in[18];
    const float* fc1b  = (const float*)d_in[19];
    const float* fc2w  = (const float*)d_in[20];
    const float* fc2b  = (const float*)d_in[21];
    const int*   rpi   = (const int*)d_in[22];

    float* ws  = (float*)d_ws;
    float* out = (float*)d_out;

    float* xn    = ws + OFF_XN;
    float* qb    = ws + OFF_Q;
    float* kb    = ws + OFF_K;
    float* vb    = ws + OFF_V;
    float* h1    = ws + OFF_H1;
    float* h2    = ws + OFF_H2;
    float* part  = ws + OFF_PART;
    float* amask = ws + OFF_AMASK;
    float* w1t   = ws + OFF_W1T;
    float* w2t   = ws + OFF_W2T;
    float* qkvT  = ws + OFF_QKVT;
    float* projT = ws + OFF_PROJT;
    float* fc1T  = ws + OFF_FC1T;
    float* fc2T  = ws + OFF_FC2T;
    float* attn  = ws + OFF_XN;   // reuse: xn dead after k_qkv
    float* y     = ws + OFF_Q;    // reuse: q dead after k_attn

    // weight transposes (tiny)
    k_wtrans<<<(64 * 192 * 27 + 255) / 256, 256, 0, stream>>>(c1w, w1t, 64, 192);
    k_wtrans<<<(192 * 64 * 27 + 255) / 256, 256, 0, stream>>>(c2w, w2t, 192, 64);
    k_mtrans<<<(576 * 192 + 255) / 256, 256, 0, stream>>>(qkvw, qkvT, 576, 192);
    k_mtrans<<<(192 * 192 + 255) / 256, 256, 0, stream>>>(projw, projT, 192, 192);
    k_mtrans<<<(768 * 192 + 255) / 256, 256, 0, stream>>>(fc1w, fc1T, 768, 192);
    k_mtrans<<<(192 * 768 + 255) / 256, 256, 0, stream>>>(fc2w, fc2T, 192, 768);

    // LN1
    k_ln<<<LTOK / 4, 256, 0, stream>>>(x, n1g, n1b, xn);
    // conv branch
    k_conv1<<<LTOK / 8, 256, 0, stream>>>(xn, w1t, c1b, h1);
    k_conv2<<<LTOK / 4, 192, 0, stream>>>(h1, w2t, c2b, h2);
    k_pool<<<256, 192, 0, stream>>>(h2, part);
    k_ca<<<1, 192, 0, stream>>>(part, ca1w, ca1b, ca2w, ca2b, amask);
    // attention branch
    k_qkv<<<LTOK / 4, 192, 0, stream>>>(xn, qkvT, qkvb, qb, kb, vb);
    k_attn<<<(NWIN * NHEAD * NTOKW) / 4, 256, 0, stream>>>(qb, kb, vb, rpb, rpi, attn);
    k_proj<<<LTOK / 4, 192, 0, stream>>>(attn, projT, projb, x, h2, amask, out);
    // LN2 + MLP
    k_ln<<<LTOK / 4, 256, 0, stream>>>(out, n2g, n2b, y);
    k_mlp<<<LTOK / 8, 256, 0, stream>>>(y, fc1T, fc1b, fc2T, fc2b, out);
}

// Round 4
// 4655.290 us; speedup vs baseline: 1.5159x; 1.5159x over previous
//
#include <hip/hip_runtime.h>
#include <hip/hip_bf16.h>

// ---------------- problem constants ----------------
#define LTOK  32768   // D*H*W
#define CDIM  192
#define DD_   8
#define HH_   64
#define WW_   64
#define NHEAD 6
#define HDIM  32
#define NWIN  64      // (D/8)*(H/8)*(W/8)
#define NTOKW 512     // tokens per window
#define C3    64      // C/3
#define FCH   768     // 4*C

// ws layout (float32-slot offsets), total 33136832 f32 = 132.5 MB
#define OFF_XN     0u          // 6291456  (also reused for attn-out)
#define OFF_QH     6291456u    // 3145728 slots = 6291456 bf16
#define OFF_KH     9437184u    // 3145728
#define OFF_VH     12582912u   // 3145728
#define OFF_Y      15728640u   // 6291456  (LN2 out)
#define OFF_H1     22020096u   // 2097152
#define OFF_H2     24117248u   // 6291456
#define OFF_PART   30408704u   // 49152
#define OFF_AMASK  30457856u   // 192
#define OFF_BIAST  30458048u   // 1572864  (6*512*512 f32)
#define OFF_W1T    32030912u
#define OFF_W2T    32362688u
#define OFF_QKVT   32694464u
#define OFF_PROJT  32805056u
#define OFF_FC1T   32841920u
#define OFF_FC2T   32989376u

typedef __attribute__((ext_vector_type(8)))  short short8v;
typedef __attribute__((ext_vector_type(16))) float f32x16;

union FragU { short8v v; unsigned u[4]; };

__device__ __forceinline__ float gelu_exact(float x) {
    return 0.5f * x * (1.0f + erff(x * 0.70710678118654752f));
}

__device__ __forceinline__ unsigned short bf16bits(float x) {
    union { __hip_bfloat16 b; unsigned short u; } cv;
    cv.b = __float2bfloat16(x);
    return cv.u;
}

// ---------------- LayerNorm: 1 wave per token (C=192 = 64*3) ----------------
__global__ __launch_bounds__(256) void k_ln(const float* __restrict__ in,
                                            const float* __restrict__ g,
                                            const float* __restrict__ b,
                                            float* __restrict__ out) {
    int wv = threadIdx.x >> 6, lane = threadIdx.x & 63;
    int t = blockIdx.x * 4 + wv;
    const float* row = in + (size_t)t * CDIM;
    float x0 = row[lane], x1 = row[lane + 64], x2 = row[lane + 128];
    float s = x0 + x1 + x2;
    for (int o = 32; o; o >>= 1) s += __shfl_xor(s, o);
    float m = s * (1.0f / 192.0f);
    float d0 = x0 - m, d1 = x1 - m, d2 = x2 - m;
    float vv = d0 * d0 + d1 * d1 + d2 * d2;
    for (int o = 32; o; o >>= 1) vv += __shfl_xor(vv, o);
    float inv = rsqrtf(vv * (1.0f / 192.0f) + 1e-5f);
    size_t base = (size_t)t * CDIM;
    out[base + lane]       = d0 * inv * g[lane]       + b[lane];
    out[base + lane + 64]  = d1 * inv * g[lane + 64]  + b[lane + 64];
    out[base + lane + 128] = d2 * inv * g[lane + 128] + b[lane + 128];
}

// ---------------- conv weight transpose ----------------
__global__ void k_wtrans(const float* __restrict__ w, float* __restrict__ wt,
                         int OC, int IC) {
    int i = blockIdx.x * 256 + threadIdx.x;
    int total = OC * IC * 27;
    if (i >= total) return;
    int oc = i % OC; int rest = i / OC; int kk = rest % 27; int c = rest / 27;
    wt[i] = w[((size_t)oc * IC + c) * 27 + kk];
}

// ---------------- generic matrix transpose ----------------
__global__ void k_mtrans(const float* __restrict__ in, float* __restrict__ out,
                         int R, int C) {
    int i = blockIdx.x * 256 + threadIdx.x;
    if (i >= R * C) return;
    int r = i % R, c = i / R;
    out[i] = in[(size_t)r * C + c];
}

// ---------------- bias precompute: biasT[h][m][n] = rpb[rpi[n][m]*6+h] ----------------
__global__ __launch_bounds__(256) void k_bias(const int* __restrict__ rpi,
                                              const float* __restrict__ rpb,
                                              float* __restrict__ biasT) {
    __shared__ int idxl[64][64];
    int tid = threadIdx.x;
    int n0 = (blockIdx.x >> 3) * 64, m0 = (blockIdx.x & 7) * 64;
    for (int it = 0; it < 16; it++) {
        int e = it * 256 + tid;
        int ln_ = e >> 6, lm = e & 63;
        idxl[ln_][lm] = rpi[(size_t)(n0 + ln_) * NTOKW + m0 + lm];
    }
    __syncthreads();
    for (int it = 0; it < 16; it++) {
        int e = it * 256 + tid;
        int lm = e >> 6, ln_ = e & 63;
        int id = idxl[ln_][lm];
        #pragma unroll
        for (int h = 0; h < NHEAD; h++)
            biasT[(size_t)h * NTOKW * NTOKW + (size_t)(m0 + lm) * NTOKW + n0 + ln_] =
                rpb[id * NHEAD + h];
    }
}

// ---------------- conv1: xn[t][192] -> h1[t][64], gelu ----------------
__global__ __launch_bounds__(256) void k_conv1(const float* __restrict__ xn,
                                               const float* __restrict__ w1t,
                                               const float* __restrict__ b1,
                                               float* __restrict__ h1) {
    __shared__ int nb[8][27];
    int tid = threadIdx.x;
    int oc = tid & 63, sg = tid >> 6;
    int t0 = blockIdx.x * 8;
    if (tid < 8 * 27) {
        int sp = tid / 27, kk = tid % 27;
        int t = t0 + sp;
        int w = t & 63, h = (t >> 6) & 63, d = t >> 12;
        int kd = kk / 9 - 1, kh = (kk / 3) % 3 - 1, kw = kk % 3 - 1;
        int dd = d + kd, hh = h + kh, ww = w + kw;
        nb[sp][kk] = (dd >= 0 && dd < DD_ && hh >= 0 && hh < HH_ && ww >= 0 && ww < WW_)
                         ? ((dd << 12) | (hh << 6) | ww) : -1;
    }
    __syncthreads();
    int sp0 = sg * 2, sp1 = sg * 2 + 1;
    float acc0 = 0.f, acc1 = 0.f;
    for (int kk = 0; kk < 27; kk++) {
        int n0 = nb[sp0][kk], n1 = nb[sp1][kk];
        if (n0 < 0 && n1 < 0) continue;
        const float* wp = w1t + kk * 64 + oc;
        if (n0 >= 0 && n1 >= 0) {
            const float* p0 = xn + (size_t)n0 * CDIM;
            const float* p1 = xn + (size_t)n1 * CDIM;
            for (int c = 0; c < CDIM; c++) {
                float w = wp[(size_t)c * 27 * 64];
                acc0 += w * p0[c]; acc1 += w * p1[c];
            }
        } else if (n0 >= 0) {
            const float* p0 = xn + (size_t)n0 * CDIM;
            for (int c = 0; c < CDIM; c++) acc0 += wp[(size_t)c * 27 * 64] * p0[c];
        } else {
            const float* p1 = xn + (size_t)n1 * CDIM;
            for (int c = 0; c < CDIM; c++) acc1 += wp[(size_t)c * 27 * 64] * p1[c];
        }
    }
    float bb = b1[oc];
    h1[(size_t)(t0 + sp0) * C3 + oc] = gelu_exact(acc0 + bb);
    h1[(size_t)(t0 + sp1) * C3 + oc] = gelu_exact(acc1 + bb);
}

// ---------------- conv2: h1[t][64] -> h2[t][192] (+bias) ----------------
__global__ __launch_bounds__(192) void k_conv2(const float* __restrict__ h1,
                                               const float* __restrict__ w2t,
                                               const float* __restrict__ b2,
                                               float* __restrict__ h2) {
    __shared__ int nb[4][27];
    int tid = threadIdx.x;
    int oc = tid;
    int t0 = blockIdx.x * 4;
    if (tid < 4 * 27) {
        int sp = tid / 27, kk = tid % 27;
        int t = t0 + sp;
        int w = t & 63, h = (t >> 6) & 63, d = t >> 12;
        int kd = kk / 9 - 1, kh = (kk / 3) % 3 - 1, kw = kk % 3 - 1;
        int dd = d + kd, hh = h + kh, ww = w + kw;
        nb[sp][kk] = (dd >= 0 && dd < DD_ && hh >= 0 && hh < HH_ && ww >= 0 && ww < WW_)
                         ? ((dd << 12) | (hh << 6) | ww) : -1;
    }
    __syncthreads();
    float acc[4] = {0.f, 0.f, 0.f, 0.f};
    for (int kk = 0; kk < 27; kk++) {
        const float* wp = w2t + kk * CDIM + oc;
        int n0 = nb[0][kk], n1 = nb[1][kk], n2 = nb[2][kk], n3 = nb[3][kk];
        for (int c = 0; c < C3; c++) {
            float w = wp[(size_t)c * 27 * CDIM];
            if (n0 >= 0) acc[0] += w * h1[(size_t)n0 * C3 + c];
            if (n1 >= 0) acc[1] += w * h1[(size_t)n1 * C3 + c];
            if (n2 >= 0) acc[2] += w * h1[(size_t)n2 * C3 + c];
            if (n3 >= 0) acc[3] += w * h1[(size_t)n3 * C3 + c];
        }
    }
    float bb = b2[oc];
    for (int s = 0; s < 4; s++)
        h2[(size_t)(t0 + s) * CDIM + oc] = acc[s] + bb;
}

// ---------------- pooled partial sums ----------------
__global__ __launch_bounds__(192) void k_pool(const float* __restrict__ h2,
                                              float* __restrict__ part) {
    int c = threadIdx.x, b = blockIdx.x;
    float s = 0.f;
    for (int i = 0; i < 128; i++) s += h2[(size_t)(b * 128 + i) * CDIM + c];
    part[b * CDIM + c] = s;
}

// ---------------- channel attention MLP -> amask[192] ----------------
__global__ __launch_bounds__(192) void k_ca(const float* __restrict__ part,
                                            const float* __restrict__ ca1w,
                                            const float* __restrict__ ca1b,
                                            const float* __restrict__ ca2w,
                                            const float* __restrict__ ca2b,
                                            float* __restrict__ amask) {
    __shared__ float pooled[CDIM];
    __shared__ float hid[6];
    int c = threadIdx.x;
    float s = 0.f;
    for (int b = 0; b < 256; b++) s += part[b * CDIM + c];
    pooled[c] = s * (1.0f / 32768.0f);
    __syncthreads();
    if (c < 6) {
        float a = ca1b[c];
        for (int j = 0; j < CDIM; j++) a += ca1w[c * CDIM + j] * pooled[j];
        hid[c] = fmaxf(a, 0.f);
    }
    __syncthreads();
    float a = ca2b[c];
    for (int j = 0; j < 6; j++) a += ca2w[c * 6 + j] * hid[j];
    amask[c] = 1.0f / (1.0f + expf(-a));
}

// ---------------- qkv: windowed gather + GEMM row; outputs bf16, q scaled ----------------
__global__ __launch_bounds__(192) void k_qkv(const float* __restrict__ xn,
                                             const float* __restrict__ qkvT, // [192][576]
                                             const float* __restrict__ qkvb,
                                             __hip_bfloat16* __restrict__ q,
                                             __hip_bfloat16* __restrict__ k,
                                             __hip_bfloat16* __restrict__ v) {
    __shared__ float xr[4][CDIM];
    int tid = threadIdx.x;
    int wt0 = blockIdx.x * 4;
    int torig[4];
    for (int i = 0; i < 4; i++) {
        int wt = wt0 + i;
        int wi = wt >> 9, n = wt & 511;
        int wh = wi >> 3, ww = wi & 7;
        int nd = n >> 6, nh = (n >> 3) & 7, nw = n & 7;
        torig[i] = (nd << 12) | ((wh * 8 + nh) << 6) | (ww * 8 + nw);
    }
    for (int i = 0; i < 4; i++) xr[i][tid] = xn[(size_t)torig[i] * CDIM + tid];
    __syncthreads();
    float aq[4] = {0, 0, 0, 0}, ak[4] = {0, 0, 0, 0}, av[4] = {0, 0, 0, 0};
    for (int c = 0; c < CDIM; c++) {
        const float* wrow = qkvT + (size_t)c * 576;
        float wq = wrow[tid], wk = wrow[192 + tid], wv = wrow[384 + tid];
        for (int i = 0; i < 4; i++) {
            float xv = xr[i][c];
            aq[i] += wq * xv; ak[i] += wk * xv; av[i] += wv * xv;
        }
    }
    int head = tid >> 5, dd = tid & 31;
    float bq = qkvb[tid], bk = qkvb[192 + tid], bv = qkvb[384 + tid];
    for (int i = 0; i < 4; i++) {
        int wt = wt0 + i; int wi = wt >> 9, n = wt & 511;
        size_t base = ((size_t)(wi * NHEAD + head) * NTOKW + n) * HDIM + dd;
        q[base] = __float2bfloat16((aq[i] + bq) * 0.17677669529663687f);
        k[base] = __float2bfloat16(ak[i] + bk);
        v[base] = __float2bfloat16(av[i] + bv);
    }
}

// ---------------- MFMA flash attention ----------------
// 1 wave = one 32-query tile of one (win,head). S^T = mfma(K,Q); O^T = mfma(V^T,P^T).
// C/D layout (verified): col=lane&31, row=(reg&3)+8*(reg>>2)+4*(lane>>5).
__global__ __launch_bounds__(256) void k_attn(const __hip_bfloat16* __restrict__ qh,
                                              const __hip_bfloat16* __restrict__ kh,
                                              const __hip_bfloat16* __restrict__ vh,
                                              const float* __restrict__ biasT,
                                              float* __restrict__ out) {
    __shared__ float ot[4][32][33];
    int wv = threadIdx.x >> 6, lane = threadIdx.x & 63;
    int tile = blockIdx.x * 4 + wv;          // 6144 tiles
    int qt = tile & 15, wh = tile >> 4;      // qt 0..15, wh 0..383
    int head = wh % NHEAD, wi = wh / NHEAD;
    int qb = qt * 32;
    int h = lane >> 5, ln31 = lane & 31;

    const unsigned short* qp = (const unsigned short*)qh + ((size_t)wh * NTOKW + qb + ln31) * HDIM;
    short8v qf0 = *(const short8v*)(qp + 8 * h);
    short8v qf1 = *(const short8v*)(qp + 16 + 8 * h);
    const unsigned short* kbase = (const unsigned short*)kh + (size_t)wh * NTOKW * HDIM;
    const unsigned short* vbase = (const unsigned short*)vh + (size_t)wh * NTOKW * HDIM;
    const float* bbase = biasT + (size_t)head * NTOKW * NTOKW + qb + ln31;

    f32x16 O;
    #pragma unroll
    for (int r = 0; r < 16; r++) O[r] = 0.f;
    float m = -1e30f, l = 0.f;

    for (int kb = 0; kb < NTOKW; kb += 32) {
        // --- S^T tile: 32 keys x 32 queries ---
        const unsigned short* kp = kbase + (size_t)(kb + ln31) * HDIM;
        short8v kf0 = *(const short8v*)(kp + 8 * h);
        short8v kf1 = *(const short8v*)(kp + 16 + 8 * h);
        f32x16 S;
        #pragma unroll
        for (int r = 0; r < 16; r++) S[r] = 0.f;
        S = __builtin_amdgcn_mfma_f32_32x32x16_bf16(kf0, qf0, S, 0, 0, 0);
        S = __builtin_amdgcn_mfma_f32_32x32x16_bf16(kf1, qf1, S, 0, 0, 0);

        // --- add relative-position bias; key(r) = (r&3)+8*(r>>2)+4h ---
        float s[16];
        #pragma unroll
        for (int r = 0; r < 16; r++) {
            int key = (r & 3) + 8 * (r >> 2) + 4 * h;
            s[r] = S[r] + bbase[(size_t)(kb + key) * NTOKW];
        }
        // --- online softmax; lane-local query column q = ln31 ---
        float cm = s[0];
        #pragma unroll
        for (int r = 1; r < 16; r++) cm = fmaxf(cm, s[r]);
        cm = fmaxf(cm, __shfl_xor(cm, 32));
        float mn = fmaxf(m, cm);
        float scale = __expf(m - mn);
        float e[16]; float cs = 0.f;
        #pragma unroll
        for (int r = 0; r < 16; r++) { e[r] = __expf(s[r] - mn); cs += e[r]; }
        cs += __shfl_xor(cs, 32);
        l = l * scale + cs;
        m = mn;
        #pragma unroll
        for (int r = 0; r < 16; r++) O[r] *= scale;

        // --- pack P^T to bf16, exchange halves ---
        unsigned P[8], Qx[8];
        #pragma unroll
        for (int i = 0; i < 8; i++)
            P[i] = (unsigned)bf16bits(e[2 * i]) | ((unsigned)bf16bits(e[2 * i + 1]) << 16);
        #pragma unroll
        for (int i = 0; i < 8; i++) Qx[i] = __shfl_xor(P[i], 32);

        FragU p0, p1;
        p0.u[0] = h ? Qx[2] : P[0];  p0.u[1] = h ? Qx[3] : P[1];
        p0.u[2] = h ? P[2]  : Qx[0]; p0.u[3] = h ? P[3]  : Qx[1];
        p1.u[0] = h ? Qx[6] : P[4];  p1.u[1] = h ? Qx[7] : P[5];
        p1.u[2] = h ? P[6]  : Qx[4]; p1.u[3] = h ? P[7]  : Qx[5];

        // --- V^T fragments: lane row d = ln31, elem i -> key 16j+8h+i ---
        const unsigned short* vp0 = vbase + (size_t)(kb + 8 * h) * HDIM + ln31;
        const unsigned short* vp1 = vbase + (size_t)(kb + 16 + 8 * h) * HDIM + ln31;
        short8v vf0, vf1;
        #pragma unroll
        for (int i = 0; i < 8; i++) {
            vf0[i] = (short)vp0[i * HDIM];
            vf1[i] = (short)vp1[i * HDIM];
        }
        O = __builtin_amdgcn_mfma_f32_32x32x16_bf16(vf0, p0.v, O, 0, 0, 0);
        O = __builtin_amdgcn_mfma_f32_32x32x16_bf16(vf1, p1.v, O, 0, 0, 0);
    }

    // --- normalize and write via LDS transpose (coalesced) ---
    float invl = 1.0f / l;
    #pragma unroll
    for (int r = 0; r < 16; r++) {
        int d = (r & 3) + 8 * (r >> 2) + 4 * h;
        ot[wv][ln31][d] = O[r] * invl;
    }
    __syncthreads();
    int t2 = lane >> 1, c0 = (lane & 1) * 16;
    float* outp = out + ((size_t)(wi * NTOKW + qb + t2)) * CDIM + head * HDIM + c0;
    #pragma unroll
    for (int i = 0; i < 16; i++) outp[i] = ot[wv][t2][c0 + i];
}

// ---------------- proj + residual + conv branch merge -> x2 (in d_out) ----------------
__global__ __launch_bounds__(192) void k_proj(const float* __restrict__ ao,
                                              const float* __restrict__ projT,
                                              const float* __restrict__ pb,
                                              const float* __restrict__ x,
                                              const float* __restrict__ h2,
                                              const float* __restrict__ amask,
                                              float* __restrict__ x2) {
    __shared__ float ar[4][CDIM];
    int tid = threadIdx.x;
    int wt0 = blockIdx.x * 4;
    for (int i = 0; i < 4; i++) ar[i][tid] = ao[(size_t)(wt0 + i) * CDIM + tid];
    __syncthreads();
    float acc[4] = {0, 0, 0, 0};
    for (int c = 0; c < CDIM; c++) {
        float w = projT[(size_t)c * CDIM + tid];
        for (int i = 0; i < 4; i++) acc[i] += w * ar[i][c];
    }
    float bb = pb[tid], am = amask[tid];
    for (int i = 0; i < 4; i++) {
        int wt = wt0 + i; int wi = wt >> 9, n = wt & 511;
        int wh = wi >> 3, ww = wi & 7;
        int nd = n >> 6, nh = (n >> 3) & 7, nw = n & 7;
        int t = (nd << 12) | ((wh * 8 + nh) << 6) | (ww * 8 + nw);
        size_t idx = (size_t)t * CDIM + tid;
        x2[idx] = x[idx] + acc[i] + bb + 0.01f * h2[idx] * am;
    }
}

// ---------------- fused MLP ----------------
__global__ __launch_bounds__(256) void k_mlp(const float* __restrict__ y,
                                             const float* __restrict__ w1T,
                                             const float* __restrict__ b1,
                                             const float* __restrict__ w2T,
                                             const float* __restrict__ b2,
                                             float* __restrict__ out) {
    __shared__ float yr[8][CDIM];
    __shared__ float hr[8][FCH];
    int tid = threadIdx.x;
    int t0 = blockIdx.x * 8;
    for (int i = tid; i < 8 * CDIM; i += 256) {
        int r = i / CDIM, c = i % CDIM;
        yr[r][c] = y[(size_t)(t0 + r) * CDIM + c];
    }
    __syncthreads();
    {
        float a[3][8];
        for (int jj = 0; jj < 3; jj++)
            for (int r = 0; r < 8; r++) a[jj][r] = 0.f;
        for (int c0 = 0; c0 < CDIM; c0 += 4) {
            float4 yv[8];
            #pragma unroll
            for (int r = 0; r < 8; r++) yv[r] = *(const float4*)&yr[r][c0];
            #pragma unroll
            for (int jj = 0; jj < 3; jj++) {
                int j = tid + jj * 256;
                float w0 = w1T[(size_t)(c0 + 0) * FCH + j];
                float w1 = w1T[(size_t)(c0 + 1) * FCH + j];
                float w2 = w1T[(size_t)(c0 + 2) * FCH + j];
                float w3 = w1T[(size_t)(c0 + 3) * FCH + j];
                #pragma unroll
                for (int r = 0; r < 8; r++)
                    a[jj][r] += w0 * yv[r].x + w1 * yv[r].y + w2 * yv[r].z + w3 * yv[r].w;
            }
        }
        for (int jj = 0; jj < 3; jj++) {
            int j = tid + jj * 256;
            float bb = b1[j];
            for (int r = 0; r < 8; r++) hr[r][j] = gelu_exact(a[jj][r] + bb);
        }
    }
    __syncthreads();
    if (tid < CDIM) {
        float a[8] = {0, 0, 0, 0, 0, 0, 0, 0};
        for (int c0 = 0; c0 < FCH; c0 += 4) {
            float4 hv[8];
            #pragma unroll
            for (int r = 0; r < 8; r++) hv[r] = *(const float4*)&hr[r][c0];
            float w0 = w2T[(size_t)(c0 + 0) * CDIM + tid];
            float w1 = w2T[(size_t)(c0 + 1) * CDIM + tid];
            float w2 = w2T[(size_t)(c0 + 2) * CDIM + tid];
            float w3 = w2T[(size_t)(c0 + 3) * CDIM + tid];
            #pragma unroll
            for (int r = 0; r < 8; r++)
                a[r] += w0 * hv[r].x + w1 * hv[r].y + w2 * hv[r].z + w3 * hv[r].w;
        }
        float bb = b2[tid];
        for (int r = 0; r < 8; r++) {
            size_t idx = (size_t)(t0 + r) * CDIM + tid;
            out[idx] = out[idx] + a[r] + bb;
        }
    }
}

// ---------------- launcher ----------------
extern "C" void kernel_launch(void* const* d_in, const int* in_sizes, int n_in,
                              void* d_out, int out_size, void* d_ws, size_t ws_size,
                              hipStream_t stream) {
    const float* x     = (const float*)d_in[0];
    const float* n1g   = (const float*)d_in[1];
    const float* n1b   = (const float*)d_in[2];
    const float* qkvw  = (const float*)d_in[3];
    const float* qkvb  = (const float*)d_in[4];
    const float* rpb   = (const float*)d_in[5];
    const float* projw = (const float*)d_in[6];
    const float* projb = (const float*)d_in[7];
    const float* c1w   = (const float*)d_in[8];
    const float* c1b   = (const float*)d_in[9];
    const float* c2w   = (const float*)d_in[10];
    const float* c2b   = (const float*)d_in[11];
    const float* ca1w  = (const float*)d_in[12];
    const float* ca1b  = (const float*)d_in[13];
    const float* ca2w  = (const float*)d_in[14];
    const float* ca2b  = (const float*)d_in[15];
    const float* n2g   = (const float*)d_in[16];
    const float* n2b   = (const float*)d_in[17];
    const float* fc1w  = (const float*)d_in[18];
    const float* fc1b  = (const float*)d_in[19];
    const float* fc2w  = (const float*)d_in[20];
    const float* fc2b  = (const float*)d_in[21];
    const int*   rpi   = (const int*)d_in[22];

    float* ws  = (float*)d_ws;
    float* out = (float*)d_out;

    float* xn    = ws + OFF_XN;
    __hip_bfloat16* qh = (__hip_bfloat16*)(ws + OFF_QH);
    __hip_bfloat16* kb_ = (__hip_bfloat16*)(ws + OFF_KH);
    __hip_bfloat16* vb_ = (__hip_bfloat16*)(ws + OFF_VH);
    float* y     = ws + OFF_Y;
    float* h1    = ws + OFF_H1;
    float* h2    = ws + OFF_H2;
    float* part  = ws + OFF_PART;
    float* amask = ws + OFF_AMASK;
    float* biasT = ws + OFF_BIAST;
    float* w1t   = ws + OFF_W1T;
    float* w2t   = ws + OFF_W2T;
    float* qkvT  = ws + OFF_QKVT;
    float* projT = ws + OFF_PROJT;
    float* fc1T  = ws + OFF_FC1T;
    float* fc2T  = ws + OFF_FC2T;
    float* attn  = ws + OFF_XN;   // reuse: xn dead after k_qkv

    // weight transposes + bias table (independent prep)
    k_wtrans<<<(64 * 192 * 27 + 255) / 256, 256, 0, stream>>>(c1w, w1t, 64, 192);
    k_wtrans<<<(192 * 64 * 27 + 255) / 256, 256, 0, stream>>>(c2w, w2t, 192, 64);
    k_mtrans<<<(576 * 192 + 255) / 256, 256, 0, stream>>>(qkvw, qkvT, 576, 192);
    k_mtrans<<<(192 * 192 + 255) / 256, 256, 0, stream>>>(projw, projT, 192, 192);
    k_mtrans<<<(768 * 192 + 255) / 256, 256, 0, stream>>>(fc1w, fc1T, 768, 192);
    k_mtrans<<<(192 * 768 + 255) / 256, 256, 0, stream>>>(fc2w, fc2T, 192, 768);
    k_bias<<<64, 256, 0, stream>>>(rpi, rpb, biasT);

    // LN1
    k_ln<<<LTOK / 4, 256, 0, stream>>>(x, n1g, n1b, xn);
    // conv branch
    k_conv1<<<LTOK / 8, 256, 0, stream>>>(xn, w1t, c1b, h1);
    k_conv2<<<LTOK / 4, 192, 0, stream>>>(h1, w2t, c2b, h2);
    k_pool<<<256, 192, 0, stream>>>(h2, part);
    k_ca<<<1, 192, 0, stream>>>(part, ca1w, ca1b, ca2w, ca2b, amask);
    // attention branch
    k_qkv<<<LTOK / 4, 192, 0, stream>>>(xn, qkvT, qkvb, qh, kb_, vb_);
    k_attn<<<(NWIN * NHEAD * 16) / 4, 256, 0, stream>>>(qh, kb_, vb_, biasT, attn);
    k_proj<<<LTOK / 4, 192, 0, stream>>>(attn, projT, projb, x, h2, amask, out);
    // LN2 + MLP
    k_ln<<<LTOK / 4, 256, 0, stream>>>(out, n2g, n2b, y);
    k_mlp<<<LTOK / 8, 256, 0, stream>>>(y, fc1T, fc1b, fc2T, fc2b, out);
}

// Round 5
// 894.927 us; speedup vs baseline: 7.8855x; 5.2019x over previous
//
#include <hip/hip_runtime.h>
#include <hip/hip_bf16.h>

// ---------------- problem constants ----------------
#define LTOK  32768   // D*H*W
#define CDIM  192
#define DD_   8
#define HH_   64
#define WW_   64
#define NHEAD 6
#define HDIM  32
#define NWIN  64      // (D/8)*(H/8)*(W/8)
#define NTOKW 512     // tokens per window
#define C3    64      // C/3
#define FCH   768     // 4*C

// ws layout (float32-slot offsets), total 33136832 f32 = 132.5 MB
#define OFF_XN     0u          // 6291456  (also reused for attn-out)
#define OFF_QH     6291456u    // 3145728 slots = 6291456 bf16
#define OFF_KH     9437184u    // 3145728
#define OFF_VH     12582912u   // 3145728
#define OFF_Y      15728640u   // 6291456  (xn bf16 early; LN2 out later)
#define OFF_H1     22020096u   // 2097152  (h1 bf16: 2M elems = 1M slots)
#define OFF_H2     24117248u   // 6291456
#define OFF_PART   30408704u   // 49152
#define OFF_AMASK  30457856u   // 192
#define OFF_BIAST  30458048u   // 1572864  (6*512*512 f32)
#define OFF_W1T    32030912u   // conv1 prepped bf16 (165888 slots used)
#define OFF_W2T    32362688u   // conv2 prepped bf16
#define OFF_QKVT   32694464u
#define OFF_PROJT  32805056u
#define OFF_FC1T   32841920u
#define OFF_FC2T   32989376u

typedef __attribute__((ext_vector_type(8)))  short short8v;
typedef __attribute__((ext_vector_type(16))) float f32x16;

union FragU { short8v v; unsigned u[4]; };

__device__ __forceinline__ float gelu_exact(float x) {
    return 0.5f * x * (1.0f + erff(x * 0.70710678118654752f));
}

__device__ __forceinline__ unsigned short bf16bits(float x) {
    union { __hip_bfloat16 b; unsigned short u; } cv;
    cv.b = __float2bfloat16(x);
    return cv.u;
}

// ---------------- LayerNorm: 1 wave per token; optional bf16 copy ----------------
__global__ __launch_bounds__(256) void k_ln(const float* __restrict__ in,
                                            const float* __restrict__ g,
                                            const float* __restrict__ b,
                                            float* __restrict__ out,
                                            __hip_bfloat16* __restrict__ obf) {
    int wv = threadIdx.x >> 6, lane = threadIdx.x & 63;
    int t = blockIdx.x * 4 + wv;
    const float* row = in + (size_t)t * CDIM;
    float x0 = row[lane], x1 = row[lane + 64], x2 = row[lane + 128];
    float s = x0 + x1 + x2;
    for (int o = 32; o; o >>= 1) s += __shfl_xor(s, o);
    float m = s * (1.0f / 192.0f);
    float d0 = x0 - m, d1 = x1 - m, d2 = x2 - m;
    float vv = d0 * d0 + d1 * d1 + d2 * d2;
    for (int o = 32; o; o >>= 1) vv += __shfl_xor(vv, o);
    float inv = rsqrtf(vv * (1.0f / 192.0f) + 1e-5f);
    size_t base = (size_t)t * CDIM;
    float y0 = d0 * inv * g[lane]       + b[lane];
    float y1 = d1 * inv * g[lane + 64]  + b[lane + 64];
    float y2 = d2 * inv * g[lane + 128] + b[lane + 128];
    out[base + lane]       = y0;
    out[base + lane + 64]  = y1;
    out[base + lane + 128] = y2;
    if (obf) {
        obf[base + lane]       = __float2bfloat16(y0);
        obf[base + lane + 64]  = __float2bfloat16(y1);
        obf[base + lane + 128] = __float2bfloat16(y2);
    }
}

// ---------------- generic matrix transpose ----------------
__global__ void k_mtrans(const float* __restrict__ in, float* __restrict__ out,
                         int R, int C) {
    int i = blockIdx.x * 256 + threadIdx.x;
    if (i >= R * C) return;
    int r = i % R, c = i / R;
    out[i] = in[(size_t)r * C + c];
}

// ---------------- conv weight prep (MFMA B-fragment order, bf16) ----------------
// w1p[((kk*12+cg)*2+h)*512 + oc*8 + j] = c1w[oc][cg*16+h*8+j][kk]
__global__ void k_wp1(const float* __restrict__ w, __hip_bfloat16* __restrict__ wp) {
    int i = blockIdx.x * 256 + threadIdx.x;
    if (i >= 331776) return;
    int j = i & 7, oc = (i >> 3) & 63, h = (i >> 9) & 1;
    int cg = (i >> 10) % 12, kk = i / 12288;
    int c = cg * 16 + h * 8 + j;
    wp[i] = __float2bfloat16(w[((size_t)oc * 192 + c) * 27 + kk]);
}
// w2p[((kk*4+cg)*2+h)*1536 + oc*8 + j] = c2w[oc][cg*16+h*8+j][kk]
__global__ void k_wp2(const float* __restrict__ w, __hip_bfloat16* __restrict__ wp) {
    int i = blockIdx.x * 256 + threadIdx.x;
    if (i >= 331776) return;
    int j = i & 7, oc = (i >> 3) % 192;
    int h = (i / 1536) & 1, cg = (i / 3072) & 3, kk = i / 12288;
    int c = cg * 16 + h * 8 + j;
    wp[i] = __float2bfloat16(w[((size_t)oc * 64 + c) * 27 + kk]);
}

// ---------------- bias precompute: biasT[h][m][n] = rpb[rpi[n][m]*6+h] ----------------
__global__ __launch_bounds__(256) void k_bias(const int* __restrict__ rpi,
                                              const float* __restrict__ rpb,
                                              float* __restrict__ biasT) {
    __shared__ int idxl[64][64];
    int tid = threadIdx.x;
    int n0 = (blockIdx.x >> 3) * 64, m0 = (blockIdx.x & 7) * 64;
    for (int it = 0; it < 16; it++) {
        int e = it * 256 + tid;
        int ln_ = e >> 6, lm = e & 63;
        idxl[ln_][lm] = rpi[(size_t)(n0 + ln_) * NTOKW + m0 + lm];
    }
    __syncthreads();
    for (int it = 0; it < 16; it++) {
        int e = it * 256 + tid;
        int lm = e >> 6, ln_ = e & 63;
        int id = idxl[ln_][lm];
        #pragma unroll
        for (int h = 0; h < NHEAD; h++)
            biasT[(size_t)h * NTOKW * NTOKW + (size_t)(m0 + lm) * NTOKW + n0 + ln_] =
                rpb[id * NHEAD + h];
    }
}

// ---------------- conv1 MFMA: xnbf[t][192] -> gelu -> h1bf[t][64] ----------------
// block = one W-row (64 tokens) x 64 oc; 4 waves (2x2 of 32x32).
__global__ __launch_bounds__(256) void k_conv1m(const __hip_bfloat16* __restrict__ xnbf,
                                                const __hip_bfloat16* __restrict__ w1p,
                                                const float* __restrict__ b1,
                                                __hip_bfloat16* __restrict__ h1bf) {
    __shared__ __align__(16) char lds[66 * 384];
    int tid = threadIdx.x;
    int wv = tid >> 6, lane = tid & 63;
    int wr = wv >> 1, wc = wv & 1;
    int half = lane >> 5, l31 = lane & 31;
    int row = blockIdx.x;                 // 0..511
    int d = row >> 6, hh = row & 63;

    // zero halo rows 0 and 65 (once; stages never touch them)
    if (tid < 48) {
        float4 z = {0.f, 0.f, 0.f, 0.f};
        char* p = lds + ((tid < 24) ? tid * 16 : 65 * 384 + (tid - 24) * 16);
        *(float4*)p = z;
    }

    f32x16 acc;
    #pragma unroll
    for (int r = 0; r < 16; r++) acc[r] = 0.f;

    for (int kd = -1; kd <= 1; kd++) {
        int dd = d + kd;
        if (dd < 0 || dd >= DD_) continue;            // block-uniform
        for (int kh = -1; kh <= 1; kh++) {
            int h2 = hh + kh;
            if (h2 < 0 || h2 >= HH_) continue;        // block-uniform
            const short* src = (const short*)xnbf + ((size_t)((dd << 12) | (h2 << 6))) * CDIM;
            __syncthreads();
            #pragma unroll
            for (int it = 0; it < 6; it++) {
                int e16 = it * 256 + tid;             // 16B chunk id, 1536 total
                int tok = e16 / 24, cb = (e16 % 24) * 16;
                short8v vdat = *(const short8v*)(src + e16 * 8);
                int lrow = tok + 1;
                *(short8v*)(lds + lrow * 384 + (cb ^ ((lrow & 7) << 4))) = vdat;
            }
            __syncthreads();
            #pragma unroll
            for (int kw = -1; kw <= 1; kw++) {
                int kk = (kd + 1) * 9 + (kh + 1) * 3 + (kw + 1);
                int atok = 32 * wr + l31 + kw + 1;    // LDS row 0..65
                int akey = (atok & 7) << 4;
                const char* abase = lds + atok * 384;
                const short* wbase = (const short*)w1p + (kk * 24 + half) * 512 + (32 * wc + l31) * 8;
                #pragma unroll
                for (int cg = 0; cg < 12; cg++) {
                    short8v af = *(const short8v*)(abase + ((cg * 32 + half * 16) ^ akey));
                    short8v bf = *(const short8v*)(wbase + cg * 1024);
                    acc = __builtin_amdgcn_mfma_f32_32x32x16_bf16(af, bf, acc, 0, 0, 0);
                }
            }
        }
    }
    int oc = 32 * wc + l31;
    float bb = b1[oc];
    int t0 = row * 64;
    #pragma unroll
    for (int r = 0; r < 16; r++) {
        int tok = 32 * wr + (r & 3) + 8 * (r >> 2) + 4 * half;
        h1bf[(size_t)(t0 + tok) * C3 + oc] = __float2bfloat16(gelu_exact(acc[r] + bb));
    }
}

// ---------------- conv2 MFMA: h1bf[t][64] -> h2[t][192] (+bias, f32) ----------------
// block = 32 tokens x 192 oc; 6 waves (1x6 of 32x32).
__global__ __launch_bounds__(384) void k_conv2m(const __hip_bfloat16* __restrict__ h1bf,
                                                const __hip_bfloat16* __restrict__ w2p,
                                                const float* __restrict__ b2,
                                                float* __restrict__ h2) {
    __shared__ __align__(16) char lds[34 * 128];
    int tid = threadIdx.x;
    int wv = tid >> 6, lane = tid & 63;
    int half = lane >> 5, l31 = lane & 31;
    int row = blockIdx.x >> 1, hr = blockIdx.x & 1;
    int d = row >> 6, hh = row & 63;

    f32x16 acc;
    #pragma unroll
    for (int r = 0; r < 16; r++) acc[r] = 0.f;

    for (int kd = -1; kd <= 1; kd++) {
        int dd = d + kd;
        if (dd < 0 || dd >= DD_) continue;
        for (int kh = -1; kh <= 1; kh++) {
            int h2r = hh + kh;
            if (h2r < 0 || h2r >= HH_) continue;
            __syncthreads();
            if (tid < 272) {                          // 34 rows x 8 chunks
                int ti = tid >> 3, cb = (tid & 7) * 16;
                int w = hr * 32 + ti - 1;
                short8v vdat = {0, 0, 0, 0, 0, 0, 0, 0};
                if (w >= 0 && w < 64)
                    vdat = *(const short8v*)((const short*)h1bf +
                           (size_t)((dd << 12) | (h2r << 6) | w) * C3 + cb / 2);
                *(short8v*)(lds + ti * 128 + (cb ^ ((ti & 7) << 4))) = vdat;
            }
            __syncthreads();
            #pragma unroll
            for (int kw = -1; kw <= 1; kw++) {
                int kk = (kd + 1) * 9 + (kh + 1) * 3 + (kw + 1);
                int atok = l31 + kw + 1;              // LDS row 0..33
                int akey = (atok & 7) << 4;
                const char* abase = lds + atok * 128;
                const short* wbase = (const short*)w2p + (kk * 8 + half) * 1536 + (wv * 32 + l31) * 8;
                #pragma unroll
                for (int cg = 0; cg < 4; cg++) {
                    short8v af = *(const short8v*)(abase + ((cg * 32 + half * 16) ^ akey));
                    short8v bf = *(const short8v*)(wbase + cg * 3072);
                    acc = __builtin_amdgcn_mfma_f32_32x32x16_bf16(af, bf, acc, 0, 0, 0);
                }
            }
        }
    }
    int oc = wv * 32 + l31;
    float bb = b2[oc];
    int t0 = row * 64 + hr * 32;
    #pragma unroll
    for (int r = 0; r < 16; r++) {
        int tok = (r & 3) + 8 * (r >> 2) + 4 * half;
        h2[(size_t)(t0 + tok) * CDIM + oc] = acc[r] + bb;
    }
}

// ---------------- pooled partial sums ----------------
__global__ __launch_bounds__(192) void k_pool(const float* __restrict__ h2,
                                              float* __restrict__ part) {
    int c = threadIdx.x, b = blockIdx.x;
    float s = 0.f;
    for (int i = 0; i < 128; i++) s += h2[(size_t)(b * 128 + i) * CDIM + c];
    part[b * CDIM + c] = s;
}

// ---------------- channel attention MLP -> amask[192] ----------------
__global__ __launch_bounds__(192) void k_ca(const float* __restrict__ part,
                                            const float* __restrict__ ca1w,
                                            const float* __restrict__ ca1b,
                                            const float* __restrict__ ca2w,
                                            const float* __restrict__ ca2b,
                                            float* __restrict__ amask) {
    __shared__ float pooled[CDIM];
    __shared__ float hid[6];
    int c = threadIdx.x;
    float s = 0.f;
    for (int b = 0; b < 256; b++) s += part[b * CDIM + c];
    pooled[c] = s * (1.0f / 32768.0f);
    __syncthreads();
    if (c < 6) {
        float a = ca1b[c];
        for (int j = 0; j < CDIM; j++) a += ca1w[c * CDIM + j] * pooled[j];
        hid[c] = fmaxf(a, 0.f);
    }
    __syncthreads();
    float a = ca2b[c];
    for (int j = 0; j < 6; j++) a += ca2w[c * 6 + j] * hid[j];
    amask[c] = 1.0f / (1.0f + expf(-a));
}

// ---------------- qkv: windowed gather + GEMM row; outputs bf16, q scaled ----------------
__global__ __launch_bounds__(192) void k_qkv(const float* __restrict__ xn,
                                             const float* __restrict__ qkvT, // [192][576]
                                             const float* __restrict__ qkvb,
                                             __hip_bfloat16* __restrict__ q,
                                             __hip_bfloat16* __restrict__ k,
                                             __hip_bfloat16* __restrict__ v) {
    __shared__ float xr[4][CDIM];
    int tid = threadIdx.x;
    int wt0 = blockIdx.x * 4;
    int torig[4];
    for (int i = 0; i < 4; i++) {
        int wt = wt0 + i;
        int wi = wt >> 9, n = wt & 511;
        int wh = wi >> 3, ww = wi & 7;
        int nd = n >> 6, nh = (n >> 3) & 7, nw = n & 7;
        torig[i] = (nd << 12) | ((wh * 8 + nh) << 6) | (ww * 8 + nw);
    }
    for (int i = 0; i < 4; i++) xr[i][tid] = xn[(size_t)torig[i] * CDIM + tid];
    __syncthreads();
    float aq[4] = {0, 0, 0, 0}, ak[4] = {0, 0, 0, 0}, av[4] = {0, 0, 0, 0};
    for (int c = 0; c < CDIM; c++) {
        const float* wrow = qkvT + (size_t)c * 576;
        float wq = wrow[tid], wk = wrow[192 + tid], wv = wrow[384 + tid];
        for (int i = 0; i < 4; i++) {
            float xv = xr[i][c];
            aq[i] += wq * xv; ak[i] += wk * xv; av[i] += wv * xv;
        }
    }
    int head = tid >> 5, dd = tid & 31;
    float bq = qkvb[tid], bk = qkvb[192 + tid], bv = qkvb[384 + tid];
    for (int i = 0; i < 4; i++) {
        int wt = wt0 + i; int wi = wt >> 9, n = wt & 511;
        size_t base = ((size_t)(wi * NHEAD + head) * NTOKW + n) * HDIM + dd;
        q[base] = __float2bfloat16((aq[i] + bq) * 0.17677669529663687f);
        k[base] = __float2bfloat16(ak[i] + bk);
        v[base] = __float2bfloat16(av[i] + bv);
    }
}

// ---------------- MFMA flash attention ----------------
__global__ __launch_bounds__(256) void k_attn(const __hip_bfloat16* __restrict__ qh,
                                              const __hip_bfloat16* __restrict__ kh,
                                              const __hip_bfloat16* __restrict__ vh,
                                              const float* __restrict__ biasT,
                                              float* __restrict__ out) {
    __shared__ float ot[4][32][33];
    int wv = threadIdx.x >> 6, lane = threadIdx.x & 63;
    int tile = blockIdx.x * 4 + wv;          // 6144 tiles
    int qt = tile & 15, wh = tile >> 4;      // qt 0..15, wh 0..383
    int head = wh % NHEAD, wi = wh / NHEAD;
    int qb = qt * 32;
    int h = lane >> 5, ln31 = lane & 31;

    const unsigned short* qp = (const unsigned short*)qh + ((size_t)wh * NTOKW + qb + ln31) * HDIM;
    short8v qf0 = *(const short8v*)(qp + 8 * h);
    short8v qf1 = *(const short8v*)(qp + 16 + 8 * h);
    const unsigned short* kbase = (const unsigned short*)kh + (size_t)wh * NTOKW * HDIM;
    const unsigned short* vbase = (const unsigned short*)vh + (size_t)wh * NTOKW * HDIM;
    const float* bbase = biasT + (size_t)head * NTOKW * NTOKW + qb + ln31;

    f32x16 O;
    #pragma unroll
    for (int r = 0; r < 16; r++) O[r] = 0.f;
    float m = -1e30f, l = 0.f;

    for (int kb = 0; kb < NTOKW; kb += 32) {
        const unsigned short* kp = kbase + (size_t)(kb + ln31) * HDIM;
        short8v kf0 = *(const short8v*)(kp + 8 * h);
        short8v kf1 = *(const short8v*)(kp + 16 + 8 * h);
        f32x16 S;
        #pragma unroll
        for (int r = 0; r < 16; r++) S[r] = 0.f;
        S = __builtin_amdgcn_mfma_f32_32x32x16_bf16(kf0, qf0, S, 0, 0, 0);
        S = __builtin_amdgcn_mfma_f32_32x32x16_bf16(kf1, qf1, S, 0, 0, 0);

        float s[16];
        #pragma unroll
        for (int r = 0; r < 16; r++) {
            int key = (r & 3) + 8 * (r >> 2) + 4 * h;
            s[r] = S[r] + bbase[(size_t)(kb + key) * NTOKW];
        }
        float cm = s[0];
        #pragma unroll
        for (int r = 1; r < 16; r++) cm = fmaxf(cm, s[r]);
        cm = fmaxf(cm, __shfl_xor(cm, 32));
        float mn = fmaxf(m, cm);
        float scale = __expf(m - mn);
        float e[16]; float cs = 0.f;
        #pragma unroll
        for (int r = 0; r < 16; r++) { e[r] = __expf(s[r] - mn); cs += e[r]; }
        cs += __shfl_xor(cs, 32);
        l = l * scale + cs;
        m = mn;
        #pragma unroll
        for (int r = 0; r < 16; r++) O[r] *= scale;

        unsigned P[8], Qx[8];
        #pragma unroll
        for (int i = 0; i < 8; i++)
            P[i] = (unsigned)bf16bits(e[2 * i]) | ((unsigned)bf16bits(e[2 * i + 1]) << 16);
        #pragma unroll
        for (int i = 0; i < 8; i++) Qx[i] = __shfl_xor(P[i], 32);

        FragU p0, p1;
        p0.u[0] = h ? Qx[2] : P[0];  p0.u[1] = h ? Qx[3] : P[1];
        p0.u[2] = h ? P[2]  : Qx[0]; p0.u[3] = h ? P[3]  : Qx[1];
        p1.u[0] = h ? Qx[6] : P[4];  p1.u[1] = h ? Qx[7] : P[5];
        p1.u[2] = h ? P[6]  : Qx[4]; p1.u[3] = h ? P[7]  : Qx[5];

        const unsigned short* vp0 = vbase + (size_t)(kb + 8 * h) * HDIM + ln31;
        const unsigned short* vp1 = vbase + (size_t)(kb + 16 + 8 * h) * HDIM + ln31;
        short8v vf0, vf1;
        #pragma unroll
        for (int i = 0; i < 8; i++) {
            vf0[i] = (short)vp0[i * HDIM];
            vf1[i] = (short)vp1[i * HDIM];
        }
        O = __builtin_amdgcn_mfma_f32_32x32x16_bf16(vf0, p0.v, O, 0, 0, 0);
        O = __builtin_amdgcn_mfma_f32_32x32x16_bf16(vf1, p1.v, O, 0, 0, 0);
    }

    float invl = 1.0f / l;
    #pragma unroll
    for (int r = 0; r < 16; r++) {
        int d = (r & 3) + 8 * (r >> 2) + 4 * h;
        ot[wv][ln31][d] = O[r] * invl;
    }
    __syncthreads();
    int t2 = lane >> 1, c0 = (lane & 1) * 16;
    float* outp = out + ((size_t)(wi * NTOKW + qb + t2)) * CDIM + head * HDIM + c0;
    #pragma unroll
    for (int i = 0; i < 16; i++) outp[i] = ot[wv][t2][c0 + i];
}

// ---------------- proj + residual + conv branch merge -> x2 (in d_out) ----------------
__global__ __launch_bounds__(192) void k_proj(const float* __restrict__ ao,
                                              const float* __restrict__ projT,
                                              const float* __restrict__ pb,
                                              const float* __restrict__ x,
                                              const float* __restrict__ h2,
                                              const float* __restrict__ amask,
                                              float* __restrict__ x2) {
    __shared__ float ar[4][CDIM];
    int tid = threadIdx.x;
    int wt0 = blockIdx.x * 4;
    for (int i = 0; i < 4; i++) ar[i][tid] = ao[(size_t)(wt0 + i) * CDIM + tid];
    __syncthreads();
    float acc[4] = {0, 0, 0, 0};
    for (int c = 0; c < CDIM; c++) {
        float w = projT[(size_t)c * CDIM + tid];
        for (int i = 0; i < 4; i++) acc[i] += w * ar[i][c];
    }
    float bb = pb[tid], am = amask[tid];
    for (int i = 0; i < 4; i++) {
        int wt = wt0 + i; int wi = wt >> 9, n = wt & 511;
        int wh = wi >> 3, ww = wi & 7;
        int nd = n >> 6, nh = (n >> 3) & 7, nw = n & 7;
        int t = (nd << 12) | ((wh * 8 + nh) << 6) | (ww * 8 + nw);
        size_t idx = (size_t)t * CDIM + tid;
        x2[idx] = x[idx] + acc[i] + bb + 0.01f * h2[idx] * am;
    }
}

// ---------------- fused MLP ----------------
__global__ __launch_bounds__(256) void k_mlp(const float* __restrict__ y,
                                             const float* __restrict__ w1T,
                                             const float* __restrict__ b1,
                                             const float* __restrict__ w2T,
                                             const float* __restrict__ b2,
                                             float* __restrict__ out) {
    __shared__ float yr[8][CDIM];
    __shared__ float hr[8][FCH];
    int tid = threadIdx.x;
    int t0 = blockIdx.x * 8;
    for (int i = tid; i < 8 * CDIM; i += 256) {
        int r = i / CDIM, c = i % CDIM;
        yr[r][c] = y[(size_t)(t0 + r) * CDIM + c];
    }
    __syncthreads();
    {
        float a[3][8];
        for (int jj = 0; jj < 3; jj++)
            for (int r = 0; r < 8; r++) a[jj][r] = 0.f;
        for (int c0 = 0; c0 < CDIM; c0 += 4) {
            float4 yv[8];
            #pragma unroll
            for (int r = 0; r < 8; r++) yv[r] = *(const float4*)&yr[r][c0];
            #pragma unroll
            for (int jj = 0; jj < 3; jj++) {
                int j = tid + jj * 256;
                float w0 = w1T[(size_t)(c0 + 0) * FCH + j];
                float w1 = w1T[(size_t)(c0 + 1) * FCH + j];
                float w2 = w1T[(size_t)(c0 + 2) * FCH + j];
                float w3 = w1T[(size_t)(c0 + 3) * FCH + j];
                #pragma unroll
                for (int r = 0; r < 8; r++)
                    a[jj][r] += w0 * yv[r].x + w1 * yv[r].y + w2 * yv[r].z + w3 * yv[r].w;
            }
        }
        for (int jj = 0; jj < 3; jj++) {
            int j = tid + jj * 256;
            float bb = b1[j];
            for (int r = 0; r < 8; r++) hr[r][j] = gelu_exact(a[jj][r] + bb);
        }
    }
    __syncthreads();
    if (tid < CDIM) {
        float a[8] = {0, 0, 0, 0, 0, 0, 0, 0};
        for (int c0 = 0; c0 < FCH; c0 += 4) {
            float4 hv[8];
            #pragma unroll
            for (int r = 0; r < 8; r++) hv[r] = *(const float4*)&hr[r][c0];
            float w0 = w2T[(size_t)(c0 + 0) * CDIM + tid];
            float w1 = w2T[(size_t)(c0 + 1) * CDIM + tid];
            float w2 = w2T[(size_t)(c0 + 2) * CDIM + tid];
            float w3 = w2T[(size_t)(c0 + 3) * CDIM + tid];
            #pragma unroll
            for (int r = 0; r < 8; r++)
                a[r] += w0 * hv[r].x + w1 * hv[r].y + w2 * hv[r].z + w3 * hv[r].w;
        }
        float bb = b2[tid];
        for (int r = 0; r < 8; r++) {
            size_t idx = (size_t)(t0 + r) * CDIM + tid;
            out[idx] = out[idx] + a[r] + bb;
        }
    }
}

// ---------------- launcher ----------------
extern "C" void kernel_launch(void* const* d_in, const int* in_sizes, int n_in,
                              void* d_out, int out_size, void* d_ws, size_t ws_size,
                              hipStream_t stream) {
    const float* x     = (const float*)d_in[0];
    const float* n1g   = (const float*)d_in[1];
    const float* n1b   = (const float*)d_in[2];
    const float* qkvw  = (const float*)d_in[3];
    const float* qkvb  = (const float*)d_in[4];
    const float* rpb   = (const float*)d_in[5];
    const float* projw = (const float*)d_in[6];
    const float* projb = (const float*)d_in[7];
    const float* c1w   = (const float*)d_in[8];
    const float* c1b   = (const float*)d_in[9];
    const float* c2w   = (const float*)d_in[10];
    const float* c2b   = (const float*)d_in[11];
    const float* ca1w  = (const float*)d_in[12];
    const float* ca1b  = (const float*)d_in[13];
    const float* ca2w  = (const float*)d_in[14];
    const float* ca2b  = (const float*)d_in[15];
    const float* n2g   = (const float*)d_in[16];
    const float* n2b   = (const float*)d_in[17];
    const float* fc1w  = (const float*)d_in[18];
    const float* fc1b  = (const float*)d_in[19];
    const float* fc2w  = (const float*)d_in[20];
    const float* fc2b  = (const float*)d_in[21];
    const int*   rpi   = (const int*)d_in[22];

    float* ws  = (float*)d_ws;
    float* out = (float*)d_out;

    float* xn    = ws + OFF_XN;
    __hip_bfloat16* qh  = (__hip_bfloat16*)(ws + OFF_QH);
    __hip_bfloat16* kb_ = (__hip_bfloat16*)(ws + OFF_KH);
    __hip_bfloat16* vb_ = (__hip_bfloat16*)(ws + OFF_VH);
    __hip_bfloat16* xnbf = (__hip_bfloat16*)(ws + OFF_Y);   // dead before LN2 writes y here
    float* y     = ws + OFF_Y;
    __hip_bfloat16* h1bf = (__hip_bfloat16*)(ws + OFF_H1);
    float* h2    = ws + OFF_H2;
    float* part  = ws + OFF_PART;
    float* amask = ws + OFF_AMASK;
    float* biasT = ws + OFF_BIAST;
    __hip_bfloat16* w1p = (__hip_bfloat16*)(ws + OFF_W1T);
    __hip_bfloat16* w2p = (__hip_bfloat16*)(ws + OFF_W2T);
    float* qkvT  = ws + OFF_QKVT;
    float* projT = ws + OFF_PROJT;
    float* fc1T  = ws + OFF_FC1T;
    float* fc2T  = ws + OFF_FC2T;
    float* attn  = ws + OFF_XN;   // reuse: xn dead after k_qkv

    // weight prep + bias table (independent)
    k_wp1<<<(331776 + 255) / 256, 256, 0, stream>>>(c1w, w1p);
    k_wp2<<<(331776 + 255) / 256, 256, 0, stream>>>(c2w, w2p);
    k_mtrans<<<(576 * 192 + 255) / 256, 256, 0, stream>>>(qkvw, qkvT, 576, 192);
    k_mtrans<<<(192 * 192 + 255) / 256, 256, 0, stream>>>(projw, projT, 192, 192);
    k_mtrans<<<(768 * 192 + 255) / 256, 256, 0, stream>>>(fc1w, fc1T, 768, 192);
    k_mtrans<<<(192 * 768 + 255) / 256, 256, 0, stream>>>(fc2w, fc2T, 192, 768);
    k_bias<<<64, 256, 0, stream>>>(rpi, rpb, biasT);

    // LN1 (f32 + bf16)
    k_ln<<<LTOK / 4, 256, 0, stream>>>(x, n1g, n1b, xn, xnbf);
    // conv branch (MFMA)
    k_conv1m<<<512, 256, 0, stream>>>(xnbf, w1p, c1b, h1bf);
    k_conv2m<<<1024, 384, 0, stream>>>(h1bf, w2p, c2b, h2);
    k_pool<<<256, 192, 0, stream>>>(h2, part);
    k_ca<<<1, 192, 0, stream>>>(part, ca1w, ca1b, ca2w, ca2b, amask);
    // attention branch
    k_qkv<<<LTOK / 4, 192, 0, stream>>>(xn, qkvT, qkvb, qh, kb_, vb_);
    k_attn<<<(NWIN * NHEAD * 16) / 4, 256, 0, stream>>>(qh, kb_, vb_, biasT, attn);
    k_proj<<<LTOK / 4, 192, 0, stream>>>(attn, projT, projb, x, h2, amask, out);
    // LN2 + MLP
    k_ln<<<LTOK / 4, 256, 0, stream>>>(out, n2g, n2b, y, (__hip_bfloat16*)nullptr);
    k_mlp<<<LTOK / 8, 256, 0, stream>>>(y, fc1T, fc1b, fc2T, fc2b, out);
}

// Round 6
// 498.361 us; speedup vs baseline: 14.1603x; 1.7957x over previous
//
#include <hip/hip_runtime.h>
#include <hip/hip_bf16.h>

// ---------------- problem constants ----------------
#define LTOK  32768   // D*H*W
#define CDIM  192
#define DD_   8
#define HH_   64
#define WW_   64
#define NHEAD 6
#define HDIM  32
#define NWIN  64      // (D/8)*(H/8)*(W/8)
#define NTOKW 512     // tokens per window
#define C3    64      // C/3
#define FCH   768     // 4*C

// ws layout (float32-slot offsets)
#define OFF_XN     0u          // 6291456  (attn-out f32)
#define OFF_QH     6291456u    // bf16 q
#define OFF_KH     9437184u    // bf16 k
#define OFF_VH     12582912u   // bf16 v
#define OFF_Y      15728640u   // xnbf (bf16, 3145728 slots)
#define OFF_YBF    18874368u   // ybf  (bf16, 3145728 slots)
#define OFF_H1     22020096u   // h1 bf16
#define OFF_H2     24117248u   // h2 f32
#define OFF_PART   30408704u
#define OFF_AMASK  30457856u
#define OFF_BIAST  30458048u   // 6*512*512 f32
#define OFF_W1T    32030912u   // conv1 prepped bf16
#define OFF_W2T    32362688u   // conv2 prepped bf16
#define OFF_QKVT   32694464u   // qkv weight bf16 (55296 slots)
#define OFF_PROJT  32805056u   // proj f32 transpose
#define OFF_FC1T   32841920u   // fc1 weight bf16 (73728 slots)
#define OFF_FC2T   32989376u   // fc2 weight bf16 (73728 slots)

typedef __attribute__((ext_vector_type(8)))  short short8v;
typedef __attribute__((ext_vector_type(16))) float f32x16;

union FragU { short8v v; unsigned u[4]; };

__device__ __forceinline__ float gelu_exact(float x) {
    return 0.5f * x * (1.0f + erff(x * 0.70710678118654752f));
}

__device__ __forceinline__ unsigned short bf16bits(float x) {
    union { __hip_bfloat16 b; unsigned short u; } cv;
    cv.b = __float2bfloat16(x);
    return cv.u;
}

// ---------------- LayerNorm: 1 wave per token; f32 and/or bf16 out ----------------
__global__ __launch_bounds__(256) void k_ln(const float* __restrict__ in,
                                            const float* __restrict__ g,
                                            const float* __restrict__ b,
                                            float* __restrict__ out,
                                            __hip_bfloat16* __restrict__ obf) {
    int wv = threadIdx.x >> 6, lane = threadIdx.x & 63;
    int t = blockIdx.x * 4 + wv;
    const float* row = in + (size_t)t * CDIM;
    float x0 = row[lane], x1 = row[lane + 64], x2 = row[lane + 128];
    float s = x0 + x1 + x2;
    for (int o = 32; o; o >>= 1) s += __shfl_xor(s, o);
    float m = s * (1.0f / 192.0f);
    float d0 = x0 - m, d1 = x1 - m, d2 = x2 - m;
    float vv = d0 * d0 + d1 * d1 + d2 * d2;
    for (int o = 32; o; o >>= 1) vv += __shfl_xor(vv, o);
    float inv = rsqrtf(vv * (1.0f / 192.0f) + 1e-5f);
    size_t base = (size_t)t * CDIM;
    float y0 = d0 * inv * g[lane]       + b[lane];
    float y1 = d1 * inv * g[lane + 64]  + b[lane + 64];
    float y2 = d2 * inv * g[lane + 128] + b[lane + 128];
    if (out) {
        out[base + lane]       = y0;
        out[base + lane + 64]  = y1;
        out[base + lane + 128] = y2;
    }
    if (obf) {
        obf[base + lane]       = __float2bfloat16(y0);
        obf[base + lane + 64]  = __float2bfloat16(y1);
        obf[base + lane + 128] = __float2bfloat16(y2);
    }
}

// ---------------- generic matrix transpose (f32) ----------------
__global__ void k_mtrans(const float* __restrict__ in, float* __restrict__ out,
                         int R, int C) {
    int i = blockIdx.x * 256 + threadIdx.x;
    if (i >= R * C) return;
    int r = i % R, c = i / R;
    out[i] = in[(size_t)r * C + c];
}

// ---------------- f32 -> bf16 cast ----------------
__global__ void k_cast(const float* __restrict__ in, __hip_bfloat16* __restrict__ out, int n) {
    int i = blockIdx.x * 256 + threadIdx.x;
    if (i < n) out[i] = __float2bfloat16(in[i]);
}

// ---------------- conv weight prep (MFMA B-fragment order, bf16) ----------------
__global__ void k_wp1(const float* __restrict__ w, __hip_bfloat16* __restrict__ wp) {
    int i = blockIdx.x * 256 + threadIdx.x;
    if (i >= 331776) return;
    int j = i & 7, oc = (i >> 3) & 63, h = (i >> 9) & 1;
    int cg = (i >> 10) % 12, kk = i / 12288;
    int c = cg * 16 + h * 8 + j;
    wp[i] = __float2bfloat16(w[((size_t)oc * 192 + c) * 27 + kk]);
}
__global__ void k_wp2(const float* __restrict__ w, __hip_bfloat16* __restrict__ wp) {
    int i = blockIdx.x * 256 + threadIdx.x;
    if (i >= 331776) return;
    int j = i & 7, oc = (i >> 3) % 192;
    int h = (i / 1536) & 1, cg = (i / 3072) & 3, kk = i / 12288;
    int c = cg * 16 + h * 8 + j;
    wp[i] = __float2bfloat16(w[((size_t)oc * 64 + c) * 27 + kk]);
}

// ---------------- bias precompute: biasT[h][m][n] = rpb[rpi[n][m]*6+h] ----------------
__global__ __launch_bounds__(256) void k_bias(const int* __restrict__ rpi,
                                              const float* __restrict__ rpb,
                                              float* __restrict__ biasT) {
    __shared__ int idxl[64][64];
    int tid = threadIdx.x;
    int n0 = (blockIdx.x >> 3) * 64, m0 = (blockIdx.x & 7) * 64;
    for (int it = 0; it < 16; it++) {
        int e = it * 256 + tid;
        int ln_ = e >> 6, lm = e & 63;
        idxl[ln_][lm] = rpi[(size_t)(n0 + ln_) * NTOKW + m0 + lm];
    }
    __syncthreads();
    for (int it = 0; it < 16; it++) {
        int e = it * 256 + tid;
        int lm = e >> 6, ln_ = e & 63;
        int id = idxl[ln_][lm];
        #pragma unroll
        for (int h = 0; h < NHEAD; h++)
            biasT[(size_t)h * NTOKW * NTOKW + (size_t)(m0 + lm) * NTOKW + n0 + ln_] =
                rpb[id * NHEAD + h];
    }
}

// ---------------- conv1 MFMA ----------------
__global__ __launch_bounds__(256) void k_conv1m(const __hip_bfloat16* __restrict__ xnbf,
                                                const __hip_bfloat16* __restrict__ w1p,
                                                const float* __restrict__ b1,
                                                __hip_bfloat16* __restrict__ h1bf) {
    __shared__ __align__(16) char lds[66 * 384];
    int tid = threadIdx.x;
    int wv = tid >> 6, lane = tid & 63;
    int wr = wv >> 1, wc = wv & 1;
    int half = lane >> 5, l31 = lane & 31;
    int row = blockIdx.x;
    int d = row >> 6, hh = row & 63;

    if (tid < 48) {
        float4 z = {0.f, 0.f, 0.f, 0.f};
        char* p = lds + ((tid < 24) ? tid * 16 : 65 * 384 + (tid - 24) * 16);
        *(float4*)p = z;
    }

    f32x16 acc;
    #pragma unroll
    for (int r = 0; r < 16; r++) acc[r] = 0.f;

    for (int kd = -1; kd <= 1; kd++) {
        int dd = d + kd;
        if (dd < 0 || dd >= DD_) continue;
        for (int kh = -1; kh <= 1; kh++) {
            int h2 = hh + kh;
            if (h2 < 0 || h2 >= HH_) continue;
            const short* src = (const short*)xnbf + ((size_t)((dd << 12) | (h2 << 6))) * CDIM;
            __syncthreads();
            #pragma unroll
            for (int it = 0; it < 6; it++) {
                int e16 = it * 256 + tid;
                int tok = e16 / 24, cb = (e16 % 24) * 16;
                short8v vdat = *(const short8v*)(src + e16 * 8);
                int lrow = tok + 1;
                *(short8v*)(lds + lrow * 384 + (cb ^ ((lrow & 7) << 4))) = vdat;
            }
            __syncthreads();
            #pragma unroll
            for (int kw = -1; kw <= 1; kw++) {
                int kk = (kd + 1) * 9 + (kh + 1) * 3 + (kw + 1);
                int atok = 32 * wr + l31 + kw + 1;
                int akey = (atok & 7) << 4;
                const char* abase = lds + atok * 384;
                const short* wbase = (const short*)w1p + (kk * 24 + half) * 512 + (32 * wc + l31) * 8;
                #pragma unroll
                for (int cg = 0; cg < 12; cg++) {
                    short8v af = *(const short8v*)(abase + ((cg * 32 + half * 16) ^ akey));
                    short8v bf = *(const short8v*)(wbase + cg * 1024);
                    acc = __builtin_amdgcn_mfma_f32_32x32x16_bf16(af, bf, acc, 0, 0, 0);
                }
            }
        }
    }
    int oc = 32 * wc + l31;
    float bb = b1[oc];
    int t0 = row * 64;
    #pragma unroll
    for (int r = 0; r < 16; r++) {
        int tok = 32 * wr + (r & 3) + 8 * (r >> 2) + 4 * half;
        h1bf[(size_t)(t0 + tok) * C3 + oc] = __float2bfloat16(gelu_exact(acc[r] + bb));
    }
}

// ---------------- conv2 MFMA ----------------
__global__ __launch_bounds__(384) void k_conv2m(const __hip_bfloat16* __restrict__ h1bf,
                                                const __hip_bfloat16* __restrict__ w2p,
                                                const float* __restrict__ b2,
                                                float* __restrict__ h2) {
    __shared__ __align__(16) char lds[34 * 128];
    int tid = threadIdx.x;
    int wv = tid >> 6, lane = tid & 63;
    int half = lane >> 5, l31 = lane & 31;
    int row = blockIdx.x >> 1, hr = blockIdx.x & 1;
    int d = row >> 6, hh = row & 63;

    f32x16 acc;
    #pragma unroll
    for (int r = 0; r < 16; r++) acc[r] = 0.f;

    for (int kd = -1; kd <= 1; kd++) {
        int dd = d + kd;
        if (dd < 0 || dd >= DD_) continue;
        for (int kh = -1; kh <= 1; kh++) {
            int h2r = hh + kh;
            if (h2r < 0 || h2r >= HH_) continue;
            __syncthreads();
            if (tid < 272) {
                int ti = tid >> 3, cb = (tid & 7) * 16;
                int w = hr * 32 + ti - 1;
                short8v vdat = {0, 0, 0, 0, 0, 0, 0, 0};
                if (w >= 0 && w < 64)
                    vdat = *(const short8v*)((const short*)h1bf +
                           (size_t)((dd << 12) | (h2r << 6) | w) * C3 + cb / 2);
                *(short8v*)(lds + ti * 128 + (cb ^ ((ti & 7) << 4))) = vdat;
            }
            __syncthreads();
            #pragma unroll
            for (int kw = -1; kw <= 1; kw++) {
                int kk = (kd + 1) * 9 + (kh + 1) * 3 + (kw + 1);
                int atok = l31 + kw + 1;
                int akey = (atok & 7) << 4;
                const char* abase = lds + atok * 128;
                const short* wbase = (const short*)w2p + (kk * 8 + half) * 1536 + (wv * 32 + l31) * 8;
                #pragma unroll
                for (int cg = 0; cg < 4; cg++) {
                    short8v af = *(const short8v*)(abase + ((cg * 32 + half * 16) ^ akey));
                    short8v bf = *(const short8v*)(wbase + cg * 3072);
                    acc = __builtin_amdgcn_mfma_f32_32x32x16_bf16(af, bf, acc, 0, 0, 0);
                }
            }
        }
    }
    int oc = wv * 32 + l31;
    float bb = b2[oc];
    int t0 = row * 64 + hr * 32;
    #pragma unroll
    for (int r = 0; r < 16; r++) {
        int tok = (r & 3) + 8 * (r >> 2) + 4 * half;
        h2[(size_t)(t0 + tok) * CDIM + oc] = acc[r] + bb;
    }
}

// ---------------- pooled partial sums ----------------
__global__ __launch_bounds__(192) void k_pool(const float* __restrict__ h2,
                                              float* __restrict__ part) {
    int c = threadIdx.x, b = blockIdx.x;
    float s = 0.f;
    for (int i = 0; i < 128; i++) s += h2[(size_t)(b * 128 + i) * CDIM + c];
    part[b * CDIM + c] = s;
}

// ---------------- channel attention MLP -> amask[192] ----------------
__global__ __launch_bounds__(192) void k_ca(const float* __restrict__ part,
                                            const float* __restrict__ ca1w,
                                            const float* __restrict__ ca1b,
                                            const float* __restrict__ ca2w,
                                            const float* __restrict__ ca2b,
                                            float* __restrict__ amask) {
    __shared__ float pooled[CDIM];
    __shared__ float hid[6];
    int c = threadIdx.x;
    float s = 0.f;
    for (int b = 0; b < 256; b++) s += part[b * CDIM + c];
    pooled[c] = s * (1.0f / 32768.0f);
    __syncthreads();
    if (c < 6) {
        float a = ca1b[c];
        for (int j = 0; j < CDIM; j++) a += ca1w[c * CDIM + j] * pooled[j];
        hid[c] = fmaxf(a, 0.f);
    }
    __syncthreads();
    float a = ca2b[c];
    for (int j = 0; j < 6; j++) a += ca2w[c * 6 + j] * hid[j];
    amask[c] = 1.0f / (1.0f + expf(-a));
}

// ---------------- qkv MFMA: out^T = mfma(W rows=od, x^T cols=tok) ----------------
// block = 2 waves, 64 window-ordered tokens; 18 output tiles (type,head).
__global__ __launch_bounds__(128) void k_qkvm(const __hip_bfloat16* __restrict__ xnbf,
                                              const __hip_bfloat16* __restrict__ qwb, // [576][192] bf16
                                              const float* __restrict__ qkvb,
                                              __hip_bfloat16* __restrict__ q,
                                              __hip_bfloat16* __restrict__ k,
                                              __hip_bfloat16* __restrict__ v) {
    __shared__ __align__(16) char xlds[64 * 384];
    __shared__ float tb[2][32][33];
    int tid = threadIdx.x;
    int wv = tid >> 6, lane = tid & 63;
    int half = lane >> 5, l31 = lane & 31;
    int t0 = blockIdx.x * 64;            // window-token space
    int wi = t0 >> 9;                     // uniform
    int wh_ = wi >> 3, ww_ = wi & 7;

    // gather-stage xn rows (swizzled)
    #pragma unroll
    for (int it = 0; it < 12; it++) {
        int e16 = it * 128 + tid;         // 0..1535
        int tok = e16 / 24, cb = (e16 % 24) * 16;
        int n = (t0 + tok) & 511;
        int nd = n >> 6, nh = (n >> 3) & 7, nw = n & 7;
        int torig = (nd << 12) | ((wh_ * 8 + nh) << 6) | (ww_ * 8 + nw);
        short8v vdat = *(const short8v*)((const short*)xnbf + (size_t)torig * CDIM + (e16 % 24) * 8);
        *(short8v*)(xlds + tok * 384 + (cb ^ ((tok & 7) << 4))) = vdat;
    }
    __syncthreads();

    int myrow = wv * 32 + l31;
    int akey = (myrow & 7) << 4;
    const char* xbase = xlds + myrow * 384;

    for (int ti = 0; ti < 18; ti++) {
        f32x16 acc;
        #pragma unroll
        for (int r = 0; r < 16; r++) acc[r] = 0.f;
        const short* wbase = (const short*)qwb + (size_t)(ti * 32 + l31) * CDIM + half * 8;
        #pragma unroll
        for (int cg = 0; cg < 12; cg++) {
            short8v bf = *(const short8v*)(xbase + ((cg * 32 + half * 16) ^ akey));
            short8v af = *(const short8v*)(wbase + cg * 16);
            acc = __builtin_amdgcn_mfma_f32_32x32x16_bf16(af, bf, acc, 0, 0, 0);
        }
        // transpose via per-wave LDS (same-wave ordering via lgkmcnt)
        #pragma unroll
        for (int r = 0; r < 16; r++) {
            int dl = (r & 3) + 8 * (r >> 2) + 4 * half;
            tb[wv][l31][dl] = acc[r];
        }
        asm volatile("s_waitcnt lgkmcnt(0)" ::: "memory");
        __builtin_amdgcn_sched_barrier(0);
        int tok = lane >> 1, d0 = (lane & 1) * 16;
        int type = ti / 6, head = ti % 6;
        float scale = (type == 0) ? 0.17677669529663687f : 1.0f;
        int n = (t0 + wv * 32 + tok) & 511;
        __hip_bfloat16* dst = (type == 0 ? q : (type == 1 ? k : v)) +
                              ((size_t)((wi * NHEAD + head) * NTOKW + n)) * HDIM + d0;
        const float* bp = qkvb + ti * 32 + d0;
        short8v o0, o1;
        #pragma unroll
        for (int i = 0; i < 8; i++)
            o0[i] = (short)bf16bits((tb[wv][tok][d0 + i] + bp[i]) * scale);
        #pragma unroll
        for (int i = 0; i < 8; i++)
            o1[i] = (short)bf16bits((tb[wv][tok][d0 + 8 + i] + bp[8 + i]) * scale);
        *(short8v*)((short*)dst) = o0;
        *(short8v*)((short*)dst + 8) = o1;
        asm volatile("s_waitcnt lgkmcnt(0)" ::: "memory");
        __builtin_amdgcn_sched_barrier(0);
    }
}

// ---------------- MFMA flash attention ----------------
__global__ __launch_bounds__(256) void k_attn(const __hip_bfloat16* __restrict__ qh,
                                              const __hip_bfloat16* __restrict__ kh,
                                              const __hip_bfloat16* __restrict__ vh,
                                              const float* __restrict__ biasT,
                                              float* __restrict__ out) {
    __shared__ float ot[4][32][33];
    int wv = threadIdx.x >> 6, lane = threadIdx.x & 63;
    int tile = blockIdx.x * 4 + wv;
    int qt = tile & 15, wh = tile >> 4;
    int head = wh % NHEAD, wi = wh / NHEAD;
    int qb = qt * 32;
    int h = lane >> 5, ln31 = lane & 31;

    const unsigned short* qp = (const unsigned short*)qh + ((size_t)wh * NTOKW + qb + ln31) * HDIM;
    short8v qf0 = *(const short8v*)(qp + 8 * h);
    short8v qf1 = *(const short8v*)(qp + 16 + 8 * h);
    const unsigned short* kbase = (const unsigned short*)kh + (size_t)wh * NTOKW * HDIM;
    const unsigned short* vbase = (const unsigned short*)vh + (size_t)wh * NTOKW * HDIM;
    const float* bbase = biasT + (size_t)head * NTOKW * NTOKW + qb + ln31;

    f32x16 O;
    #pragma unroll
    for (int r = 0; r < 16; r++) O[r] = 0.f;
    float m = -1e30f, l = 0.f;

    for (int kb = 0; kb < NTOKW; kb += 32) {
        const unsigned short* kp = kbase + (size_t)(kb + ln31) * HDIM;
        short8v kf0 = *(const short8v*)(kp + 8 * h);
        short8v kf1 = *(const short8v*)(kp + 16 + 8 * h);
        f32x16 S;
        #pragma unroll
        for (int r = 0; r < 16; r++) S[r] = 0.f;
        S = __builtin_amdgcn_mfma_f32_32x32x16_bf16(kf0, qf0, S, 0, 0, 0);
        S = __builtin_amdgcn_mfma_f32_32x32x16_bf16(kf1, qf1, S, 0, 0, 0);

        float s[16];
        #pragma unroll
        for (int r = 0; r < 16; r++) {
            int key = (r & 3) + 8 * (r >> 2) + 4 * h;
            s[r] = S[r] + bbase[(size_t)(kb + key) * NTOKW];
        }
        float cm = s[0];
        #pragma unroll
        for (int r = 1; r < 16; r++) cm = fmaxf(cm, s[r]);
        cm = fmaxf(cm, __shfl_xor(cm, 32));
        float mn = fmaxf(m, cm);
        float scale = __expf(m - mn);
        float e[16]; float cs = 0.f;
        #pragma unroll
        for (int r = 0; r < 16; r++) { e[r] = __expf(s[r] - mn); cs += e[r]; }
        cs += __shfl_xor(cs, 32);
        l = l * scale + cs;
        m = mn;
        #pragma unroll
        for (int r = 0; r < 16; r++) O[r] *= scale;

        unsigned P[8], Qx[8];
        #pragma unroll
        for (int i = 0; i < 8; i++)
            P[i] = (unsigned)bf16bits(e[2 * i]) | ((unsigned)bf16bits(e[2 * i + 1]) << 16);
        #pragma unroll
        for (int i = 0; i < 8; i++) Qx[i] = __shfl_xor(P[i], 32);

        FragU p0, p1;
        p0.u[0] = h ? Qx[2] : P[0];  p0.u[1] = h ? Qx[3] : P[1];
        p0.u[2] = h ? P[2]  : Qx[0]; p0.u[3] = h ? P[3]  : Qx[1];
        p1.u[0] = h ? Qx[6] : P[4];  p1.u[1] = h ? Qx[7] : P[5];
        p1.u[2] = h ? P[6]  : Qx[4]; p1.u[3] = h ? P[7]  : Qx[5];

        const unsigned short* vp0 = vbase + (size_t)(kb + 8 * h) * HDIM + ln31;
        const unsigned short* vp1 = vbase + (size_t)(kb + 16 + 8 * h) * HDIM + ln31;
        short8v vf0, vf1;
        #pragma unroll
        for (int i = 0; i < 8; i++) {
            vf0[i] = (short)vp0[i * HDIM];
            vf1[i] = (short)vp1[i * HDIM];
        }
        O = __builtin_amdgcn_mfma_f32_32x32x16_bf16(vf0, p0.v, O, 0, 0, 0);
        O = __builtin_amdgcn_mfma_f32_32x32x16_bf16(vf1, p1.v, O, 0, 0, 0);
    }

    float invl = 1.0f / l;
    #pragma unroll
    for (int r = 0; r < 16; r++) {
        int d = (r & 3) + 8 * (r >> 2) + 4 * h;
        ot[wv][ln31][d] = O[r] * invl;
    }
    __syncthreads();
    int t2 = lane >> 1, c0 = (lane & 1) * 16;
    float* outp = out + ((size_t)(wi * NTOKW + qb + t2)) * CDIM + head * HDIM + c0;
    #pragma unroll
    for (int i = 0; i < 16; i++) outp[i] = ot[wv][t2][c0 + i];
}

// ---------------- proj + residual + conv branch merge -> x2 (in d_out) ----------------
__global__ __launch_bounds__(192) void k_proj(const float* __restrict__ ao,
                                              const float* __restrict__ projT,
                                              const float* __restrict__ pb,
                                              const float* __restrict__ x,
                                              const float* __restrict__ h2,
                                              const float* __restrict__ amask,
                                              float* __restrict__ x2) {
    __shared__ float ar[4][CDIM];
    int tid = threadIdx.x;
    int wt0 = blockIdx.x * 4;
    for (int i = 0; i < 4; i++) ar[i][tid] = ao[(size_t)(wt0 + i) * CDIM + tid];
    __syncthreads();
    float acc[4] = {0, 0, 0, 0};
    for (int c = 0; c < CDIM; c++) {
        float w = projT[(size_t)c * CDIM + tid];
        for (int i = 0; i < 4; i++) acc[i] += w * ar[i][c];
    }
    float bb = pb[tid], am = amask[tid];
    for (int i = 0; i < 4; i++) {
        int wt = wt0 + i; int wi = wt >> 9, n = wt & 511;
        int wh = wi >> 3, ww = wi & 7;
        int nd = n >> 6, nh = (n >> 3) & 7, nw = n & 7;
        int t = (nd << 12) | ((wh * 8 + nh) << 6) | (ww * 8 + nw);
        size_t idx = (size_t)t * CDIM + tid;
        x2[idx] = x[idx] + acc[i] + bb + 0.01f * h2[idx] * am;
    }
}

// ---------------- fused MLP (MFMA): out += fc2(gelu(fc1(y))) ----------------
// block = 4 waves, 128 tokens; out^T accumulated in 6x f32x16 per wave.
__global__ __launch_bounds__(256) void k_mlpm(const __hip_bfloat16* __restrict__ ybf,
                                              const __hip_bfloat16* __restrict__ w1b, // [768][192]
                                              const float* __restrict__ b1,
                                              const __hip_bfloat16* __restrict__ w2b, // [192][768]
                                              const float* __restrict__ b2,
                                              float* __restrict__ out) {
    __shared__ __align__(16) char ylds[128 * 384];   // y stage; tail reused for transpose
    __shared__ float b1l[768];
    int tid = threadIdx.x;
    int wv = tid >> 6, lane = tid & 63;
    int half = lane >> 5, l31 = lane & 31;
    int t0 = blockIdx.x * 128;

    const short* src = (const short*)ybf + (size_t)t0 * CDIM;
    #pragma unroll
    for (int it = 0; it < 12; it++) {
        int e16 = it * 256 + tid;
        int tok = e16 / 24, cb = (e16 % 24) * 16;
        short8v vdat = *(const short8v*)(src + e16 * 8);
        *(short8v*)(ylds + tok * 384 + (cb ^ ((tok & 7) << 4))) = vdat;
    }
    for (int i = tid; i < 768; i += 256) b1l[i] = b1[i];
    __syncthreads();

    int myrow = wv * 32 + l31;
    int akey = (myrow & 7) << 4;
    const char* ybase = ylds + myrow * 384;

    f32x16 oacc[6];
    #pragma unroll
    for (int ot = 0; ot < 6; ot++)
        #pragma unroll
        for (int r = 0; r < 16; r++) oacc[ot][r] = 0.f;

    for (int hc = 0; hc < 24; hc++) {
        f32x16 hacc;
        #pragma unroll
        for (int r = 0; r < 16; r++) hacc[r] = 0.f;
        const short* w1base = (const short*)w1b + (size_t)(hc * 32 + l31) * CDIM + half * 8;
        #pragma unroll
        for (int cg = 0; cg < 12; cg++) {
            short8v bf = *(const short8v*)(ybase + ((cg * 32 + half * 16) ^ akey));
            short8v af = *(const short8v*)(w1base + cg * 16);
            hacc = __builtin_amdgcn_mfma_f32_32x32x16_bf16(af, bf, hacc, 0, 0, 0);
        }
        float e[16];
        #pragma unroll
        for (int r = 0; r < 16; r++) {
            int hid = (r & 3) + 8 * (r >> 2) + 4 * half;
            e[r] = gelu_exact(hacc[r] + b1l[hc * 32 + hid]);
        }
        unsigned P[8], Qx[8];
        #pragma unroll
        for (int i = 0; i < 8; i++)
            P[i] = (unsigned)bf16bits(e[2 * i]) | ((unsigned)bf16bits(e[2 * i + 1]) << 16);
        #pragma unroll
        for (int i = 0; i < 8; i++) Qx[i] = __shfl_xor(P[i], 32);
        FragU p0, p1;
        p0.u[0] = half ? Qx[2] : P[0];  p0.u[1] = half ? Qx[3] : P[1];
        p0.u[2] = half ? P[2]  : Qx[0]; p0.u[3] = half ? P[3]  : Qx[1];
        p1.u[0] = half ? Qx[6] : P[4];  p1.u[1] = half ? Qx[7] : P[5];
        p1.u[2] = half ? P[6]  : Qx[4]; p1.u[3] = half ? P[7]  : Qx[5];

        const short* w2base = (const short*)w2b + (size_t)l31 * FCH + hc * 32 + half * 8;
        #pragma unroll
        for (int ot = 0; ot < 6; ot++) {
            short8v a0 = *(const short8v*)(w2base + (size_t)ot * 32 * FCH);
            short8v a1 = *(const short8v*)(w2base + (size_t)ot * 32 * FCH + 16);
            oacc[ot] = __builtin_amdgcn_mfma_f32_32x32x16_bf16(a0, p0.v, oacc[ot], 0, 0, 0);
            oacc[ot] = __builtin_amdgcn_mfma_f32_32x32x16_bf16(a1, p1.v, oacc[ot], 0, 0, 0);
        }
    }

    __syncthreads();   // all waves done reading ylds; reuse it for transpose
    float* tbw = (float*)ylds + wv * 32 * 33;
    #pragma unroll
    for (int ot = 0; ot < 6; ot++) {
        #pragma unroll
        for (int r = 0; r < 16; r++) {
            int oc = (r & 3) + 8 * (r >> 2) + 4 * half;
            tbw[l31 * 33 + oc] = oacc[ot][r];
        }
        asm volatile("s_waitcnt lgkmcnt(0)" ::: "memory");
        __builtin_amdgcn_sched_barrier(0);
        int tok = lane >> 1, c0 = (lane & 1) * 16;
        float* op = out + (size_t)(t0 + wv * 32 + tok) * CDIM + ot * 32 + c0;
        const float* bp = b2 + ot * 32 + c0;
        #pragma unroll
        for (int i = 0; i < 16; i++)
            op[i] += tbw[tok * 33 + c0 + i] + bp[i];
        asm volatile("s_waitcnt lgkmcnt(0)" ::: "memory");
        __builtin_amdgcn_sched_barrier(0);
    }
}

// ---------------- launcher ----------------
extern "C" void kernel_launch(void* const* d_in, const int* in_sizes, int n_in,
                              void* d_out, int out_size, void* d_ws, size_t ws_size,
                              hipStream_t stream) {
    const float* x     = (const float*)d_in[0];
    const float* n1g   = (const float*)d_in[1];
    const float* n1b   = (const float*)d_in[2];
    const float* qkvw  = (const float*)d_in[3];
    const float* qkvb  = (const float*)d_in[4];
    const float* rpb   = (const float*)d_in[5];
    const float* projw = (const float*)d_in[6];
    const float* projb = (const float*)d_in[7];
    const float* c1w   = (const float*)d_in[8];
    const float* c1b   = (const float*)d_in[9];
    const float* c2w   = (const float*)d_in[10];
    const float* c2b   = (const float*)d_in[11];
    const float* ca1w  = (const float*)d_in[12];
    const float* ca1b  = (const float*)d_in[13];
    const float* ca2w  = (const float*)d_in[14];
    const float* ca2b  = (const float*)d_in[15];
    const float* n2g   = (const float*)d_in[16];
    const float* n2b   = (const float*)d_in[17];
    const float* fc1w  = (const float*)d_in[18];
    const float* fc1b  = (const float*)d_in[19];
    const float* fc2w  = (const float*)d_in[20];
    const float* fc2b  = (const float*)d_in[21];
    const int*   rpi   = (const int*)d_in[22];

    float* ws  = (float*)d_ws;
    float* out = (float*)d_out;

    __hip_bfloat16* qh   = (__hip_bfloat16*)(ws + OFF_QH);
    __hip_bfloat16* kb_  = (__hip_bfloat16*)(ws + OFF_KH);
    __hip_bfloat16* vb_  = (__hip_bfloat16*)(ws + OFF_VH);
    __hip_bfloat16* xnbf = (__hip_bfloat16*)(ws + OFF_Y);
    __hip_bfloat16* ybf  = (__hip_bfloat16*)(ws + OFF_YBF);
    __hip_bfloat16* h1bf = (__hip_bfloat16*)(ws + OFF_H1);
    float* h2    = ws + OFF_H2;
    float* part  = ws + OFF_PART;
    float* amask = ws + OFF_AMASK;
    float* biasT = ws + OFF_BIAST;
    __hip_bfloat16* w1p  = (__hip_bfloat16*)(ws + OFF_W1T);
    __hip_bfloat16* w2p  = (__hip_bfloat16*)(ws + OFF_W2T);
    __hip_bfloat16* qwb  = (__hip_bfloat16*)(ws + OFF_QKVT);
    float* projT = ws + OFF_PROJT;
    __hip_bfloat16* w1b  = (__hip_bfloat16*)(ws + OFF_FC1T);
    __hip_bfloat16* w2b  = (__hip_bfloat16*)(ws + OFF_FC2T);
    float* attn  = ws + OFF_XN;

    // weight prep + bias table (independent)
    k_wp1<<<(331776 + 255) / 256, 256, 0, stream>>>(c1w, w1p);
    k_wp2<<<(331776 + 255) / 256, 256, 0, stream>>>(c2w, w2p);
    k_cast<<<(110592 + 255) / 256, 256, 0, stream>>>(qkvw, qwb, 110592);
    k_cast<<<(147456 + 255) / 256, 256, 0, stream>>>(fc1w, w1b, 147456);
    k_cast<<<(147456 + 255) / 256, 256, 0, stream>>>(fc2w, w2b, 147456);
    k_mtrans<<<(192 * 192 + 255) / 256, 256, 0, stream>>>(projw, projT, 192, 192);
    k_bias<<<64, 256, 0, stream>>>(rpi, rpb, biasT);

    // LN1 (bf16 only)
    k_ln<<<LTOK / 4, 256, 0, stream>>>(x, n1g, n1b, (float*)nullptr, xnbf);
    // conv branch (MFMA)
    k_conv1m<<<512, 256, 0, stream>>>(xnbf, w1p, c1b, h1bf);
    k_conv2m<<<1024, 384, 0, stream>>>(h1bf, w2p, c2b, h2);
    k_pool<<<256, 192, 0, stream>>>(h2, part);
    k_ca<<<1, 192, 0, stream>>>(part, ca1w, ca1b, ca2w, ca2b, amask);
    // attention branch (MFMA)
    k_qkvm<<<LTOK / 64, 128, 0, stream>>>(xnbf, qwb, qkvb, qh, kb_, vb_);
    k_attn<<<(NWIN * NHEAD * 16) / 4, 256, 0, stream>>>(qh, kb_, vb_, biasT, attn);
    k_proj<<<LTOK / 4, 192, 0, stream>>>(attn, projT, projb, x, h2, amask, out);
    // LN2 (bf16 only) + fused MFMA MLP
    k_ln<<<LTOK / 4, 256, 0, stream>>>(out, n2g, n2b, (float*)nullptr, ybf);
    k_mlpm<<<LTOK / 128, 256, 0, stream>>>(ybf, w1b, fc1b, w2b, fc2b, out);
}

// Round 8
// 477.915 us; speedup vs baseline: 14.7661x; 1.0428x over previous
//
#include <hip/hip_runtime.h>
#include <hip/hip_bf16.h>

// ---------------- problem constants ----------------
#define LTOK  32768   // D*H*W
#define CDIM  192
#define DD_   8
#define HH_   64
#define WW_   64
#define NHEAD 6
#define HDIM  32
#define NWIN  64      // (D/8)*(H/8)*(W/8)
#define NTOKW 512     // tokens per window
#define C3    64      // C/3
#define FCH   768     // 4*C

// ws layout (float32-slot offsets)
#define OFF_XN     0u          // attn-out bf16
#define OFF_QH     6291456u
#define OFF_KH     9437184u
#define OFF_VH     12582912u
#define OFF_Y      15728640u   // xnbf
#define OFF_YBF    18874368u   // ybf
#define OFF_H1     22020096u   // h1 bf16
#define OFF_H2     24117248u   // h2 f32
#define OFF_PART   30408704u
#define OFF_AMASK  30457856u
#define OFF_BIAST  30458048u
#define OFF_W1T    32030912u
#define OFF_W2T    32362688u
#define OFF_QKVT   32694464u
#define OFF_PROJT  32805056u
#define OFF_FC1T   32841920u
#define OFF_FC2T   32989376u

typedef __attribute__((ext_vector_type(8)))  short short8v;
typedef __attribute__((ext_vector_type(16))) float f32x16;

union FragU { short8v v; unsigned u[4]; };

__device__ __forceinline__ float gelu_exact(float x) {
    return 0.5f * x * (1.0f + erff(x * 0.70710678118654752f));
}

__device__ __forceinline__ unsigned short bf16bits(float x) {
    union { __hip_bfloat16 b; unsigned short u; } cv;
    cv.b = __float2bfloat16(x);
    return cv.u;
}

// ---------------- LayerNorm: 1 wave per token; f32 and/or bf16 out ----------------
__global__ __launch_bounds__(256) void k_ln(const float* __restrict__ in,
                                            const float* __restrict__ g,
                                            const float* __restrict__ b,
                                            float* __restrict__ out,
                                            __hip_bfloat16* __restrict__ obf) {
    int wv = threadIdx.x >> 6, lane = threadIdx.x & 63;
    int t = blockIdx.x * 4 + wv;
    const float* row = in + (size_t)t * CDIM;
    float x0 = row[lane], x1 = row[lane + 64], x2 = row[lane + 128];
    float s = x0 + x1 + x2;
    for (int o = 32; o; o >>= 1) s += __shfl_xor(s, o);
    float m = s * (1.0f / 192.0f);
    float d0 = x0 - m, d1 = x1 - m, d2 = x2 - m;
    float vv = d0 * d0 + d1 * d1 + d2 * d2;
    for (int o = 32; o; o >>= 1) vv += __shfl_xor(vv, o);
    float inv = rsqrtf(vv * (1.0f / 192.0f) + 1e-5f);
    size_t base = (size_t)t * CDIM;
    float y0 = d0 * inv * g[lane]       + b[lane];
    float y1 = d1 * inv * g[lane + 64]  + b[lane + 64];
    float y2 = d2 * inv * g[lane + 128] + b[lane + 128];
    if (out) {
        out[base + lane]       = y0;
        out[base + lane + 64]  = y1;
        out[base + lane + 128] = y2;
    }
    if (obf) {
        obf[base + lane]       = __float2bfloat16(y0);
        obf[base + lane + 64]  = __float2bfloat16(y1);
        obf[base + lane + 128] = __float2bfloat16(y2);
    }
}

// ---------------- f32 -> bf16 cast ----------------
__global__ void k_cast(const float* __restrict__ in, __hip_bfloat16* __restrict__ out, int n) {
    int i = blockIdx.x * 256 + threadIdx.x;
    if (i < n) out[i] = __float2bfloat16(in[i]);
}

// ---------------- conv weight prep (MFMA B-fragment order, bf16) ----------------
__global__ void k_wp1(const float* __restrict__ w, __hip_bfloat16* __restrict__ wp) {
    int i = blockIdx.x * 256 + threadIdx.x;
    if (i >= 331776) return;
    int j = i & 7, oc = (i >> 3) & 63, h = (i >> 9) & 1;
    int cg = (i >> 10) % 12, kk = i / 12288;
    int c = cg * 16 + h * 8 + j;
    wp[i] = __float2bfloat16(w[((size_t)oc * 192 + c) * 27 + kk]);
}
__global__ void k_wp2(const float* __restrict__ w, __hip_bfloat16* __restrict__ wp) {
    int i = blockIdx.x * 256 + threadIdx.x;
    if (i >= 331776) return;
    int j = i & 7, oc = (i >> 3) % 192;
    int h = (i / 1536) & 1, cg = (i / 3072) & 3, kk = i / 12288;
    int c = cg * 16 + h * 8 + j;
    wp[i] = __float2bfloat16(w[((size_t)oc * 64 + c) * 27 + kk]);
}

// ---------------- bias precompute: biasT[h][m][n] = rpb[rpi[n][m]*6+h] ----------------
__global__ __launch_bounds__(256) void k_bias(const int* __restrict__ rpi,
                                              const float* __restrict__ rpb,
                                              float* __restrict__ biasT) {
    __shared__ int idxl[64][64];
    int tid = threadIdx.x;
    int n0 = (blockIdx.x >> 3) * 64, m0 = (blockIdx.x & 7) * 64;
    for (int it = 0; it < 16; it++) {
        int e = it * 256 + tid;
        int ln_ = e >> 6, lm = e & 63;
        idxl[ln_][lm] = rpi[(size_t)(n0 + ln_) * NTOKW + m0 + lm];
    }
    __syncthreads();
    for (int it = 0; it < 16; it++) {
        int e = it * 256 + tid;
        int lm = e >> 6, ln_ = e & 63;
        int id = idxl[ln_][lm];
        #pragma unroll
        for (int h = 0; h < NHEAD; h++)
            biasT[(size_t)h * NTOKW * NTOKW + (size_t)(m0 + lm) * NTOKW + n0 + ln_] =
                rpb[id * NHEAD + h];
    }
}

// ---------------- conv1 MFMA ----------------
__global__ __launch_bounds__(256) void k_conv1m(const __hip_bfloat16* __restrict__ xnbf,
                                                const __hip_bfloat16* __restrict__ w1p,
                                                const float* __restrict__ b1,
                                                __hip_bfloat16* __restrict__ h1bf) {
    __shared__ __align__(16) char lds[66 * 384];
    int tid = threadIdx.x;
    int wv = tid >> 6, lane = tid & 63;
    int wr = wv >> 1, wc = wv & 1;
    int half = lane >> 5, l31 = lane & 31;
    int row = blockIdx.x;
    int d = row >> 6, hh = row & 63;

    if (tid < 48) {
        float4 z = {0.f, 0.f, 0.f, 0.f};
        char* p = lds + ((tid < 24) ? tid * 16 : 65 * 384 + (tid - 24) * 16);
        *(float4*)p = z;
    }

    f32x16 acc;
    #pragma unroll
    for (int r = 0; r < 16; r++) acc[r] = 0.f;

    for (int kd = -1; kd <= 1; kd++) {
        int dd = d + kd;
        if (dd < 0 || dd >= DD_) continue;
        for (int kh = -1; kh <= 1; kh++) {
            int h2 = hh + kh;
            if (h2 < 0 || h2 >= HH_) continue;
            const short* src = (const short*)xnbf + ((size_t)((dd << 12) | (h2 << 6))) * CDIM;
            __syncthreads();
            #pragma unroll
            for (int it = 0; it < 6; it++) {
                int e16 = it * 256 + tid;
                int tok = e16 / 24, cb = (e16 % 24) * 16;
                short8v vdat = *(const short8v*)(src + e16 * 8);
                int lrow = tok + 1;
                *(short8v*)(lds + lrow * 384 + (cb ^ ((lrow & 7) << 4))) = vdat;
            }
            __syncthreads();
            #pragma unroll
            for (int kw = -1; kw <= 1; kw++) {
                int kk = (kd + 1) * 9 + (kh + 1) * 3 + (kw + 1);
                int atok = 32 * wr + l31 + kw + 1;
                int akey = (atok & 7) << 4;
                const char* abase = lds + atok * 384;
                const short* wbase = (const short*)w1p + (kk * 24 + half) * 512 + (32 * wc + l31) * 8;
                #pragma unroll
                for (int cg = 0; cg < 12; cg++) {
                    short8v af = *(const short8v*)(abase + ((cg * 32 + half * 16) ^ akey));
                    short8v bf = *(const short8v*)(wbase + cg * 1024);
                    acc = __builtin_amdgcn_mfma_f32_32x32x16_bf16(af, bf, acc, 0, 0, 0);
                }
            }
        }
    }
    int oc = 32 * wc + l31;
    float bb = b1[oc];
    int t0 = row * 64;
    #pragma unroll
    for (int r = 0; r < 16; r++) {
        int tok = 32 * wr + (r & 3) + 8 * (r >> 2) + 4 * half;
        h1bf[(size_t)(t0 + tok) * C3 + oc] = __float2bfloat16(gelu_exact(acc[r] + bb));
    }
}

// ---------------- conv2 MFMA ----------------
__global__ __launch_bounds__(384) void k_conv2m(const __hip_bfloat16* __restrict__ h1bf,
                                                const __hip_bfloat16* __restrict__ w2p,
                                                const float* __restrict__ b2,
                                                float* __restrict__ h2) {
    __shared__ __align__(16) char lds[34 * 128];
    int tid = threadIdx.x;
    int wv = tid >> 6, lane = tid & 63;
    int half = lane >> 5, l31 = lane & 31;
    int row = blockIdx.x >> 1, hr = blockIdx.x & 1;
    int d = row >> 6, hh = row & 63;

    f32x16 acc;
    #pragma unroll
    for (int r = 0; r < 16; r++) acc[r] = 0.f;

    for (int kd = -1; kd <= 1; kd++) {
        int dd = d + kd;
        if (dd < 0 || dd >= DD_) continue;
        for (int kh = -1; kh <= 1; kh++) {
            int h2r = hh + kh;
            if (h2r < 0 || h2r >= HH_) continue;
            __syncthreads();
            if (tid < 272) {
                int ti = tid >> 3, cb = (tid & 7) * 16;
                int w = hr * 32 + ti - 1;
                short8v vdat = {0, 0, 0, 0, 0, 0, 0, 0};
                if (w >= 0 && w < 64)
                    vdat = *(const short8v*)((const short*)h1bf +
                           (size_t)((dd << 12) | (h2r << 6) | w) * C3 + cb / 2);
                *(short8v*)(lds + ti * 128 + (cb ^ ((ti & 7) << 4))) = vdat;
            }
            __syncthreads();
            #pragma unroll
            for (int kw = -1; kw <= 1; kw++) {
                int kk = (kd + 1) * 9 + (kh + 1) * 3 + (kw + 1);
                int atok = l31 + kw + 1;
                int akey = (atok & 7) << 4;
                const char* abase = lds + atok * 128;
                const short* wbase = (const short*)w2p + (kk * 8 + half) * 1536 + (wv * 32 + l31) * 8;
                #pragma unroll
                for (int cg = 0; cg < 4; cg++) {
                    short8v af = *(const short8v*)(abase + ((cg * 32 + half * 16) ^ akey));
                    short8v bf = *(const short8v*)(wbase + cg * 3072);
                    acc = __builtin_amdgcn_mfma_f32_32x32x16_bf16(af, bf, acc, 0, 0, 0);
                }
            }
        }
    }
    int oc = wv * 32 + l31;
    float bb = b2[oc];
    int t0 = row * 64 + hr * 32;
    #pragma unroll
    for (int r = 0; r < 16; r++) {
        int tok = (r & 3) + 8 * (r >> 2) + 4 * half;
        h2[(size_t)(t0 + tok) * CDIM + oc] = acc[r] + bb;
    }
}

// ---------------- pooled partial sums ----------------
__global__ __launch_bounds__(192) void k_pool(const float* __restrict__ h2,
                                              float* __restrict__ part) {
    int c = threadIdx.x, b = blockIdx.x;
    float s = 0.f;
    for (int i = 0; i < 128; i++) s += h2[(size_t)(b * 128 + i) * CDIM + c];
    part[b * CDIM + c] = s;
}

// ---------------- channel attention MLP -> amask[192] ----------------
__global__ __launch_bounds__(192) void k_ca(const float* __restrict__ part,
                                            const float* __restrict__ ca1w,
                                            const float* __restrict__ ca1b,
                                            const float* __restrict__ ca2w,
                                            const float* __restrict__ ca2b,
                                            float* __restrict__ amask) {
    __shared__ float pooled[CDIM];
    __shared__ float hid[6];
    int c = threadIdx.x;
    float s = 0.f;
    for (int b = 0; b < 256; b++) s += part[b * CDIM + c];
    pooled[c] = s * (1.0f / 32768.0f);
    __syncthreads();
    if (c < 6) {
        float a = ca1b[c];
        for (int j = 0; j < CDIM; j++) a += ca1w[c * CDIM + j] * pooled[j];
        hid[c] = fmaxf(a, 0.f);
    }
    __syncthreads();
    float a = ca2b[c];
    for (int j = 0; j < 6; j++) a += ca2w[c * 6 + j] * hid[j];
    amask[c] = 1.0f / (1.0f + expf(-a));
}

// ---------------- qkv MFMA: 1 wave, 32 window-ordered tokens ----------------
__global__ __launch_bounds__(64) void k_qkvm(const __hip_bfloat16* __restrict__ xnbf,
                                             const __hip_bfloat16* __restrict__ qwb,
                                             const float* __restrict__ qkvb,
                                             __hip_bfloat16* __restrict__ q,
                                             __hip_bfloat16* __restrict__ k,
                                             __hip_bfloat16* __restrict__ v) {
    __shared__ __align__(16) char xlds[32 * 384];
    __shared__ float tb[32][33];
    int lane = threadIdx.x;
    int half = lane >> 5, l31 = lane & 31;
    int t0 = blockIdx.x * 32;
    int wi = t0 >> 9;
    int wh_ = wi >> 3, ww_ = wi & 7;

    #pragma unroll
    for (int it = 0; it < 12; it++) {
        int e16 = it * 64 + lane;
        int tok = e16 / 24, cb = (e16 % 24) * 16;
        int n = (t0 + tok) & 511;
        int nd = n >> 6, nh = (n >> 3) & 7, nw = n & 7;
        int torig = (nd << 12) | ((wh_ * 8 + nh) << 6) | (ww_ * 8 + nw);
        short8v vdat = *(const short8v*)((const short*)xnbf + (size_t)torig * CDIM + (e16 % 24) * 8);
        *(short8v*)(xlds + tok * 384 + (cb ^ ((tok & 7) << 4))) = vdat;
    }
    __syncthreads();

    int akey = (l31 & 7) << 4;
    const char* xbase = xlds + l31 * 384;

    for (int ti = 0; ti < 18; ti++) {
        f32x16 acc;
        #pragma unroll
        for (int r = 0; r < 16; r++) acc[r] = 0.f;
        const short* wbase = (const short*)qwb + (size_t)(ti * 32 + l31) * CDIM + half * 8;
        #pragma unroll
        for (int cg = 0; cg < 12; cg++) {
            short8v bf = *(const short8v*)(xbase + ((cg * 32 + half * 16) ^ akey));
            short8v af = *(const short8v*)(wbase + cg * 16);
            acc = __builtin_amdgcn_mfma_f32_32x32x16_bf16(af, bf, acc, 0, 0, 0);
        }
        #pragma unroll
        for (int r = 0; r < 16; r++) {
            int dl = (r & 3) + 8 * (r >> 2) + 4 * half;
            tb[l31][dl] = acc[r];
        }
        asm volatile("s_waitcnt lgkmcnt(0)" ::: "memory");
        __builtin_amdgcn_sched_barrier(0);
        int tok = lane >> 1, d0 = (lane & 1) * 16;
        int type = ti / 6, head = ti % 6;
        float scale = (type == 0) ? 0.17677669529663687f : 1.0f;
        int n = (t0 + tok) & 511;
        __hip_bfloat16* dst = (type == 0 ? q : (type == 1 ? k : v)) +
                              ((size_t)((wi * NHEAD + head) * NTOKW + n)) * HDIM + d0;
        const float* bp = qkvb + ti * 32 + d0;
        short8v o0, o1;
        #pragma unroll
        for (int i = 0; i < 8; i++)
            o0[i] = (short)bf16bits((tb[tok][d0 + i] + bp[i]) * scale);
        #pragma unroll
        for (int i = 0; i < 8; i++)
            o1[i] = (short)bf16bits((tb[tok][d0 + 8 + i] + bp[8 + i]) * scale);
        *(short8v*)((short*)dst) = o0;
        *(short8v*)((short*)dst + 8) = o1;
        asm volatile("s_waitcnt lgkmcnt(0)" ::: "memory");
        __builtin_amdgcn_sched_barrier(0);
    }
}

// ---------------- MFMA flash attention (bf16 output) ----------------
__global__ __launch_bounds__(256) void k_attn(const __hip_bfloat16* __restrict__ qh,
                                              const __hip_bfloat16* __restrict__ kh,
                                              const __hip_bfloat16* __restrict__ vh,
                                              const float* __restrict__ biasT,
                                              __hip_bfloat16* __restrict__ outbf) {
    __shared__ float ot[4][32][33];
    int wv = threadIdx.x >> 6, lane = threadIdx.x & 63;
    int tile = blockIdx.x * 4 + wv;
    int qt = tile & 15, wh = tile >> 4;
    int head = wh % NHEAD, wi = wh / NHEAD;
    int qb = qt * 32;
    int h = lane >> 5, ln31 = lane & 31;

    const unsigned short* qp = (const unsigned short*)qh + ((size_t)wh * NTOKW + qb + ln31) * HDIM;
    short8v qf0 = *(const short8v*)(qp + 8 * h);
    short8v qf1 = *(const short8v*)(qp + 16 + 8 * h);
    const unsigned short* kbase = (const unsigned short*)kh + (size_t)wh * NTOKW * HDIM;
    const unsigned short* vbase = (const unsigned short*)vh + (size_t)wh * NTOKW * HDIM;
    const float* bbase = biasT + (size_t)head * NTOKW * NTOKW + qb + ln31;

    f32x16 O;
    #pragma unroll
    for (int r = 0; r < 16; r++) O[r] = 0.f;
    float m = -1e30f, l = 0.f;

    for (int kb = 0; kb < NTOKW; kb += 32) {
        const unsigned short* kp = kbase + (size_t)(kb + ln31) * HDIM;
        short8v kf0 = *(const short8v*)(kp + 8 * h);
        short8v kf1 = *(const short8v*)(kp + 16 + 8 * h);
        f32x16 S;
        #pragma unroll
        for (int r = 0; r < 16; r++) S[r] = 0.f;
        S = __builtin_amdgcn_mfma_f32_32x32x16_bf16(kf0, qf0, S, 0, 0, 0);
        S = __builtin_amdgcn_mfma_f32_32x32x16_bf16(kf1, qf1, S, 0, 0, 0);

        float s[16];
        #pragma unroll
        for (int r = 0; r < 16; r++) {
            int key = (r & 3) + 8 * (r >> 2) + 4 * h;
            s[r] = S[r] + bbase[(size_t)(kb + key) * NTOKW];
        }
        float cm = s[0];
        #pragma unroll
        for (int r = 1; r < 16; r++) cm = fmaxf(cm, s[r]);
        cm = fmaxf(cm, __shfl_xor(cm, 32));
        float mn = fmaxf(m, cm);
        float scale = __expf(m - mn);
        float e[16]; float cs = 0.f;
        #pragma unroll
        for (int r = 0; r < 16; r++) { e[r] = __expf(s[r] - mn); cs += e[r]; }
        cs += __shfl_xor(cs, 32);
        l = l * scale + cs;
        m = mn;
        #pragma unroll
        for (int r = 0; r < 16; r++) O[r] *= scale;

        unsigned P[8], Qx[8];
        #pragma unroll
        for (int i = 0; i < 8; i++)
            P[i] = (unsigned)bf16bits(e[2 * i]) | ((unsigned)bf16bits(e[2 * i + 1]) << 16);
        #pragma unroll
        for (int i = 0; i < 8; i++) Qx[i] = __shfl_xor(P[i], 32);

        FragU p0, p1;
        p0.u[0] = h ? Qx[2] : P[0];  p0.u[1] = h ? Qx[3] : P[1];
        p0.u[2] = h ? P[2]  : Qx[0]; p0.u[3] = h ? P[3]  : Qx[1];
        p1.u[0] = h ? Qx[6] : P[4];  p1.u[1] = h ? Qx[7] : P[5];
        p1.u[2] = h ? P[6]  : Qx[4]; p1.u[3] = h ? P[7]  : Qx[5];

        const unsigned short* vp0 = vbase + (size_t)(kb + 8 * h) * HDIM + ln31;
        const unsigned short* vp1 = vbase + (size_t)(kb + 16 + 8 * h) * HDIM + ln31;
        short8v vf0, vf1;
        #pragma unroll
        for (int i = 0; i < 8; i++) {
            vf0[i] = (short)vp0[i * HDIM];
            vf1[i] = (short)vp1[i * HDIM];
        }
        O = __builtin_amdgcn_mfma_f32_32x32x16_bf16(vf0, p0.v, O, 0, 0, 0);
        O = __builtin_amdgcn_mfma_f32_32x32x16_bf16(vf1, p1.v, O, 0, 0, 0);
    }

    float invl = 1.0f / l;
    #pragma unroll
    for (int r = 0; r < 16; r++) {
        int d = (r & 3) + 8 * (r >> 2) + 4 * h;
        ot[wv][ln31][d] = O[r] * invl;
    }
    __syncthreads();
    int t2 = lane >> 1, c0 = (lane & 1) * 16;
    short* outp = (short*)outbf + ((size_t)(wi * NTOKW + qb + t2)) * CDIM + head * HDIM + c0;
    short8v s0, s1;
    #pragma unroll
    for (int i = 0; i < 8; i++) s0[i] = (short)bf16bits(ot[wv][t2][c0 + i]);
    #pragma unroll
    for (int i = 0; i < 8; i++) s1[i] = (short)bf16bits(ot[wv][t2][c0 + 8 + i]);
    *(short8v*)outp = s0;
    *(short8v*)(outp + 8) = s1;
}

// ---------------- proj MFMA + residual + conv merge -> x2 (d_out) ----------------
__global__ __launch_bounds__(64) void k_projm(const __hip_bfloat16* __restrict__ attnbf,
                                              const __hip_bfloat16* __restrict__ pwb,
                                              const float* __restrict__ pb,
                                              const float* __restrict__ x,
                                              const float* __restrict__ h2,
                                              const float* __restrict__ amask,
                                              float* __restrict__ x2) {
    __shared__ __align__(16) char alds[32 * 384];
    __shared__ float tb[32][33];
    int lane = threadIdx.x;
    int half = lane >> 5, l31 = lane & 31;
    int t0 = blockIdx.x * 32;
    int wi = t0 >> 9;
    int wh_ = wi >> 3, ww_ = wi & 7;

    const short* src = (const short*)attnbf + (size_t)t0 * CDIM;
    #pragma unroll
    for (int it = 0; it < 12; it++) {
        int e16 = it * 64 + lane;
        int tok = e16 / 24, cb = (e16 % 24) * 16;
        short8v vdat = *(const short8v*)(src + e16 * 8);
        *(short8v*)(alds + tok * 384 + (cb ^ ((tok & 7) << 4))) = vdat;
    }
    __syncthreads();

    int akey = (l31 & 7) << 4;
    const char* abase = alds + l31 * 384;

    for (int ot = 0; ot < 6; ot++) {
        f32x16 acc;
        #pragma unroll
        for (int r = 0; r < 16; r++) acc[r] = 0.f;
        const short* wbase = (const short*)pwb + (size_t)(ot * 32 + l31) * CDIM + half * 8;
        #pragma unroll
        for (int cg = 0; cg < 12; cg++) {
            short8v bf = *(const short8v*)(abase + ((cg * 32 + half * 16) ^ akey));
            short8v af = *(const short8v*)(wbase + cg * 16);
            acc = __builtin_amdgcn_mfma_f32_32x32x16_bf16(af, bf, acc, 0, 0, 0);
        }
        #pragma unroll
        for (int r = 0; r < 16; r++) {
            int oc = (r & 3) + 8 * (r >> 2) + 4 * half;
            tb[l31][oc] = acc[r];
        }
        asm volatile("s_waitcnt lgkmcnt(0)" ::: "memory");
        __builtin_amdgcn_sched_barrier(0);
        int tok = lane >> 1, c0 = (lane & 1) * 16;
        int n = (t0 + tok) & 511;
        int nd = n >> 6, nh = (n >> 3) & 7, nw = n & 7;
        int t = (nd << 12) | ((wh_ * 8 + nh) << 6) | (ww_ * 8 + nw);
        size_t idx = (size_t)t * CDIM + ot * 32 + c0;
        const float* bp = pb + ot * 32 + c0;
        const float* ap = amask + ot * 32 + c0;
        #pragma unroll
        for (int i = 0; i < 16; i++)
            x2[idx + i] = x[idx + i] + tb[tok][c0 + i] + bp[i] + 0.01f * h2[idx + i] * ap[i];
        asm volatile("s_waitcnt lgkmcnt(0)" ::: "memory");
        __builtin_amdgcn_sched_barrier(0);
    }
}

// ---------------- fused MLP (MFMA): 1 wave, 32 tokens ----------------
__global__ __launch_bounds__(64) void k_mlpm(const __hip_bfloat16* __restrict__ ybf,
                                             const __hip_bfloat16* __restrict__ w1b,
                                             const float* __restrict__ b1,
                                             const __hip_bfloat16* __restrict__ w2b,
                                             const float* __restrict__ b2,
                                             float* __restrict__ out) {
    __shared__ __align__(16) char ylds[32 * 384];
    int lane = threadIdx.x;
    int half = lane >> 5, l31 = lane & 31;
    int t0 = blockIdx.x * 32;

    const short* src = (const short*)ybf + (size_t)t0 * CDIM;
    #pragma unroll
    for (int it = 0; it < 12; it++) {
        int e16 = it * 64 + lane;
        int tok = e16 / 24, cb = (e16 % 24) * 16;
        short8v vdat = *(const short8v*)(src + e16 * 8);
        *(short8v*)(ylds + tok * 384 + (cb ^ ((tok & 7) << 4))) = vdat;
    }
    __syncthreads();

    int akey = (l31 & 7) << 4;
    const char* ybase = ylds + l31 * 384;

    f32x16 oacc[6];
    #pragma unroll
    for (int ot = 0; ot < 6; ot++)
        #pragma unroll
        for (int r = 0; r < 16; r++) oacc[ot][r] = 0.f;

    for (int hc = 0; hc < 24; hc++) {
        f32x16 hacc;
        #pragma unroll
        for (int r = 0; r < 16; r++) hacc[r] = 0.f;
        const short* w1base = (const short*)w1b + (size_t)(hc * 32 + l31) * CDIM + half * 8;
        #pragma unroll
        for (int cg = 0; cg < 12; cg++) {
            short8v bf = *(const short8v*)(ybase + ((cg * 32 + half * 16) ^ akey));
            short8v af = *(const short8v*)(w1base + cg * 16);
            hacc = __builtin_amdgcn_mfma_f32_32x32x16_bf16(af, bf, hacc, 0, 0, 0);
        }
        float e[16];
        #pragma unroll
        for (int r = 0; r < 16; r++) {
            int hid = (r & 3) + 8 * (r >> 2) + 4 * half;
            e[r] = gelu_exact(hacc[r] + b1[hc * 32 + hid]);
        }
        unsigned P[8], Qx[8];
        #pragma unroll
        for (int i = 0; i < 8; i++)
            P[i] = (unsigned)bf16bits(e[2 * i]) | ((unsigned)bf16bits(e[2 * i + 1]) << 16);
        #pragma unroll
        for (int i = 0; i < 8; i++) Qx[i] = __shfl_xor(P[i], 32);
        FragU p0, p1;
        p0.u[0] = half ? Qx[2] : P[0];  p0.u[1] = half ? Qx[3] : P[1];
        p0.u[2] = half ? P[2]  : Qx[0]; p0.u[3] = half ? P[3]  : Qx[1];
        p1.u[0] = half ? Qx[6] : P[4];  p1.u[1] = half ? Qx[7] : P[5];
        p1.u[2] = half ? P[6]  : Qx[4]; p1.u[3] = half ? P[7]  : Qx[5];

        const short* w2base = (const short*)w2b + (size_t)l31 * FCH + hc * 32 + half * 8;
        #pragma unroll
        for (int ot = 0; ot < 6; ot++) {
            short8v a0 = *(const short8v*)(w2base + (size_t)ot * 32 * FCH);
            short8v a1 = *(const short8v*)(w2base + (size_t)ot * 32 * FCH + 16);
            oacc[ot] = __builtin_amdgcn_mfma_f32_32x32x16_bf16(a0, p0.v, oacc[ot], 0, 0, 0);
            oacc[ot] = __builtin_amdgcn_mfma_f32_32x32x16_bf16(a1, p1.v, oacc[ot], 0, 0, 0);
        }
    }

    __syncthreads();
    float* tbw = (float*)ylds;
    #pragma unroll
    for (int ot = 0; ot < 6; ot++) {
        #pragma unroll
        for (int r = 0; r < 16; r++) {
            int oc = (r & 3) + 8 * (r >> 2) + 4 * half;
            tbw[l31 * 33 + oc] = oacc[ot][r];
        }
        asm volatile("s_waitcnt lgkmcnt(0)" ::: "memory");
        __builtin_amdgcn_sched_barrier(0);
        int tok = lane >> 1, c0 = (lane & 1) * 16;
        float* op = out + (size_t)(t0 + tok) * CDIM + ot * 32 + c0;
        const float* bp = b2 + ot * 32 + c0;
        #pragma unroll
        for (int i = 0; i < 16; i++)
            op[i] += tbw[tok * 33 + c0 + i] + bp[i];
        asm volatile("s_waitcnt lgkmcnt(0)" ::: "memory");
        __builtin_amdgcn_sched_barrier(0);
    }
}

// ---------------- launcher ----------------
extern "C" void kernel_launch(void* const* d_in, const int* in_sizes, int n_in,
                              void* d_out, int out_size, void* d_ws, size_t ws_size,
                              hipStream_t stream) {
    const float* x     = (const float*)d_in[0];
    const float* n1g   = (const float*)d_in[1];
    const float* n1b   = (const float*)d_in[2];
    const float* qkvw  = (const float*)d_in[3];
    const float* qkvb  = (const float*)d_in[4];
    const float* rpb   = (const float*)d_in[5];
    const float* projw = (const float*)d_in[6];
    const float* projb = (const float*)d_in[7];
    const float* c1w   = (const float*)d_in[8];
    const float* c1b   = (const float*)d_in[9];
    const float* c2w   = (const float*)d_in[10];
    const float* c2b   = (const float*)d_in[11];
    const float* ca1w  = (const float*)d_in[12];
    const float* ca1b  = (const float*)d_in[13];
    const float* ca2w  = (const float*)d_in[14];
    const float* ca2b  = (const float*)d_in[15];
    const float* n2g   = (const float*)d_in[16];
    const float* n2b   = (const float*)d_in[17];
    const float* fc1w  = (const float*)d_in[18];
    const float* fc1b  = (const float*)d_in[19];
    const float* fc2w  = (const float*)d_in[20];
    const float* fc2b  = (const float*)d_in[21];
    const int*   rpi   = (const int*)d_in[22];

    float* ws  = (float*)d_ws;
    float* out = (float*)d_out;

    __hip_bfloat16* attnbf = (__hip_bfloat16*)(ws + OFF_XN);
    __hip_bfloat16* qh   = (__hip_bfloat16*)(ws + OFF_QH);
    __hip_bfloat16* kb_  = (__hip_bfloat16*)(ws + OFF_KH);
    __hip_bfloat16* vb_  = (__hip_bfloat16*)(ws + OFF_VH);
    __hip_bfloat16* xnbf = (__hip_bfloat16*)(ws + OFF_Y);
    __hip_bfloat16* ybf  = (__hip_bfloat16*)(ws + OFF_YBF);
    __hip_bfloat16* h1bf = (__hip_bfloat16*)(ws + OFF_H1);
    float* h2    = ws + OFF_H2;
    float* part  = ws + OFF_PART;
    float* amask = ws + OFF_AMASK;
    float* biasT = ws + OFF_BIAST;
    __hip_bfloat16* w1p  = (__hip_bfloat16*)(ws + OFF_W1T);
    __hip_bfloat16* w2p  = (__hip_bfloat16*)(ws + OFF_W2T);
    __hip_bfloat16* qwb  = (__hip_bfloat16*)(ws + OFF_QKVT);
    __hip_bfloat16* pwb  = (__hip_bfloat16*)(ws + OFF_PROJT);
    __hip_bfloat16* w1b  = (__hip_bfloat16*)(ws + OFF_FC1T);
    __hip_bfloat16* w2b  = (__hip_bfloat16*)(ws + OFF_FC2T);

    // weight prep + bias table (independent)
    k_wp1<<<(331776 + 255) / 256, 256, 0, stream>>>(c1w, w1p);
    k_wp2<<<(331776 + 255) / 256, 256, 0, stream>>>(c2w, w2p);
    k_cast<<<(110592 + 255) / 256, 256, 0, stream>>>(qkvw, qwb, 110592);
    k_cast<<<(36864 + 255) / 256, 256, 0, stream>>>(projw, pwb, 36864);
    k_cast<<<(147456 + 255) / 256, 256, 0, stream>>>(fc1w, w1b, 147456);
    k_cast<<<(147456 + 255) / 256, 256, 0, stream>>>(fc2w, w2b, 147456);
    k_bias<<<64, 256, 0, stream>>>(rpi, rpb, biasT);

    // LN1 (bf16 only)
    k_ln<<<LTOK / 4, 256, 0, stream>>>(x, n1g, n1b, (float*)nullptr, xnbf);
    // conv branch (MFMA)
    k_conv1m<<<512, 256, 0, stream>>>(xnbf, w1p, c1b, h1bf);
    k_conv2m<<<1024, 384, 0, stream>>>(h1bf, w2p, c2b, h2);
    k_pool<<<256, 192, 0, stream>>>(h2, part);
    k_ca<<<1, 192, 0, stream>>>(part, ca1w, ca1b, ca2w, ca2b, amask);
    // attention branch (MFMA)
    k_qkvm<<<LTOK / 32, 64, 0, stream>>>(xnbf, qwb, qkvb, qh, kb_, vb_);
    k_attn<<<(NWIN * NHEAD * 16) / 4, 256, 0, stream>>>(qh, kb_, vb_, biasT, attnbf);
    k_projm<<<LTOK / 32, 64, 0, stream>>>(attnbf, pwb, projb, x, h2, amask, out);
    // LN2 (bf16 only) + fused MFMA MLP
    k_ln<<<LTOK / 4, 256, 0, stream>>>(out, n2g, n2b, (float*)nullptr, ybf);
    k_mlpm<<<LTOK / 32, 64, 0, stream>>>(ybf, w1b, fc1b, w2b, fc2b, out);
}

// Round 9
// 430.200 us; speedup vs baseline: 16.4039x; 1.1109x over previous
//
#include <hip/hip_runtime.h>
#include <hip/hip_bf16.h>

// ---------------- problem constants ----------------
#define LTOK  32768   // D*H*W
#define CDIM  192
#define DD_   8
#define HH_   64
#define WW_   64
#define NHEAD 6
#define HDIM  32
#define NWIN  64      // (D/8)*(H/8)*(W/8)
#define NTOKW 512     // tokens per window
#define C3    64      // C/3
#define FCH   768     // 4*C

// ws layout (float32-slot offsets)
#define OFF_XN     0u          // attn-out bf16
#define OFF_QH     6291456u
#define OFF_KH     9437184u
#define OFF_VH     12582912u
#define OFF_Y      15728640u   // xnbf
#define OFF_YBF    18874368u   // ybf
#define OFF_H1     22020096u   // h1 bf16
#define OFF_H2     24117248u   // h2 f32
#define OFF_PART   30408704u
#define OFF_AMASK  30457856u
#define OFF_BIAST  30458048u
#define OFF_W1T    32030912u
#define OFF_W2T    32362688u
#define OFF_QKVT   32694464u
#define OFF_PROJT  32805056u
#define OFF_FC1T   32841920u
#define OFF_FC2T   32989376u

typedef __attribute__((ext_vector_type(8)))  short short8v;
typedef __attribute__((ext_vector_type(16))) float f32x16;

union FragU { short8v v; unsigned u[4]; };

__device__ __forceinline__ float gelu_exact(float x) {
    return 0.5f * x * (1.0f + erff(x * 0.70710678118654752f));
}

__device__ __forceinline__ unsigned short bf16bits(float x) {
    union { __hip_bfloat16 b; unsigned short u; } cv;
    cv.b = __float2bfloat16(x);
    return cv.u;
}

// ---------------- LayerNorm: 1 wave per token; f32 and/or bf16 out ----------------
__global__ __launch_bounds__(256) void k_ln(const float* __restrict__ in,
                                            const float* __restrict__ g,
                                            const float* __restrict__ b,
                                            float* __restrict__ out,
                                            __hip_bfloat16* __restrict__ obf) {
    int wv = threadIdx.x >> 6, lane = threadIdx.x & 63;
    int t = blockIdx.x * 4 + wv;
    const float* row = in + (size_t)t * CDIM;
    float x0 = row[lane], x1 = row[lane + 64], x2 = row[lane + 128];
    float s = x0 + x1 + x2;
    for (int o = 32; o; o >>= 1) s += __shfl_xor(s, o);
    float m = s * (1.0f / 192.0f);
    float d0 = x0 - m, d1 = x1 - m, d2 = x2 - m;
    float vv = d0 * d0 + d1 * d1 + d2 * d2;
    for (int o = 32; o; o >>= 1) vv += __shfl_xor(vv, o);
    float inv = rsqrtf(vv * (1.0f / 192.0f) + 1e-5f);
    size_t base = (size_t)t * CDIM;
    float y0 = d0 * inv * g[lane]       + b[lane];
    float y1 = d1 * inv * g[lane + 64]  + b[lane + 64];
    float y2 = d2 * inv * g[lane + 128] + b[lane + 128];
    if (out) {
        out[base + lane]       = y0;
        out[base + lane + 64]  = y1;
        out[base + lane + 128] = y2;
    }
    if (obf) {
        obf[base + lane]       = __float2bfloat16(y0);
        obf[base + lane + 64]  = __float2bfloat16(y1);
        obf[base + lane + 128] = __float2bfloat16(y2);
    }
}

// ---------------- f32 -> bf16 cast ----------------
__global__ void k_cast(const float* __restrict__ in, __hip_bfloat16* __restrict__ out, int n) {
    int i = blockIdx.x * 256 + threadIdx.x;
    if (i < n) out[i] = __float2bfloat16(in[i]);
}

// ---------------- conv weight prep (MFMA B-fragment order, bf16) ----------------
__global__ void k_wp1(const float* __restrict__ w, __hip_bfloat16* __restrict__ wp) {
    int i = blockIdx.x * 256 + threadIdx.x;
    if (i >= 331776) return;
    int j = i & 7, oc = (i >> 3) & 63, h = (i >> 9) & 1;
    int cg = (i >> 10) % 12, kk = i / 12288;
    int c = cg * 16 + h * 8 + j;
    wp[i] = __float2bfloat16(w[((size_t)oc * 192 + c) * 27 + kk]);
}
__global__ void k_wp2(const float* __restrict__ w, __hip_bfloat16* __restrict__ wp) {
    int i = blockIdx.x * 256 + threadIdx.x;
    if (i >= 331776) return;
    int j = i & 7, oc = (i >> 3) % 192;
    int h = (i / 1536) & 1, cg = (i / 3072) & 3, kk = i / 12288;
    int c = cg * 16 + h * 8 + j;
    wp[i] = __float2bfloat16(w[((size_t)oc * 64 + c) * 27 + kk]);
}

// ---------------- bias precompute: biasT[h][m][n] = rpb[rpi[n][m]*6+h] ----------------
__global__ __launch_bounds__(256) void k_bias(const int* __restrict__ rpi,
                                              const float* __restrict__ rpb,
                                              float* __restrict__ biasT) {
    __shared__ int idxl[64][64];
    int tid = threadIdx.x;
    int n0 = (blockIdx.x >> 3) * 64, m0 = (blockIdx.x & 7) * 64;
    for (int it = 0; it < 16; it++) {
        int e = it * 256 + tid;
        int ln_ = e >> 6, lm = e & 63;
        idxl[ln_][lm] = rpi[(size_t)(n0 + ln_) * NTOKW + m0 + lm];
    }
    __syncthreads();
    for (int it = 0; it < 16; it++) {
        int e = it * 256 + tid;
        int lm = e >> 6, ln_ = e & 63;
        int id = idxl[ln_][lm];
        #pragma unroll
        for (int h = 0; h < NHEAD; h++)
            biasT[(size_t)h * NTOKW * NTOKW + (size_t)(m0 + lm) * NTOKW + n0 + ln_] =
                rpb[id * NHEAD + h];
    }
}

// ---------------- conv1 MFMA ----------------
__global__ __launch_bounds__(256) void k_conv1m(const __hip_bfloat16* __restrict__ xnbf,
                                                const __hip_bfloat16* __restrict__ w1p,
                                                const float* __restrict__ b1,
                                                __hip_bfloat16* __restrict__ h1bf) {
    __shared__ __align__(16) char lds[66 * 384];
    int tid = threadIdx.x;
    int wv = tid >> 6, lane = tid & 63;
    int wr = wv >> 1, wc = wv & 1;
    int half = lane >> 5, l31 = lane & 31;
    int row = blockIdx.x;
    int d = row >> 6, hh = row & 63;

    if (tid < 48) {
        float4 z = {0.f, 0.f, 0.f, 0.f};
        char* p = lds + ((tid < 24) ? tid * 16 : 65 * 384 + (tid - 24) * 16);
        *(float4*)p = z;
    }

    f32x16 acc;
    #pragma unroll
    for (int r = 0; r < 16; r++) acc[r] = 0.f;

    for (int kd = -1; kd <= 1; kd++) {
        int dd = d + kd;
        if (dd < 0 || dd >= DD_) continue;
        for (int kh = -1; kh <= 1; kh++) {
            int h2 = hh + kh;
            if (h2 < 0 || h2 >= HH_) continue;
            const short* src = (const short*)xnbf + ((size_t)((dd << 12) | (h2 << 6))) * CDIM;
            __syncthreads();
            #pragma unroll
            for (int it = 0; it < 6; it++) {
                int e16 = it * 256 + tid;
                int tok = e16 / 24, cb = (e16 % 24) * 16;
                short8v vdat = *(const short8v*)(src + e16 * 8);
                int lrow = tok + 1;
                *(short8v*)(lds + lrow * 384 + (cb ^ ((lrow & 7) << 4))) = vdat;
            }
            __syncthreads();
            #pragma unroll
            for (int kw = -1; kw <= 1; kw++) {
                int kk = (kd + 1) * 9 + (kh + 1) * 3 + (kw + 1);
                int atok = 32 * wr + l31 + kw + 1;
                int akey = (atok & 7) << 4;
                const char* abase = lds + atok * 384;
                const short* wbase = (const short*)w1p + (kk * 24 + half) * 512 + (32 * wc + l31) * 8;
                #pragma unroll
                for (int cg = 0; cg < 12; cg++) {
                    short8v af = *(const short8v*)(abase + ((cg * 32 + half * 16) ^ akey));
                    short8v bf = *(const short8v*)(wbase + cg * 1024);
                    acc = __builtin_amdgcn_mfma_f32_32x32x16_bf16(af, bf, acc, 0, 0, 0);
                }
            }
        }
    }
    int oc = 32 * wc + l31;
    float bb = b1[oc];
    int t0 = row * 64;
    #pragma unroll
    for (int r = 0; r < 16; r++) {
        int tok = 32 * wr + (r & 3) + 8 * (r >> 2) + 4 * half;
        h1bf[(size_t)(t0 + tok) * C3 + oc] = __float2bfloat16(gelu_exact(acc[r] + bb));
    }
}

// ---------------- conv2 MFMA ----------------
__global__ __launch_bounds__(384) void k_conv2m(const __hip_bfloat16* __restrict__ h1bf,
                                                const __hip_bfloat16* __restrict__ w2p,
                                                const float* __restrict__ b2,
                                                float* __restrict__ h2) {
    __shared__ __align__(16) char lds[34 * 128];
    int tid = threadIdx.x;
    int wv = tid >> 6, lane = tid & 63;
    int half = lane >> 5, l31 = lane & 31;
    int row = blockIdx.x >> 1, hr = blockIdx.x & 1;
    int d = row >> 6, hh = row & 63;

    f32x16 acc;
    #pragma unroll
    for (int r = 0; r < 16; r++) acc[r] = 0.f;

    for (int kd = -1; kd <= 1; kd++) {
        int dd = d + kd;
        if (dd < 0 || dd >= DD_) continue;
        for (int kh = -1; kh <= 1; kh++) {
            int h2r = hh + kh;
            if (h2r < 0 || h2r >= HH_) continue;
            __syncthreads();
            if (tid < 272) {
                int ti = tid >> 3, cb = (tid & 7) * 16;
                int w = hr * 32 + ti - 1;
                short8v vdat = {0, 0, 0, 0, 0, 0, 0, 0};
                if (w >= 0 && w < 64)
                    vdat = *(const short8v*)((const short*)h1bf +
                           (size_t)((dd << 12) | (h2r << 6) | w) * C3 + cb / 2);
                *(short8v*)(lds + ti * 128 + (cb ^ ((ti & 7) << 4))) = vdat;
            }
            __syncthreads();
            #pragma unroll
            for (int kw = -1; kw <= 1; kw++) {
                int kk = (kd + 1) * 9 + (kh + 1) * 3 + (kw + 1);
                int atok = l31 + kw + 1;
                int akey = (atok & 7) << 4;
                const char* abase = lds + atok * 128;
                const short* wbase = (const short*)w2p + (kk * 8 + half) * 1536 + (wv * 32 + l31) * 8;
                #pragma unroll
                for (int cg = 0; cg < 4; cg++) {
                    short8v af = *(const short8v*)(abase + ((cg * 32 + half * 16) ^ akey));
                    short8v bf = *(const short8v*)(wbase + cg * 3072);
                    acc = __builtin_amdgcn_mfma_f32_32x32x16_bf16(af, bf, acc, 0, 0, 0);
                }
            }
        }
    }
    int oc = wv * 32 + l31;
    float bb = b2[oc];
    int t0 = row * 64 + hr * 32;
    #pragma unroll
    for (int r = 0; r < 16; r++) {
        int tok = (r & 3) + 8 * (r >> 2) + 4 * half;
        h2[(size_t)(t0 + tok) * CDIM + oc] = acc[r] + bb;
    }
}

// ---------------- pooled partial sums ----------------
__global__ __launch_bounds__(192) void k_pool(const float* __restrict__ h2,
                                              float* __restrict__ part) {
    int c = threadIdx.x, b = blockIdx.x;
    float s = 0.f;
    for (int i = 0; i < 128; i++) s += h2[(size_t)(b * 128 + i) * CDIM + c];
    part[b * CDIM + c] = s;
}

// ---------------- channel attention MLP -> amask[192] ----------------
__global__ __launch_bounds__(192) void k_ca(const float* __restrict__ part,
                                            const float* __restrict__ ca1w,
                                            const float* __restrict__ ca1b,
                                            const float* __restrict__ ca2w,
                                            const float* __restrict__ ca2b,
                                            float* __restrict__ amask) {
    __shared__ float pooled[CDIM];
    __shared__ float hid[6];
    int c = threadIdx.x;
    float s = 0.f;
    for (int b = 0; b < 256; b++) s += part[b * CDIM + c];
    pooled[c] = s * (1.0f / 32768.0f);
    __syncthreads();
    if (c < 6) {
        float a = ca1b[c];
        for (int j = 0; j < CDIM; j++) a += ca1w[c * CDIM + j] * pooled[j];
        hid[c] = fmaxf(a, 0.f);
    }
    __syncthreads();
    float a = ca2b[c];
    for (int j = 0; j < 6; j++) a += ca2w[c * 6 + j] * hid[j];
    amask[c] = 1.0f / (1.0f + expf(-a));
}

// ---------------- qkv MFMA: 3 waves (q/k/v), 32 window-ordered tokens ----------------
__global__ __launch_bounds__(192) void k_qkvm(const __hip_bfloat16* __restrict__ xnbf,
                                              const __hip_bfloat16* __restrict__ qwb,
                                              const float* __restrict__ qkvb,
                                              __hip_bfloat16* __restrict__ q,
                                              __hip_bfloat16* __restrict__ k,
                                              __hip_bfloat16* __restrict__ v) {
    __shared__ __align__(16) char xlds[32 * 384];
    __shared__ float tb[3][32][33];
    int tid = threadIdx.x;
    int wv = tid >> 6, lane = tid & 63;
    int half = lane >> 5, l31 = lane & 31;
    int t0 = blockIdx.x * 32;
    int wi = t0 >> 9;
    int wh_ = wi >> 3, ww_ = wi & 7;

    #pragma unroll
    for (int it = 0; it < 4; it++) {
        int e16 = it * 192 + tid;        // 0..767
        int tok = e16 / 24, cb = (e16 % 24) * 16;
        int n = (t0 + tok) & 511;
        int nd = n >> 6, nh = (n >> 3) & 7, nw = n & 7;
        int torig = (nd << 12) | ((wh_ * 8 + nh) << 6) | (ww_ * 8 + nw);
        short8v vdat = *(const short8v*)((const short*)xnbf + (size_t)torig * CDIM + (e16 % 24) * 8);
        *(short8v*)(xlds + tok * 384 + (cb ^ ((tok & 7) << 4))) = vdat;
    }
    __syncthreads();

    int akey = (l31 & 7) << 4;
    const char* xbase = xlds + l31 * 384;
    __hip_bfloat16* dstbase = (wv == 0) ? q : (wv == 1 ? k : v);
    float scale = (wv == 0) ? 0.17677669529663687f : 1.0f;

    for (int j = 0; j < 6; j++) {
        int ti = wv * 6 + j;             // wave owns one output type
        f32x16 acc;
        #pragma unroll
        for (int r = 0; r < 16; r++) acc[r] = 0.f;
        const short* wbase = (const short*)qwb + (size_t)(ti * 32 + l31) * CDIM + half * 8;
        #pragma unroll
        for (int cg = 0; cg < 12; cg++) {
            short8v bf = *(const short8v*)(xbase + ((cg * 32 + half * 16) ^ akey));
            short8v af = *(const short8v*)(wbase + cg * 16);
            acc = __builtin_amdgcn_mfma_f32_32x32x16_bf16(af, bf, acc, 0, 0, 0);
        }
        #pragma unroll
        for (int r = 0; r < 16; r++) {
            int dl = (r & 3) + 8 * (r >> 2) + 4 * half;
            tb[wv][l31][dl] = acc[r];
        }
        asm volatile("s_waitcnt lgkmcnt(0)" ::: "memory");
        __builtin_amdgcn_sched_barrier(0);
        int tok = lane >> 1, d0 = (lane & 1) * 16;
        int n = (t0 + tok) & 511;
        __hip_bfloat16* dst = dstbase +
                              ((size_t)((wi * NHEAD + j) * NTOKW + n)) * HDIM + d0;
        const float* bp = qkvb + ti * 32 + d0;
        short8v o0, o1;
        #pragma unroll
        for (int i = 0; i < 8; i++)
            o0[i] = (short)bf16bits((tb[wv][tok][d0 + i] + bp[i]) * scale);
        #pragma unroll
        for (int i = 0; i < 8; i++)
            o1[i] = (short)bf16bits((tb[wv][tok][d0 + 8 + i] + bp[8 + i]) * scale);
        *(short8v*)((short*)dst) = o0;
        *(short8v*)((short*)dst + 8) = o1;
        asm volatile("s_waitcnt lgkmcnt(0)" ::: "memory");
        __builtin_amdgcn_sched_barrier(0);
    }
}

// ---------------- MFMA flash attention (bf16 output) ----------------
__global__ __launch_bounds__(256) void k_attn(const __hip_bfloat16* __restrict__ qh,
                                              const __hip_bfloat16* __restrict__ kh,
                                              const __hip_bfloat16* __restrict__ vh,
                                              const float* __restrict__ biasT,
                                              __hip_bfloat16* __restrict__ outbf) {
    __shared__ float ot[4][32][33];
    int wv = threadIdx.x >> 6, lane = threadIdx.x & 63;
    int tile = blockIdx.x * 4 + wv;
    int qt = tile & 15, wh = tile >> 4;
    int head = wh % NHEAD, wi = wh / NHEAD;
    int qb = qt * 32;
    int h = lane >> 5, ln31 = lane & 31;

    const unsigned short* qp = (const unsigned short*)qh + ((size_t)wh * NTOKW + qb + ln31) * HDIM;
    short8v qf0 = *(const short8v*)(qp + 8 * h);
    short8v qf1 = *(const short8v*)(qp + 16 + 8 * h);
    const unsigned short* kbase = (const unsigned short*)kh + (size_t)wh * NTOKW * HDIM;
    const unsigned short* vbase = (const unsigned short*)vh + (size_t)wh * NTOKW * HDIM;
    const float* bbase = biasT + (size_t)head * NTOKW * NTOKW + qb + ln31;

    f32x16 O;
    #pragma unroll
    for (int r = 0; r < 16; r++) O[r] = 0.f;
    float m = -1e30f, l = 0.f;

    for (int kb = 0; kb < NTOKW; kb += 32) {
        const unsigned short* kp = kbase + (size_t)(kb + ln31) * HDIM;
        short8v kf0 = *(const short8v*)(kp + 8 * h);
        short8v kf1 = *(const short8v*)(kp + 16 + 8 * h);
        f32x16 S;
        #pragma unroll
        for (int r = 0; r < 16; r++) S[r] = 0.f;
        S = __builtin_amdgcn_mfma_f32_32x32x16_bf16(kf0, qf0, S, 0, 0, 0);
        S = __builtin_amdgcn_mfma_f32_32x32x16_bf16(kf1, qf1, S, 0, 0, 0);

        float s[16];
        #pragma unroll
        for (int r = 0; r < 16; r++) {
            int key = (r & 3) + 8 * (r >> 2) + 4 * h;
            s[r] = S[r] + bbase[(size_t)(kb + key) * NTOKW];
        }
        float cm = s[0];
        #pragma unroll
        for (int r = 1; r < 16; r++) cm = fmaxf(cm, s[r]);
        cm = fmaxf(cm, __shfl_xor(cm, 32));
        float mn = fmaxf(m, cm);
        float scale = __expf(m - mn);
        float e[16]; float cs = 0.f;
        #pragma unroll
        for (int r = 0; r < 16; r++) { e[r] = __expf(s[r] - mn); cs += e[r]; }
        cs += __shfl_xor(cs, 32);
        l = l * scale + cs;
        m = mn;
        #pragma unroll
        for (int r = 0; r < 16; r++) O[r] *= scale;

        unsigned P[8], Qx[8];
        #pragma unroll
        for (int i = 0; i < 8; i++)
            P[i] = (unsigned)bf16bits(e[2 * i]) | ((unsigned)bf16bits(e[2 * i + 1]) << 16);
        #pragma unroll
        for (int i = 0; i < 8; i++) Qx[i] = __shfl_xor(P[i], 32);

        FragU p0, p1;
        p0.u[0] = h ? Qx[2] : P[0];  p0.u[1] = h ? Qx[3] : P[1];
        p0.u[2] = h ? P[2]  : Qx[0]; p0.u[3] = h ? P[3]  : Qx[1];
        p1.u[0] = h ? Qx[6] : P[4];  p1.u[1] = h ? Qx[7] : P[5];
        p1.u[2] = h ? P[6]  : Qx[4]; p1.u[3] = h ? P[7]  : Qx[5];

        const unsigned short* vp0 = vbase + (size_t)(kb + 8 * h) * HDIM + ln31;
        const unsigned short* vp1 = vbase + (size_t)(kb + 16 + 8 * h) * HDIM + ln31;
        short8v vf0, vf1;
        #pragma unroll
        for (int i = 0; i < 8; i++) {
            vf0[i] = (short)vp0[i * HDIM];
            vf1[i] = (short)vp1[i * HDIM];
        }
        O = __builtin_amdgcn_mfma_f32_32x32x16_bf16(vf0, p0.v, O, 0, 0, 0);
        O = __builtin_amdgcn_mfma_f32_32x32x16_bf16(vf1, p1.v, O, 0, 0, 0);
    }

    float invl = 1.0f / l;
    #pragma unroll
    for (int r = 0; r < 16; r++) {
        int d = (r & 3) + 8 * (r >> 2) + 4 * h;
        ot[wv][ln31][d] = O[r] * invl;
    }
    __syncthreads();
    int t2 = lane >> 1, c0 = (lane & 1) * 16;
    short* outp = (short*)outbf + ((size_t)(wi * NTOKW + qb + t2)) * CDIM + head * HDIM + c0;
    short8v s0, s1;
    #pragma unroll
    for (int i = 0; i < 8; i++) s0[i] = (short)bf16bits(ot[wv][t2][c0 + i]);
    #pragma unroll
    for (int i = 0; i < 8; i++) s1[i] = (short)bf16bits(ot[wv][t2][c0 + 8 + i]);
    *(short8v*)outp = s0;
    *(short8v*)(outp + 8) = s1;
}

// ---------------- proj MFMA + residual + conv merge: 3 waves, 2 tiles each ----------------
__global__ __launch_bounds__(192) void k_projm(const __hip_bfloat16* __restrict__ attnbf,
                                               const __hip_bfloat16* __restrict__ pwb,
                                               const float* __restrict__ pb,
                                               const float* __restrict__ x,
                                               const float* __restrict__ h2,
                                               const float* __restrict__ amask,
                                               float* __restrict__ x2) {
    __shared__ __align__(16) char alds[32 * 384];
    __shared__ float tb[3][32][33];
    int tid = threadIdx.x;
    int wv = tid >> 6, lane = tid & 63;
    int half = lane >> 5, l31 = lane & 31;
    int t0 = blockIdx.x * 32;
    int wi = t0 >> 9;
    int wh_ = wi >> 3, ww_ = wi & 7;

    const short* src = (const short*)attnbf + (size_t)t0 * CDIM;
    #pragma unroll
    for (int it = 0; it < 4; it++) {
        int e16 = it * 192 + tid;
        int tok = e16 / 24, cb = (e16 % 24) * 16;
        short8v vdat = *(const short8v*)(src + e16 * 8);
        *(short8v*)(alds + tok * 384 + (cb ^ ((tok & 7) << 4))) = vdat;
    }
    __syncthreads();

    int akey = (l31 & 7) << 4;
    const char* abase = alds + l31 * 384;

    for (int j = 0; j < 2; j++) {
        int ot = wv * 2 + j;
        f32x16 acc;
        #pragma unroll
        for (int r = 0; r < 16; r++) acc[r] = 0.f;
        const short* wbase = (const short*)pwb + (size_t)(ot * 32 + l31) * CDIM + half * 8;
        #pragma unroll
        for (int cg = 0; cg < 12; cg++) {
            short8v bf = *(const short8v*)(abase + ((cg * 32 + half * 16) ^ akey));
            short8v af = *(const short8v*)(wbase + cg * 16);
            acc = __builtin_amdgcn_mfma_f32_32x32x16_bf16(af, bf, acc, 0, 0, 0);
        }
        #pragma unroll
        for (int r = 0; r < 16; r++) {
            int oc = (r & 3) + 8 * (r >> 2) + 4 * half;
            tb[wv][l31][oc] = acc[r];
        }
        asm volatile("s_waitcnt lgkmcnt(0)" ::: "memory");
        __builtin_amdgcn_sched_barrier(0);
        int tok = lane >> 1, c0 = (lane & 1) * 16;
        int n = (t0 + tok) & 511;
        int nd = n >> 6, nh = (n >> 3) & 7, nw = n & 7;
        int t = (nd << 12) | ((wh_ * 8 + nh) << 6) | (ww_ * 8 + nw);
        size_t idx = (size_t)t * CDIM + ot * 32 + c0;
        const float* bp = pb + ot * 32 + c0;
        const float* ap = amask + ot * 32 + c0;
        #pragma unroll
        for (int i = 0; i < 16; i++)
            x2[idx + i] = x[idx + i] + tb[wv][tok][c0 + i] + bp[i] + 0.01f * h2[idx + i] * ap[i];
        asm volatile("s_waitcnt lgkmcnt(0)" ::: "memory");
        __builtin_amdgcn_sched_barrier(0);
    }
}

// ---------------- fused MLP (MFMA): 4 waves, hc-split + LDS reduction ----------------
__global__ __launch_bounds__(256) void k_mlpm(const __hip_bfloat16* __restrict__ ybf,
                                              const __hip_bfloat16* __restrict__ w1b,
                                              const float* __restrict__ b1,
                                              const __hip_bfloat16* __restrict__ w2b,
                                              const float* __restrict__ b2,
                                              float* __restrict__ out) {
    __shared__ __align__(16) char ylds[32 * 384];       // 12 KB staging
    __shared__ __align__(16) float rbuf[6 * 32 * 32];   // 24 KB reduce/transpose
    int tid = threadIdx.x;
    int wv = tid >> 6, lane = tid & 63;
    int half = lane >> 5, l31 = lane & 31;
    int t0 = blockIdx.x * 32;

    const short* src = (const short*)ybf + (size_t)t0 * CDIM;
    #pragma unroll
    for (int it = 0; it < 3; it++) {
        int e16 = it * 256 + tid;      // 0..767
        int tok = e16 / 24, cb = (e16 % 24) * 16;
        short8v vdat = *(const short8v*)(src + e16 * 8);
        *(short8v*)(ylds + tok * 384 + (cb ^ ((tok & 7) << 4))) = vdat;
    }
    __syncthreads();

    int akey = (l31 & 7) << 4;
    const char* ybase = ylds + l31 * 384;

    f32x16 oacc[6];
    #pragma unroll
    for (int ot = 0; ot < 6; ot++)
        #pragma unroll
        for (int r = 0; r < 16; r++) oacc[ot][r] = 0.f;

    // each wave handles 6 of the 24 hidden chunks
    for (int j = 0; j < 6; j++) {
        int hc = wv * 6 + j;
        f32x16 hacc;
        #pragma unroll
        for (int r = 0; r < 16; r++) hacc[r] = 0.f;
        const short* w1base = (const short*)w1b + (size_t)(hc * 32 + l31) * CDIM + half * 8;
        #pragma unroll
        for (int cg = 0; cg < 12; cg++) {
            short8v bf = *(const short8v*)(ybase + ((cg * 32 + half * 16) ^ akey));
            short8v af = *(const short8v*)(w1base + cg * 16);
            hacc = __builtin_amdgcn_mfma_f32_32x32x16_bf16(af, bf, hacc, 0, 0, 0);
        }
        float e[16];
        #pragma unroll
        for (int r = 0; r < 16; r++) {
            int hid = (r & 3) + 8 * (r >> 2) + 4 * half;
            e[r] = gelu_exact(hacc[r] + b1[hc * 32 + hid]);
        }
        unsigned P[8], Qx[8];
        #pragma unroll
        for (int i = 0; i < 8; i++)
            P[i] = (unsigned)bf16bits(e[2 * i]) | ((unsigned)bf16bits(e[2 * i + 1]) << 16);
        #pragma unroll
        for (int i = 0; i < 8; i++) Qx[i] = __shfl_xor(P[i], 32);
        FragU p0, p1;
        p0.u[0] = half ? Qx[2] : P[0];  p0.u[1] = half ? Qx[3] : P[1];
        p0.u[2] = half ? P[2]  : Qx[0]; p0.u[3] = half ? P[3]  : Qx[1];
        p1.u[0] = half ? Qx[6] : P[4];  p1.u[1] = half ? Qx[7] : P[5];
        p1.u[2] = half ? P[6]  : Qx[4]; p1.u[3] = half ? P[7]  : Qx[5];

        const short* w2base = (const short*)w2b + (size_t)l31 * FCH + hc * 32 + half * 8;
        #pragma unroll
        for (int ot = 0; ot < 6; ot++) {
            short8v a0 = *(const short8v*)(w2base + (size_t)ot * 32 * FCH);
            short8v a1 = *(const short8v*)(w2base + (size_t)ot * 32 * FCH + 16);
            oacc[ot] = __builtin_amdgcn_mfma_f32_32x32x16_bf16(a0, p0.v, oacc[ot], 0, 0, 0);
            oacc[ot] = __builtin_amdgcn_mfma_f32_32x32x16_bf16(a1, p1.v, oacc[ot], 0, 0, 0);
        }
    }

    // barrier-sequenced float4 reduction into rbuf (XOR-swizzled chunk -> <=4-way bank)
    float4* rb4 = (float4*)rbuf;
    for (int w = 0; w < 4; w++) {
        if (wv == w) {
            #pragma unroll
            for (int ot = 0; ot < 6; ot++) {
                #pragma unroll
                for (int g = 0; g < 4; g++) {
                    float4 val = {oacc[ot][g * 4 + 0], oacc[ot][g * 4 + 1],
                                  oacc[ot][g * 4 + 2], oacc[ot][g * 4 + 3]};
                    int chunk = 2 * g + half;          // oc quad index within 32-ch tile
                    float4* p = &rb4[(ot * 32 + l31) * 8 + (chunk ^ (l31 & 7))];
                    if (w == 0) *p = val;
                    else {
                        float4 o = *p;
                        o.x += val.x; o.y += val.y; o.z += val.z; o.w += val.w;
                        *p = o;
                    }
                }
            }
        }
        __syncthreads();
    }

    // final coalesced write: out += rbuf + b2
    #pragma unroll
    for (int i = 0; i < 6; i++) {
        int c4 = i * 256 + tid;                // 0..1535 float4 chunks
        int oc4 = c4 & 7;
        int tok = (c4 >> 3) & 31;
        int ot  = c4 >> 8;
        float4 vv = rb4[(ot * 32 + tok) * 8 + (oc4 ^ (tok & 7))];
        float* op = out + (size_t)(t0 + tok) * CDIM + ot * 32 + oc4 * 4;
        const float* bp = b2 + ot * 32 + oc4 * 4;
        op[0] += vv.x + bp[0];
        op[1] += vv.y + bp[1];
        op[2] += vv.z + bp[2];
        op[3] += vv.w + bp[3];
    }
}

// ---------------- launcher ----------------
extern "C" void kernel_launch(void* const* d_in, const int* in_sizes, int n_in,
                              void* d_out, int out_size, void* d_ws, size_t ws_size,
                              hipStream_t stream) {
    const float* x     = (const float*)d_in[0];
    const float* n1g   = (const float*)d_in[1];
    const float* n1b   = (const float*)d_in[2];
    const float* qkvw  = (const float*)d_in[3];
    const float* qkvb  = (const float*)d_in[4];
    const float* rpb   = (const float*)d_in[5];
    const float* projw = (const float*)d_in[6];
    const float* projb = (const float*)d_in[7];
    const float* c1w   = (const float*)d_in[8];
    const float* c1b   = (const float*)d_in[9];
    const float* c2w   = (const float*)d_in[10];
    const float* c2b   = (const float*)d_in[11];
    const float* ca1w  = (const float*)d_in[12];
    const float* ca1b  = (const float*)d_in[13];
    const float* ca2w  = (const float*)d_in[14];
    const float* ca2b  = (const float*)d_in[15];
    const float* n2g   = (const float*)d_in[16];
    const float* n2b   = (const float*)d_in[17];
    const float* fc1w  = (const float*)d_in[18];
    const float* fc1b  = (const float*)d_in[19];
    const float* fc2w  = (const float*)d_in[20];
    const float* fc2b  = (const float*)d_in[21];
    const int*   rpi   = (const int*)d_in[22];

    float* ws  = (float*)d_ws;
    float* out = (float*)d_out;

    __hip_bfloat16* attnbf = (__hip_bfloat16*)(ws + OFF_XN);
    __hip_bfloat16* qh   = (__hip_bfloat16*)(ws + OFF_QH);
    __hip_bfloat16* kb_  = (__hip_bfloat16*)(ws + OFF_KH);
    __hip_bfloat16* vb_  = (__hip_bfloat16*)(ws + OFF_VH);
    __hip_bfloat16* xnbf = (__hip_bfloat16*)(ws + OFF_Y);
    __hip_bfloat16* ybf  = (__hip_bfloat16*)(ws + OFF_YBF);
    __hip_bfloat16* h1bf = (__hip_bfloat16*)(ws + OFF_H1);
    float* h2    = ws + OFF_H2;
    float* part  = ws + OFF_PART;
    float* amask = ws + OFF_AMASK;
    float* biasT = ws + OFF_BIAST;
    __hip_bfloat16* w1p  = (__hip_bfloat16*)(ws + OFF_W1T);
    __hip_bfloat16* w2p  = (__hip_bfloat16*)(ws + OFF_W2T);
    __hip_bfloat16* qwb  = (__hip_bfloat16*)(ws + OFF_QKVT);
    __hip_bfloat16* pwb  = (__hip_bfloat16*)(ws + OFF_PROJT);
    __hip_bfloat16* w1b  = (__hip_bfloat16*)(ws + OFF_FC1T);
    __hip_bfloat16* w2b  = (__hip_bfloat16*)(ws + OFF_FC2T);

    // weight prep + bias table (independent)
    k_wp1<<<(331776 + 255) / 256, 256, 0, stream>>>(c1w, w1p);
    k_wp2<<<(331776 + 255) / 256, 256, 0, stream>>>(c2w, w2p);
    k_cast<<<(110592 + 255) / 256, 256, 0, stream>>>(qkvw, qwb, 110592);
    k_cast<<<(36864 + 255) / 256, 256, 0, stream>>>(projw, pwb, 36864);
    k_cast<<<(147456 + 255) / 256, 256, 0, stream>>>(fc1w, w1b, 147456);
    k_cast<<<(147456 + 255) / 256, 256, 0, stream>>>(fc2w, w2b, 147456);
    k_bias<<<64, 256, 0, stream>>>(rpi, rpb, biasT);

    // LN1 (bf16 only)
    k_ln<<<LTOK / 4, 256, 0, stream>>>(x, n1g, n1b, (float*)nullptr, xnbf);
    // conv branch (MFMA)
    k_conv1m<<<512, 256, 0, stream>>>(xnbf, w1p, c1b, h1bf);
    k_conv2m<<<1024, 384, 0, stream>>>(h1bf, w2p, c2b, h2);
    k_pool<<<256, 192, 0, stream>>>(h2, part);
    k_ca<<<1, 192, 0, stream>>>(part, ca1w, ca1b, ca2w, ca2b, amask);
    // attention branch (MFMA)
    k_qkvm<<<LTOK / 32, 192, 0, stream>>>(xnbf, qwb, qkvb, qh, kb_, vb_);
    k_attn<<<(NWIN * NHEAD * 16) / 4, 256, 0, stream>>>(qh, kb_, vb_, biasT, attnbf);
    k_projm<<<LTOK / 32, 192, 0, stream>>>(attnbf, pwb, projb, x, h2, amask, out);
    // LN2 (bf16 only) + fused MFMA MLP (hc-split across 4 waves)
    k_ln<<<LTOK / 4, 256, 0, stream>>>(out, n2g, n2b, (float*)nullptr, ybf);
    k_mlpm<<<LTOK / 32, 256, 0, stream>>>(ybf, w1b, fc1b, w2b, fc2b, out);
}

// Round 10
// 384.308 us; speedup vs baseline: 18.3627x; 1.1194x over previous
//
#include <hip/hip_runtime.h>
#include <hip/hip_bf16.h>

// ---------------- problem constants ----------------
#define LTOK  32768   // D*H*W
#define CDIM  192
#define DD_   8
#define HH_   64
#define WW_   64
#define NHEAD 6
#define HDIM  32
#define NWIN  64      // (D/8)*(H/8)*(W/8)
#define NTOKW 512     // tokens per window
#define C3    64      // C/3
#define FCH   768     // 4*C

// ws layout (float32-slot offsets)
#define OFF_XN     0u          // attn-out bf16
#define OFF_QH     6291456u
#define OFF_KH     9437184u
#define OFF_VH     12582912u
#define OFF_Y      15728640u   // xnbf
#define OFF_YBF    18874368u   // ybf
#define OFF_H1     22020096u   // h1 bf16
#define OFF_H2     24117248u   // h2 f32
#define OFF_PART   30408704u
#define OFF_AMASK  30457856u
#define OFF_BIAST  30458048u
#define OFF_W1T    32030912u
#define OFF_W2T    32362688u
#define OFF_QKVT   32694464u
#define OFF_PROJT  32805056u
#define OFF_FC1T   32841920u
#define OFF_FC2T   32989376u

typedef __attribute__((ext_vector_type(8)))  short short8v;
typedef __attribute__((ext_vector_type(16))) float f32x16;

union FragU { short8v v; unsigned u[4]; };

__device__ __forceinline__ float gelu_exact(float x) {
    return 0.5f * x * (1.0f + erff(x * 0.70710678118654752f));
}

__device__ __forceinline__ unsigned short bf16bits(float x) {
    union { __hip_bfloat16 b; unsigned short u; } cv;
    cv.b = __float2bfloat16(x);
    return cv.u;
}

// ---------------- LayerNorm: 1 wave per token; f32 and/or bf16 out ----------------
__global__ __launch_bounds__(256) void k_ln(const float* __restrict__ in,
                                            const float* __restrict__ g,
                                            const float* __restrict__ b,
                                            float* __restrict__ out,
                                            __hip_bfloat16* __restrict__ obf) {
    int wv = threadIdx.x >> 6, lane = threadIdx.x & 63;
    int t = blockIdx.x * 4 + wv;
    const float* row = in + (size_t)t * CDIM;
    float x0 = row[lane], x1 = row[lane + 64], x2 = row[lane + 128];
    float s = x0 + x1 + x2;
    for (int o = 32; o; o >>= 1) s += __shfl_xor(s, o);
    float m = s * (1.0f / 192.0f);
    float d0 = x0 - m, d1 = x1 - m, d2 = x2 - m;
    float vv = d0 * d0 + d1 * d1 + d2 * d2;
    for (int o = 32; o; o >>= 1) vv += __shfl_xor(vv, o);
    float inv = rsqrtf(vv * (1.0f / 192.0f) + 1e-5f);
    size_t base = (size_t)t * CDIM;
    float y0 = d0 * inv * g[lane]       + b[lane];
    float y1 = d1 * inv * g[lane + 64]  + b[lane + 64];
    float y2 = d2 * inv * g[lane + 128] + b[lane + 128];
    if (out) {
        out[base + lane]       = y0;
        out[base + lane + 64]  = y1;
        out[base + lane + 128] = y2;
    }
    if (obf) {
        obf[base + lane]       = __float2bfloat16(y0);
        obf[base + lane + 64]  = __float2bfloat16(y1);
        obf[base + lane + 128] = __float2bfloat16(y2);
    }
}

// ---------------- generic A-fragment weight pack (coalesced lane layout) ----------------
// packed[(((rt*(C/16)+kc)*2+half)*256) + l31*8 + j] = W[rt*32+l31][kc*16+half*8+j]
__global__ void k_wpack(const float* __restrict__ w, __hip_bfloat16* __restrict__ wp,
                        int R, int C) {
    int i = blockIdx.x * 256 + threadIdx.x;
    if (i >= R * C) return;
    int j = i & 7, l31 = (i >> 3) & 31, half = (i >> 8) & 1;
    int rest = i >> 9;
    int nkc = C >> 4;
    int kc = rest % nkc, rt = rest / nkc;
    int row = rt * 32 + l31, col = kc * 16 + half * 8 + j;
    wp[i] = __float2bfloat16(w[(size_t)row * C + col]);
}

// ---------------- conv weight prep (MFMA B-fragment order, bf16) ----------------
__global__ void k_wp1(const float* __restrict__ w, __hip_bfloat16* __restrict__ wp) {
    int i = blockIdx.x * 256 + threadIdx.x;
    if (i >= 331776) return;
    int j = i & 7, oc = (i >> 3) & 63, h = (i >> 9) & 1;
    int cg = (i >> 10) % 12, kk = i / 12288;
    int c = cg * 16 + h * 8 + j;
    wp[i] = __float2bfloat16(w[((size_t)oc * 192 + c) * 27 + kk]);
}
__global__ void k_wp2(const float* __restrict__ w, __hip_bfloat16* __restrict__ wp) {
    int i = blockIdx.x * 256 + threadIdx.x;
    if (i >= 331776) return;
    int j = i & 7, oc = (i >> 3) % 192;
    int h = (i / 1536) & 1, cg = (i / 3072) & 3, kk = i / 12288;
    int c = cg * 16 + h * 8 + j;
    wp[i] = __float2bfloat16(w[((size_t)oc * 64 + c) * 27 + kk]);
}

// ---------------- bias precompute: biasT[h][m][n] = rpb[rpi[n][m]*6+h] ----------------
__global__ __launch_bounds__(256) void k_bias(const int* __restrict__ rpi,
                                              const float* __restrict__ rpb,
                                              float* __restrict__ biasT) {
    __shared__ int idxl[64][64];
    int tid = threadIdx.x;
    int n0 = (blockIdx.x >> 3) * 64, m0 = (blockIdx.x & 7) * 64;
    for (int it = 0; it < 16; it++) {
        int e = it * 256 + tid;
        int ln_ = e >> 6, lm = e & 63;
        idxl[ln_][lm] = rpi[(size_t)(n0 + ln_) * NTOKW + m0 + lm];
    }
    __syncthreads();
    for (int it = 0; it < 16; it++) {
        int e = it * 256 + tid;
        int lm = e >> 6, ln_ = e & 63;
        int id = idxl[ln_][lm];
        #pragma unroll
        for (int h = 0; h < NHEAD; h++)
            biasT[(size_t)h * NTOKW * NTOKW + (size_t)(m0 + lm) * NTOKW + n0 + ln_] =
                rpb[id * NHEAD + h];
    }
}

// ---------------- conv1 MFMA ----------------
__global__ __launch_bounds__(256) void k_conv1m(const __hip_bfloat16* __restrict__ xnbf,
                                                const __hip_bfloat16* __restrict__ w1p,
                                                const float* __restrict__ b1,
                                                __hip_bfloat16* __restrict__ h1bf) {
    __shared__ __align__(16) char lds[66 * 384];
    int tid = threadIdx.x;
    int wv = tid >> 6, lane = tid & 63;
    int wr = wv >> 1, wc = wv & 1;
    int half = lane >> 5, l31 = lane & 31;
    int row = blockIdx.x;
    int d = row >> 6, hh = row & 63;

    if (tid < 48) {
        float4 z = {0.f, 0.f, 0.f, 0.f};
        char* p = lds + ((tid < 24) ? tid * 16 : 65 * 384 + (tid - 24) * 16);
        *(float4*)p = z;
    }

    f32x16 acc;
    #pragma unroll
    for (int r = 0; r < 16; r++) acc[r] = 0.f;

    for (int kd = -1; kd <= 1; kd++) {
        int dd = d + kd;
        if (dd < 0 || dd >= DD_) continue;
        for (int kh = -1; kh <= 1; kh++) {
            int h2 = hh + kh;
            if (h2 < 0 || h2 >= HH_) continue;
            const short* src = (const short*)xnbf + ((size_t)((dd << 12) | (h2 << 6))) * CDIM;
            __syncthreads();
            #pragma unroll
            for (int it = 0; it < 6; it++) {
                int e16 = it * 256 + tid;
                int tok = e16 / 24, cb = (e16 % 24) * 16;
                short8v vdat = *(const short8v*)(src + e16 * 8);
                int lrow = tok + 1;
                *(short8v*)(lds + lrow * 384 + (cb ^ ((lrow & 7) << 4))) = vdat;
            }
            __syncthreads();
            #pragma unroll
            for (int kw = -1; kw <= 1; kw++) {
                int kk = (kd + 1) * 9 + (kh + 1) * 3 + (kw + 1);
                int atok = 32 * wr + l31 + kw + 1;
                int akey = (atok & 7) << 4;
                const char* abase = lds + atok * 384;
                const short* wbase = (const short*)w1p + (kk * 24 + half) * 512 + (32 * wc + l31) * 8;
                #pragma unroll
                for (int cg = 0; cg < 12; cg++) {
                    short8v af = *(const short8v*)(abase + ((cg * 32 + half * 16) ^ akey));
                    short8v bf = *(const short8v*)(wbase + cg * 1024);
                    acc = __builtin_amdgcn_mfma_f32_32x32x16_bf16(af, bf, acc, 0, 0, 0);
                }
            }
        }
    }
    int oc = 32 * wc + l31;
    float bb = b1[oc];
    int t0 = row * 64;
    #pragma unroll
    for (int r = 0; r < 16; r++) {
        int tok = 32 * wr + (r & 3) + 8 * (r >> 2) + 4 * half;
        h1bf[(size_t)(t0 + tok) * C3 + oc] = __float2bfloat16(gelu_exact(acc[r] + bb));
    }
}

// ---------------- conv2 MFMA ----------------
__global__ __launch_bounds__(384) void k_conv2m(const __hip_bfloat16* __restrict__ h1bf,
                                                const __hip_bfloat16* __restrict__ w2p,
                                                const float* __restrict__ b2,
                                                float* __restrict__ h2) {
    __shared__ __align__(16) char lds[34 * 128];
    int tid = threadIdx.x;
    int wv = tid >> 6, lane = tid & 63;
    int half = lane >> 5, l31 = lane & 31;
    int row = blockIdx.x >> 1, hr = blockIdx.x & 1;
    int d = row >> 6, hh = row & 63;

    f32x16 acc;
    #pragma unroll
    for (int r = 0; r < 16; r++) acc[r] = 0.f;

    for (int kd = -1; kd <= 1; kd++) {
        int dd = d + kd;
        if (dd < 0 || dd >= DD_) continue;
        for (int kh = -1; kh <= 1; kh++) {
            int h2r = hh + kh;
            if (h2r < 0 || h2r >= HH_) continue;
            __syncthreads();
            if (tid < 272) {
                int ti = tid >> 3, cb = (tid & 7) * 16;
                int w = hr * 32 + ti - 1;
                short8v vdat = {0, 0, 0, 0, 0, 0, 0, 0};
                if (w >= 0 && w < 64)
                    vdat = *(const short8v*)((const short*)h1bf +
                           (size_t)((dd << 12) | (h2r << 6) | w) * C3 + cb / 2);
                *(short8v*)(lds + ti * 128 + (cb ^ ((ti & 7) << 4))) = vdat;
            }
            __syncthreads();
            #pragma unroll
            for (int kw = -1; kw <= 1; kw++) {
                int kk = (kd + 1) * 9 + (kh + 1) * 3 + (kw + 1);
                int atok = l31 + kw + 1;
                int akey = (atok & 7) << 4;
                const char* abase = lds + atok * 128;
                const short* wbase = (const short*)w2p + (kk * 8 + half) * 1536 + (wv * 32 + l31) * 8;
                #pragma unroll
                for (int cg = 0; cg < 4; cg++) {
                    short8v af = *(const short8v*)(abase + ((cg * 32 + half * 16) ^ akey));
                    short8v bf = *(const short8v*)(wbase + cg * 3072);
                    acc = __builtin_amdgcn_mfma_f32_32x32x16_bf16(af, bf, acc, 0, 0, 0);
                }
            }
        }
    }
    int oc = wv * 32 + l31;
    float bb = b2[oc];
    int t0 = row * 64 + hr * 32;
    #pragma unroll
    for (int r = 0; r < 16; r++) {
        int tok = (r & 3) + 8 * (r >> 2) + 4 * half;
        h2[(size_t)(t0 + tok) * CDIM + oc] = acc[r] + bb;
    }
}

// ---------------- pooled partial sums ----------------
__global__ __launch_bounds__(192) void k_pool(const float* __restrict__ h2,
                                              float* __restrict__ part) {
    int c = threadIdx.x, b = blockIdx.x;
    float s = 0.f;
    for (int i = 0; i < 128; i++) s += h2[(size_t)(b * 128 + i) * CDIM + c];
    part[b * CDIM + c] = s;
}

// ---------------- channel attention MLP -> amask[192] ----------------
__global__ __launch_bounds__(192) void k_ca(const float* __restrict__ part,
                                            const float* __restrict__ ca1w,
                                            const float* __restrict__ ca1b,
                                            const float* __restrict__ ca2w,
                                            const float* __restrict__ ca2b,
                                            float* __restrict__ amask) {
    __shared__ float pooled[CDIM];
    __shared__ float hid[6];
    int c = threadIdx.x;
    float s = 0.f;
    for (int b = 0; b < 256; b++) s += part[b * CDIM + c];
    pooled[c] = s * (1.0f / 32768.0f);
    __syncthreads();
    if (c < 6) {
        float a = ca1b[c];
        for (int j = 0; j < CDIM; j++) a += ca1w[c * CDIM + j] * pooled[j];
        hid[c] = fmaxf(a, 0.f);
    }
    __syncthreads();
    float a = ca2b[c];
    for (int j = 0; j < 6; j++) a += ca2w[c * 6 + j] * hid[j];
    amask[c] = 1.0f / (1.0f + expf(-a));
}

// ---------------- qkv MFMA: 3 waves (q/k/v), 32 window-ordered tokens ----------------
__global__ __launch_bounds__(192) void k_qkvm(const __hip_bfloat16* __restrict__ xnbf,
                                              const __hip_bfloat16* __restrict__ qwb, // packed
                                              const float* __restrict__ qkvb,
                                              __hip_bfloat16* __restrict__ q,
                                              __hip_bfloat16* __restrict__ k,
                                              __hip_bfloat16* __restrict__ v) {
    __shared__ __align__(16) char xlds[32 * 384];
    __shared__ float tb[3][32][33];
    int tid = threadIdx.x;
    int wv = tid >> 6, lane = tid & 63;
    int half = lane >> 5, l31 = lane & 31;
    int t0 = blockIdx.x * 32;
    int wi = t0 >> 9;
    int wh_ = wi >> 3, ww_ = wi & 7;

    #pragma unroll
    for (int it = 0; it < 4; it++) {
        int e16 = it * 192 + tid;        // 0..767
        int tok = e16 / 24, cb = (e16 % 24) * 16;
        int n = (t0 + tok) & 511;
        int nd = n >> 6, nh = (n >> 3) & 7, nw = n & 7;
        int torig = (nd << 12) | ((wh_ * 8 + nh) << 6) | (ww_ * 8 + nw);
        short8v vdat = *(const short8v*)((const short*)xnbf + (size_t)torig * CDIM + (e16 % 24) * 8);
        *(short8v*)(xlds + tok * 384 + (cb ^ ((tok & 7) << 4))) = vdat;
    }
    __syncthreads();

    int akey = (l31 & 7) << 4;
    const char* xbase = xlds + l31 * 384;
    __hip_bfloat16* dstbase = (wv == 0) ? q : (wv == 1 ? k : v);
    float scale = (wv == 0) ? 0.17677669529663687f : 1.0f;

    for (int j = 0; j < 6; j++) {
        int ti = wv * 6 + j;             // wave owns one output type
        f32x16 a0, a1;
        #pragma unroll
        for (int r = 0; r < 16; r++) { a0[r] = 0.f; a1[r] = 0.f; }
        const short* wbase = (const short*)qwb + ti * 6144 + half * 256 + l31 * 8;
        #pragma unroll
        for (int cg = 0; cg < 12; cg += 2) {
            short8v bf0 = *(const short8v*)(xbase + ((cg * 32 + half * 16) ^ akey));
            short8v bf1 = *(const short8v*)(xbase + (((cg + 1) * 32 + half * 16) ^ akey));
            short8v af0 = *(const short8v*)(wbase + cg * 512);
            short8v af1 = *(const short8v*)(wbase + (cg + 1) * 512);
            a0 = __builtin_amdgcn_mfma_f32_32x32x16_bf16(af0, bf0, a0, 0, 0, 0);
            a1 = __builtin_amdgcn_mfma_f32_32x32x16_bf16(af1, bf1, a1, 0, 0, 0);
        }
        #pragma unroll
        for (int r = 0; r < 16; r++) {
            int dl = (r & 3) + 8 * (r >> 2) + 4 * half;
            tb[wv][l31][dl] = a0[r] + a1[r];
        }
        asm volatile("s_waitcnt lgkmcnt(0)" ::: "memory");
        __builtin_amdgcn_sched_barrier(0);
        int tok = lane >> 1, d0 = (lane & 1) * 16;
        int n = (t0 + tok) & 511;
        __hip_bfloat16* dst = dstbase +
                              ((size_t)((wi * NHEAD + j) * NTOKW + n)) * HDIM + d0;
        const float* bp = qkvb + ti * 32 + d0;
        short8v o0, o1;
        #pragma unroll
        for (int i = 0; i < 8; i++)
            o0[i] = (short)bf16bits((tb[wv][tok][d0 + i] + bp[i]) * scale);
        #pragma unroll
        for (int i = 0; i < 8; i++)
            o1[i] = (short)bf16bits((tb[wv][tok][d0 + 8 + i] + bp[8 + i]) * scale);
        *(short8v*)((short*)dst) = o0;
        *(short8v*)((short*)dst + 8) = o1;
        asm volatile("s_waitcnt lgkmcnt(0)" ::: "memory");
        __builtin_amdgcn_sched_barrier(0);
    }
}

// ---------------- MFMA flash attention (bf16 output) ----------------
__global__ __launch_bounds__(256) void k_attn(const __hip_bfloat16* __restrict__ qh,
                                              const __hip_bfloat16* __restrict__ kh,
                                              const __hip_bfloat16* __restrict__ vh,
                                              const float* __restrict__ biasT,
                                              __hip_bfloat16* __restrict__ outbf) {
    __shared__ float ot[4][32][33];
    int wv = threadIdx.x >> 6, lane = threadIdx.x & 63;
    int tile = blockIdx.x * 4 + wv;
    int qt = tile & 15, wh = tile >> 4;
    int head = wh % NHEAD, wi = wh / NHEAD;
    int qb = qt * 32;
    int h = lane >> 5, ln31 = lane & 31;

    const unsigned short* qp = (const unsigned short*)qh + ((size_t)wh * NTOKW + qb + ln31) * HDIM;
    short8v qf0 = *(const short8v*)(qp + 8 * h);
    short8v qf1 = *(const short8v*)(qp + 16 + 8 * h);
    const unsigned short* kbase = (const unsigned short*)kh + (size_t)wh * NTOKW * HDIM;
    const unsigned short* vbase = (const unsigned short*)vh + (size_t)wh * NTOKW * HDIM;
    const float* bbase = biasT + (size_t)head * NTOKW * NTOKW + qb + ln31;

    f32x16 O;
    #pragma unroll
    for (int r = 0; r < 16; r++) O[r] = 0.f;
    float m = -1e30f, l = 0.f;

    for (int kb = 0; kb < NTOKW; kb += 32) {
        const unsigned short* kp = kbase + (size_t)(kb + ln31) * HDIM;
        short8v kf0 = *(const short8v*)(kp + 8 * h);
        short8v kf1 = *(const short8v*)(kp + 16 + 8 * h);
        f32x16 S;
        #pragma unroll
        for (int r = 0; r < 16; r++) S[r] = 0.f;
        S = __builtin_amdgcn_mfma_f32_32x32x16_bf16(kf0, qf0, S, 0, 0, 0);
        S = __builtin_amdgcn_mfma_f32_32x32x16_bf16(kf1, qf1, S, 0, 0, 0);

        float s[16];
        #pragma unroll
        for (int r = 0; r < 16; r++) {
            int key = (r & 3) + 8 * (r >> 2) + 4 * h;
            s[r] = S[r] + bbase[(size_t)(kb + key) * NTOKW];
        }
        float cm = s[0];
        #pragma unroll
        for (int r = 1; r < 16; r++) cm = fmaxf(cm, s[r]);
        cm = fmaxf(cm, __shfl_xor(cm, 32));
        float mn = fmaxf(m, cm);
        float scale = __expf(m - mn);
        float e[16]; float cs = 0.f;
        #pragma unroll
        for (int r = 0; r < 16; r++) { e[r] = __expf(s[r] - mn); cs += e[r]; }
        cs += __shfl_xor(cs, 32);
        l = l * scale + cs;
        m = mn;
        #pragma unroll
        for (int r = 0; r < 16; r++) O[r] *= scale;

        unsigned P[8], Qx[8];
        #pragma unroll
        for (int i = 0; i < 8; i++)
            P[i] = (unsigned)bf16bits(e[2 * i]) | ((unsigned)bf16bits(e[2 * i + 1]) << 16);
        #pragma unroll
        for (int i = 0; i < 8; i++) Qx[i] = __shfl_xor(P[i], 32);

        FragU p0, p1;
        p0.u[0] = h ? Qx[2] : P[0];  p0.u[1] = h ? Qx[3] : P[1];
        p0.u[2] = h ? P[2]  : Qx[0]; p0.u[3] = h ? P[3]  : Qx[1];
        p1.u[0] = h ? Qx[6] : P[4];  p1.u[1] = h ? Qx[7] : P[5];
        p1.u[2] = h ? P[6]  : Qx[4]; p1.u[3] = h ? P[7]  : Qx[5];

        const unsigned short* vp0 = vbase + (size_t)(kb + 8 * h) * HDIM + ln31;
        const unsigned short* vp1 = vbase + (size_t)(kb + 16 + 8 * h) * HDIM + ln31;
        short8v vf0, vf1;
        #pragma unroll
        for (int i = 0; i < 8; i++) {
            vf0[i] = (short)vp0[i * HDIM];
            vf1[i] = (short)vp1[i * HDIM];
        }
        O = __builtin_amdgcn_mfma_f32_32x32x16_bf16(vf0, p0.v, O, 0, 0, 0);
        O = __builtin_amdgcn_mfma_f32_32x32x16_bf16(vf1, p1.v, O, 0, 0, 0);
    }

    float invl = 1.0f / l;
    #pragma unroll
    for (int r = 0; r < 16; r++) {
        int d = (r & 3) + 8 * (r >> 2) + 4 * h;
        ot[wv][ln31][d] = O[r] * invl;
    }
    __syncthreads();
    int t2 = lane >> 1, c0 = (lane & 1) * 16;
    short* outp = (short*)outbf + ((size_t)(wi * NTOKW + qb + t2)) * CDIM + head * HDIM + c0;
    short8v s0, s1;
    #pragma unroll
    for (int i = 0; i < 8; i++) s0[i] = (short)bf16bits(ot[wv][t2][c0 + i]);
    #pragma unroll
    for (int i = 0; i < 8; i++) s1[i] = (short)bf16bits(ot[wv][t2][c0 + 8 + i]);
    *(short8v*)outp = s0;
    *(short8v*)(outp + 8) = s1;
}

// ---------------- proj MFMA + residual + conv merge: 3 waves, 2 tiles each ----------------
__global__ __launch_bounds__(192) void k_projm(const __hip_bfloat16* __restrict__ attnbf,
                                               const __hip_bfloat16* __restrict__ pwb, // packed
                                               const float* __restrict__ pb,
                                               const float* __restrict__ x,
                                               const float* __restrict__ h2,
                                               const float* __restrict__ amask,
                                               float* __restrict__ x2) {
    __shared__ __align__(16) char alds[32 * 384];
    __shared__ float tb[3][32][33];
    int tid = threadIdx.x;
    int wv = tid >> 6, lane = tid & 63;
    int half = lane >> 5, l31 = lane & 31;
    int t0 = blockIdx.x * 32;
    int wi = t0 >> 9;
    int wh_ = wi >> 3, ww_ = wi & 7;

    const short* src = (const short*)attnbf + (size_t)t0 * CDIM;
    #pragma unroll
    for (int it = 0; it < 4; it++) {
        int e16 = it * 192 + tid;
        int tok = e16 / 24, cb = (e16 % 24) * 16;
        short8v vdat = *(const short8v*)(src + e16 * 8);
        *(short8v*)(alds + tok * 384 + (cb ^ ((tok & 7) << 4))) = vdat;
    }
    __syncthreads();

    int akey = (l31 & 7) << 4;
    const char* abase = alds + l31 * 384;

    for (int j = 0; j < 2; j++) {
        int ot = wv * 2 + j;
        f32x16 a0, a1;
        #pragma unroll
        for (int r = 0; r < 16; r++) { a0[r] = 0.f; a1[r] = 0.f; }
        const short* wbase = (const short*)pwb + ot * 6144 + half * 256 + l31 * 8;
        #pragma unroll
        for (int cg = 0; cg < 12; cg += 2) {
            short8v bf0 = *(const short8v*)(abase + ((cg * 32 + half * 16) ^ akey));
            short8v bf1 = *(const short8v*)(abase + (((cg + 1) * 32 + half * 16) ^ akey));
            short8v af0 = *(const short8v*)(wbase + cg * 512);
            short8v af1 = *(const short8v*)(wbase + (cg + 1) * 512);
            a0 = __builtin_amdgcn_mfma_f32_32x32x16_bf16(af0, bf0, a0, 0, 0, 0);
            a1 = __builtin_amdgcn_mfma_f32_32x32x16_bf16(af1, bf1, a1, 0, 0, 0);
        }
        #pragma unroll
        for (int r = 0; r < 16; r++) {
            int oc = (r & 3) + 8 * (r >> 2) + 4 * half;
            tb[wv][l31][oc] = a0[r] + a1[r];
        }
        asm volatile("s_waitcnt lgkmcnt(0)" ::: "memory");
        __builtin_amdgcn_sched_barrier(0);
        int tok = lane >> 1, c0 = (lane & 1) * 16;
        int n = (t0 + tok) & 511;
        int nd = n >> 6, nh = (n >> 3) & 7, nw = n & 7;
        int t = (nd << 12) | ((wh_ * 8 + nh) << 6) | (ww_ * 8 + nw);
        size_t idx = (size_t)t * CDIM + ot * 32 + c0;
        const float* bp = pb + ot * 32 + c0;
        const float* ap = amask + ot * 32 + c0;
        #pragma unroll
        for (int i = 0; i < 16; i++)
            x2[idx + i] = x[idx + i] + tb[wv][tok][c0 + i] + bp[i] + 0.01f * h2[idx + i] * ap[i];
        asm volatile("s_waitcnt lgkmcnt(0)" ::: "memory");
        __builtin_amdgcn_sched_barrier(0);
    }
}

// ---------------- fused MLP (MFMA): 4 waves, hc-split + LDS reduction ----------------
__global__ __launch_bounds__(256) void k_mlpm(const __hip_bfloat16* __restrict__ ybf,
                                              const __hip_bfloat16* __restrict__ w1b, // packed
                                              const float* __restrict__ b1,
                                              const __hip_bfloat16* __restrict__ w2b, // packed
                                              const float* __restrict__ b2,
                                              float* __restrict__ out) {
    __shared__ __align__(16) char ylds[32 * 384];       // 12 KB staging
    __shared__ __align__(16) float rbuf[6 * 32 * 32];   // 24 KB reduce/transpose
    int tid = threadIdx.x;
    int wv = tid >> 6, lane = tid & 63;
    int half = lane >> 5, l31 = lane & 31;
    int t0 = blockIdx.x * 32;

    const short* src = (const short*)ybf + (size_t)t0 * CDIM;
    #pragma unroll
    for (int it = 0; it < 3; it++) {
        int e16 = it * 256 + tid;      // 0..767
        int tok = e16 / 24, cb = (e16 % 24) * 16;
        short8v vdat = *(const short8v*)(src + e16 * 8);
        *(short8v*)(ylds + tok * 384 + (cb ^ ((tok & 7) << 4))) = vdat;
    }
    __syncthreads();

    int akey = (l31 & 7) << 4;
    const char* ybase = ylds + l31 * 384;

    f32x16 oacc[6];
    #pragma unroll
    for (int ot = 0; ot < 6; ot++)
        #pragma unroll
        for (int r = 0; r < 16; r++) oacc[ot][r] = 0.f;

    // each wave handles 6 of the 24 hidden chunks
    for (int j = 0; j < 6; j++) {
        int hc = wv * 6 + j;
        f32x16 h0, h1;
        #pragma unroll
        for (int r = 0; r < 16; r++) { h0[r] = 0.f; h1[r] = 0.f; }
        const short* w1base = (const short*)w1b + hc * 6144 + half * 256 + l31 * 8;
        #pragma unroll
        for (int cg = 0; cg < 12; cg += 2) {
            short8v bf0 = *(const short8v*)(ybase + ((cg * 32 + half * 16) ^ akey));
            short8v bf1 = *(const short8v*)(ybase + (((cg + 1) * 32 + half * 16) ^ akey));
            short8v af0 = *(const short8v*)(w1base + cg * 512);
            short8v af1 = *(const short8v*)(w1base + (cg + 1) * 512);
            h0 = __builtin_amdgcn_mfma_f32_32x32x16_bf16(af0, bf0, h0, 0, 0, 0);
            h1 = __builtin_amdgcn_mfma_f32_32x32x16_bf16(af1, bf1, h1, 0, 0, 0);
        }
        float e[16];
        #pragma unroll
        for (int r = 0; r < 16; r++) {
            int hid = (r & 3) + 8 * (r >> 2) + 4 * half;
            e[r] = gelu_exact(h0[r] + h1[r] + b1[hc * 32 + hid]);
        }
        unsigned P[8], Qx[8];
        #pragma unroll
        for (int i = 0; i < 8; i++)
            P[i] = (unsigned)bf16bits(e[2 * i]) | ((unsigned)bf16bits(e[2 * i + 1]) << 16);
        #pragma unroll
        for (int i = 0; i < 8; i++) Qx[i] = __shfl_xor(P[i], 32);
        FragU p0, p1;
        p0.u[0] = half ? Qx[2] : P[0];  p0.u[1] = half ? Qx[3] : P[1];
        p0.u[2] = half ? P[2]  : Qx[0]; p0.u[3] = half ? P[3]  : Qx[1];
        p1.u[0] = half ? Qx[6] : P[4];  p1.u[1] = half ? Qx[7] : P[5];
        p1.u[2] = half ? P[6]  : Qx[4]; p1.u[3] = half ? P[7]  : Qx[5];

        // packed fc2: a0 at kc=2*hc, a1 at kc=2*hc+1; tile ot stride 24576
        const short* w2base = (const short*)w2b + hc * 1024 + half * 256 + l31 * 8;
        #pragma unroll
        for (int ot = 0; ot < 6; ot++) {
            short8v a0 = *(const short8v*)(w2base + ot * 24576);
            short8v a1 = *(const short8v*)(w2base + ot * 24576 + 512);
            oacc[ot] = __builtin_amdgcn_mfma_f32_32x32x16_bf16(a0, p0.v, oacc[ot], 0, 0, 0);
            oacc[ot] = __builtin_amdgcn_mfma_f32_32x32x16_bf16(a1, p1.v, oacc[ot], 0, 0, 0);
        }
    }

    // barrier-sequenced float4 reduction into rbuf
    float4* rb4 = (float4*)rbuf;
    for (int w = 0; w < 4; w++) {
        if (wv == w) {
            #pragma unroll
            for (int ot = 0; ot < 6; ot++) {
                #pragma unroll
                for (int g = 0; g < 4; g++) {
                    float4 val = {oacc[ot][g * 4 + 0], oacc[ot][g * 4 + 1],
                                  oacc[ot][g * 4 + 2], oacc[ot][g * 4 + 3]};
                    int chunk = 2 * g + half;          // oc quad index within 32-ch tile
                    float4* p = &rb4[(ot * 32 + l31) * 8 + (chunk ^ (l31 & 7))];
                    if (w == 0) *p = val;
                    else {
                        float4 o = *p;
                        o.x += val.x; o.y += val.y; o.z += val.z; o.w += val.w;
                        *p = o;
                    }
                }
            }
        }
        __syncthreads();
    }

    // final coalesced write: out += rbuf + b2
    #pragma unroll
    for (int i = 0; i < 6; i++) {
        int c4 = i * 256 + tid;                // 0..1535 float4 chunks
        int oc4 = c4 & 7;
        int tok = (c4 >> 3) & 31;
        int ot  = c4 >> 8;
        float4 vv = rb4[(ot * 32 + tok) * 8 + (oc4 ^ (tok & 7))];
        float* op = out + (size_t)(t0 + tok) * CDIM + ot * 32 + oc4 * 4;
        const float* bp = b2 + ot * 32 + oc4 * 4;
        op[0] += vv.x + bp[0];
        op[1] += vv.y + bp[1];
        op[2] += vv.z + bp[2];
        op[3] += vv.w + bp[3];
    }
}

// ---------------- launcher ----------------
extern "C" void kernel_launch(void* const* d_in, const int* in_sizes, int n_in,
                              void* d_out, int out_size, void* d_ws, size_t ws_size,
                              hipStream_t stream) {
    const float* x     = (const float*)d_in[0];
    const float* n1g   = (const float*)d_in[1];
    const float* n1b   = (const float*)d_in[2];
    const float* qkvw  = (const float*)d_in[3];
    const float* qkvb  = (const float*)d_in[4];
    const float* rpb   = (const float*)d_in[5];
    const float* projw = (const float*)d_in[6];
    const float* projb = (const float*)d_in[7];
    const float* c1w   = (const float*)d_in[8];
    const float* c1b   = (const float*)d_in[9];
    const float* c2w   = (const float*)d_in[10];
    const float* c2b   = (const float*)d_in[11];
    const float* ca1w  = (const float*)d_in[12];
    const float* ca1b  = (const float*)d_in[13];
    const float* ca2w  = (const float*)d_in[14];
    const float* ca2b  = (const float*)d_in[15];
    const float* n2g   = (const float*)d_in[16];
    const float* n2b   = (const float*)d_in[17];
    const float* fc1w  = (const float*)d_in[18];
    const float* fc1b  = (const float*)d_in[19];
    const float* fc2w  = (const float*)d_in[20];
    const float* fc2b  = (const float*)d_in[21];
    const int*   rpi   = (const int*)d_in[22];

    float* ws  = (float*)d_ws;
    float* out = (float*)d_out;

    __hip_bfloat16* attnbf = (__hip_bfloat16*)(ws + OFF_XN);
    __hip_bfloat16* qh   = (__hip_bfloat16*)(ws + OFF_QH);
    __hip_bfloat16* kb_  = (__hip_bfloat16*)(ws + OFF_KH);
    __hip_bfloat16* vb_  = (__hip_bfloat16*)(ws + OFF_VH);
    __hip_bfloat16* xnbf = (__hip_bfloat16*)(ws + OFF_Y);
    __hip_bfloat16* ybf  = (__hip_bfloat16*)(ws + OFF_YBF);
    __hip_bfloat16* h1bf = (__hip_bfloat16*)(ws + OFF_H1);
    float* h2    = ws + OFF_H2;
    float* part  = ws + OFF_PART;
    float* amask = ws + OFF_AMASK;
    float* biasT = ws + OFF_BIAST;
    __hip_bfloat16* w1p  = (__hip_bfloat16*)(ws + OFF_W1T);
    __hip_bfloat16* w2p  = (__hip_bfloat16*)(ws + OFF_W2T);
    __hip_bfloat16* qwb  = (__hip_bfloat16*)(ws + OFF_QKVT);
    __hip_bfloat16* pwb  = (__hip_bfloat16*)(ws + OFF_PROJT);
    __hip_bfloat16* w1b  = (__hip_bfloat16*)(ws + OFF_FC1T);
    __hip_bfloat16* w2b  = (__hip_bfloat16*)(ws + OFF_FC2T);

    // weight prep (fragment-packed, coalesced) + bias table
    k_wp1<<<(331776 + 255) / 256, 256, 0, stream>>>(c1w, w1p);
    k_wp2<<<(331776 + 255) / 256, 256, 0, stream>>>(c2w, w2p);
    k_wpack<<<(110592 + 255) / 256, 256, 0, stream>>>(qkvw, qwb, 576, 192);
    k_wpack<<<(36864 + 255) / 256, 256, 0, stream>>>(projw, pwb, 192, 192);
    k_wpack<<<(147456 + 255) / 256, 256, 0, stream>>>(fc1w, w1b, 768, 192);
    k_wpack<<<(147456 + 255) / 256, 256, 0, stream>>>(fc2w, w2b, 192, 768);
    k_bias<<<64, 256, 0, stream>>>(rpi, rpb, biasT);

    // LN1 (bf16 only)
    k_ln<<<LTOK / 4, 256, 0, stream>>>(x, n1g, n1b, (float*)nullptr, xnbf);
    // conv branch (MFMA)
    k_conv1m<<<512, 256, 0, stream>>>(xnbf, w1p, c1b, h1bf);
    k_conv2m<<<1024, 384, 0, stream>>>(h1bf, w2p, c2b, h2);
    k_pool<<<256, 192, 0, stream>>>(h2, part);
    k_ca<<<1, 192, 0, stream>>>(part, ca1w, ca1b, ca2w, ca2b, amask);
    // attention branch (MFMA)
    k_qkvm<<<LTOK / 32, 192, 0, stream>>>(xnbf, qwb, qkvb, qh, kb_, vb_);
    k_attn<<<(NWIN * NHEAD * 16) / 4, 256, 0, stream>>>(qh, kb_, vb_, biasT, attnbf);
    k_projm<<<LTOK / 32, 192, 0, stream>>>(attnbf, pwb, projb, x, h2, amask, out);
    // LN2 (bf16 only) + fused MFMA MLP
    k_ln<<<LTOK / 4, 256, 0, stream>>>(out, n2g, n2b, (float*)nullptr, ybf);
    k_mlpm<<<LTOK / 32, 256, 0, stream>>>(ybf, w1b, fc1b, w2b, fc2b, out);
}

// Round 11
// 382.905 us; speedup vs baseline: 18.4300x; 1.0037x over previous
//
#include <hip/hip_runtime.h>
#include <hip/hip_bf16.h>

// ---------------- problem constants ----------------
#define LTOK  32768   // D*H*W
#define CDIM  192
#define DD_   8
#define HH_   64
#define WW_   64
#define NHEAD 6
#define HDIM  32
#define NWIN  64      // (D/8)*(H/8)*(W/8)
#define NTOKW 512     // tokens per window
#define C3    64      // C/3
#define FCH   768     // 4*C

// ws layout (float32-slot offsets)
#define OFF_XN     0u          // attn-out bf16
#define OFF_QH     6291456u
#define OFF_KH     9437184u
#define OFF_VH     12582912u
#define OFF_Y      15728640u   // xnbf
#define OFF_YBF    18874368u   // ybf
#define OFF_H1     22020096u   // h1 bf16
#define OFF_H2     24117248u   // h2 f32
#define OFF_PART   30408704u
#define OFF_AMASK  30457856u
#define OFF_BIAST  30458048u
#define OFF_W1T    32030912u
#define OFF_W2T    32362688u
#define OFF_QKVT   32694464u
#define OFF_PROJT  32805056u
#define OFF_FC1T   32841920u
#define OFF_FC2T   32989376u

typedef __attribute__((ext_vector_type(8)))  short short8v;
typedef __attribute__((ext_vector_type(16))) float f32x16;

union FragU { short8v v; unsigned u[4]; };

// tanh-form gelu via exp: |diff vs erf-gelu| < 2e-3 anywhere, < 2e-4 for |x|<1
__device__ __forceinline__ float gelu_fast(float x) {
    float z = 0.7978845608028654f * (x + 0.044715f * x * x * x);
    float e = __expf(2.0f * z);
    float t = 1.0f - 2.0f / (e + 1.0f);
    return 0.5f * x * (1.0f + t);
}

__device__ __forceinline__ unsigned short bf16bits(float x) {
    union { __hip_bfloat16 b; unsigned short u; } cv;
    cv.b = __float2bfloat16(x);
    return cv.u;
}

// ---------------- LayerNorm: 1 wave per token; f32 and/or bf16 out ----------------
__global__ __launch_bounds__(256) void k_ln(const float* __restrict__ in,
                                            const float* __restrict__ g,
                                            const float* __restrict__ b,
                                            float* __restrict__ out,
                                            __hip_bfloat16* __restrict__ obf) {
    int wv = threadIdx.x >> 6, lane = threadIdx.x & 63;
    int t = blockIdx.x * 4 + wv;
    const float* row = in + (size_t)t * CDIM;
    float x0 = row[lane], x1 = row[lane + 64], x2 = row[lane + 128];
    float s = x0 + x1 + x2;
    for (int o = 32; o; o >>= 1) s += __shfl_xor(s, o);
    float m = s * (1.0f / 192.0f);
    float d0 = x0 - m, d1 = x1 - m, d2 = x2 - m;
    float vv = d0 * d0 + d1 * d1 + d2 * d2;
    for (int o = 32; o; o >>= 1) vv += __shfl_xor(vv, o);
    float inv = rsqrtf(vv * (1.0f / 192.0f) + 1e-5f);
    size_t base = (size_t)t * CDIM;
    float y0 = d0 * inv * g[lane]       + b[lane];
    float y1 = d1 * inv * g[lane + 64]  + b[lane + 64];
    float y2 = d2 * inv * g[lane + 128] + b[lane + 128];
    if (out) {
        out[base + lane]       = y0;
        out[base + lane + 64]  = y1;
        out[base + lane + 128] = y2;
    }
    if (obf) {
        obf[base + lane]       = __float2bfloat16(y0);
        obf[base + lane + 64]  = __float2bfloat16(y1);
        obf[base + lane + 128] = __float2bfloat16(y2);
    }
}

// ---------------- merged weight prep (all 6 matrices, one dispatch) ----------------
__device__ __forceinline__ void wpack_one(const float* __restrict__ w,
                                          __hip_bfloat16* __restrict__ wp,
                                          int i, int C) {
    int j = i & 7, l31 = (i >> 3) & 31, half = (i >> 8) & 1;
    int rest = i >> 9;
    int nkc = C >> 4;
    int kc = rest % nkc, rt = rest / nkc;
    int row = rt * 32 + l31, col = kc * 16 + half * 8 + j;
    wp[i] = __float2bfloat16(w[(size_t)row * C + col]);
}

__global__ void k_prep(const float* __restrict__ c1w, const float* __restrict__ c2w,
                       const float* __restrict__ qkvw, const float* __restrict__ projw,
                       const float* __restrict__ fc1w, const float* __restrict__ fc2w,
                       __hip_bfloat16* __restrict__ w1p, __hip_bfloat16* __restrict__ w2p,
                       __hip_bfloat16* __restrict__ qwb, __hip_bfloat16* __restrict__ pwb,
                       __hip_bfloat16* __restrict__ w1b, __hip_bfloat16* __restrict__ w2b) {
    int i = blockIdx.x * 256 + threadIdx.x;
    if (i < 331776) {
        int j = i & 7, oc = (i >> 3) & 63, h = (i >> 9) & 1;
        int cg = (i >> 10) % 12, kk = i / 12288;
        int c = cg * 16 + h * 8 + j;
        w1p[i] = __float2bfloat16(c1w[((size_t)oc * 192 + c) * 27 + kk]);
    } else if (i < 663552) {
        int t = i - 331776;
        int j = t & 7, oc = (t >> 3) % 192;
        int h = (t / 1536) & 1, cg = (t / 3072) & 3, kk = t / 12288;
        int c = cg * 16 + h * 8 + j;
        w2p[t] = __float2bfloat16(c2w[((size_t)oc * 64 + c) * 27 + kk]);
    } else if (i < 774144) {
        wpack_one(qkvw, qwb, i - 663552, 192);
    } else if (i < 811008) {
        wpack_one(projw, pwb, i - 774144, 192);
    } else if (i < 958464) {
        wpack_one(fc1w, w1b, i - 811008, 192);
    } else if (i < 1105920) {
        wpack_one(fc2w, w2b, i - 958464, 768);
    }
}

// ---------------- bias precompute: biasT[h][m][n] = rpb[rpi[n][m]*6+h] ----------------
__global__ __launch_bounds__(256) void k_bias(const int* __restrict__ rpi,
                                              const float* __restrict__ rpb,
                                              float* __restrict__ biasT) {
    __shared__ int idxl[64][64];
    int tid = threadIdx.x;
    int n0 = (blockIdx.x >> 3) * 64, m0 = (blockIdx.x & 7) * 64;
    for (int it = 0; it < 16; it++) {
        int e = it * 256 + tid;
        int ln_ = e >> 6, lm = e & 63;
        idxl[ln_][lm] = rpi[(size_t)(n0 + ln_) * NTOKW + m0 + lm];
    }
    __syncthreads();
    for (int it = 0; it < 16; it++) {
        int e = it * 256 + tid;
        int lm = e >> 6, ln_ = e & 63;
        int id = idxl[ln_][lm];
        #pragma unroll
        for (int h = 0; h < NHEAD; h++)
            biasT[(size_t)h * NTOKW * NTOKW + (size_t)(m0 + lm) * NTOKW + n0 + ln_] =
                rpb[id * NHEAD + h];
    }
}

// ---------------- conv1 MFMA ----------------
__global__ __launch_bounds__(256) void k_conv1m(const __hip_bfloat16* __restrict__ xnbf,
                                                const __hip_bfloat16* __restrict__ w1p,
                                                const float* __restrict__ b1,
                                                __hip_bfloat16* __restrict__ h1bf) {
    __shared__ __align__(16) char lds[66 * 384];
    int tid = threadIdx.x;
    int wv = tid >> 6, lane = tid & 63;
    int wr = wv >> 1, wc = wv & 1;
    int half = lane >> 5, l31 = lane & 31;
    int row = blockIdx.x;
    int d = row >> 6, hh = row & 63;

    if (tid < 48) {
        float4 z = {0.f, 0.f, 0.f, 0.f};
        char* p = lds + ((tid < 24) ? tid * 16 : 65 * 384 + (tid - 24) * 16);
        *(float4*)p = z;
    }

    f32x16 acc;
    #pragma unroll
    for (int r = 0; r < 16; r++) acc[r] = 0.f;

    for (int kd = -1; kd <= 1; kd++) {
        int dd = d + kd;
        if (dd < 0 || dd >= DD_) continue;
        for (int kh = -1; kh <= 1; kh++) {
            int h2 = hh + kh;
            if (h2 < 0 || h2 >= HH_) continue;
            const short* src = (const short*)xnbf + ((size_t)((dd << 12) | (h2 << 6))) * CDIM;
            __syncthreads();
            #pragma unroll
            for (int it = 0; it < 6; it++) {
                int e16 = it * 256 + tid;
                int tok = e16 / 24, cb = (e16 % 24) * 16;
                short8v vdat = *(const short8v*)(src + e16 * 8);
                int lrow = tok + 1;
                *(short8v*)(lds + lrow * 384 + (cb ^ ((lrow & 7) << 4))) = vdat;
            }
            __syncthreads();
            #pragma unroll
            for (int kw = -1; kw <= 1; kw++) {
                int kk = (kd + 1) * 9 + (kh + 1) * 3 + (kw + 1);
                int atok = 32 * wr + l31 + kw + 1;
                int akey = (atok & 7) << 4;
                const char* abase = lds + atok * 384;
                const short* wbase = (const short*)w1p + (kk * 24 + half) * 512 + (32 * wc + l31) * 8;
                #pragma unroll
                for (int cg = 0; cg < 12; cg++) {
                    short8v af = *(const short8v*)(abase + ((cg * 32 + half * 16) ^ akey));
                    short8v bf = *(const short8v*)(wbase + cg * 1024);
                    acc = __builtin_amdgcn_mfma_f32_32x32x16_bf16(af, bf, acc, 0, 0, 0);
                }
            }
        }
    }
    int oc = 32 * wc + l31;
    float bb = b1[oc];
    int t0 = row * 64;
    #pragma unroll
    for (int r = 0; r < 16; r++) {
        int tok = 32 * wr + (r & 3) + 8 * (r >> 2) + 4 * half;
        h1bf[(size_t)(t0 + tok) * C3 + oc] = __float2bfloat16(gelu_fast(acc[r] + bb));
    }
}

// ---------------- conv2 MFMA ----------------
__global__ __launch_bounds__(384) void k_conv2m(const __hip_bfloat16* __restrict__ h1bf,
                                                const __hip_bfloat16* __restrict__ w2p,
                                                const float* __restrict__ b2,
                                                float* __restrict__ h2) {
    __shared__ __align__(16) char lds[34 * 128];
    int tid = threadIdx.x;
    int wv = tid >> 6, lane = tid & 63;
    int half = lane >> 5, l31 = lane & 31;
    int row = blockIdx.x >> 1, hr = blockIdx.x & 1;
    int d = row >> 6, hh = row & 63;

    f32x16 acc;
    #pragma unroll
    for (int r = 0; r < 16; r++) acc[r] = 0.f;

    for (int kd = -1; kd <= 1; kd++) {
        int dd = d + kd;
        if (dd < 0 || dd >= DD_) continue;
        for (int kh = -1; kh <= 1; kh++) {
            int h2r = hh + kh;
            if (h2r < 0 || h2r >= HH_) continue;
            __syncthreads();
            if (tid < 272) {
                int ti = tid >> 3, cb = (tid & 7) * 16;
                int w = hr * 32 + ti - 1;
                short8v vdat = {0, 0, 0, 0, 0, 0, 0, 0};
                if (w >= 0 && w < 64)
                    vdat = *(const short8v*)((const short*)h1bf +
                           (size_t)((dd << 12) | (h2r << 6) | w) * C3 + cb / 2);
                *(short8v*)(lds + ti * 128 + (cb ^ ((ti & 7) << 4))) = vdat;
            }
            __syncthreads();
            #pragma unroll
            for (int kw = -1; kw <= 1; kw++) {
                int kk = (kd + 1) * 9 + (kh + 1) * 3 + (kw + 1);
                int atok = l31 + kw + 1;
                int akey = (atok & 7) << 4;
                const char* abase = lds + atok * 128;
                const short* wbase = (const short*)w2p + (kk * 8 + half) * 1536 + (wv * 32 + l31) * 8;
                #pragma unroll
                for (int cg = 0; cg < 4; cg++) {
                    short8v af = *(const short8v*)(abase + ((cg * 32 + half * 16) ^ akey));
                    short8v bf = *(const short8v*)(wbase + cg * 3072);
                    acc = __builtin_amdgcn_mfma_f32_32x32x16_bf16(af, bf, acc, 0, 0, 0);
                }
            }
        }
    }
    int oc = wv * 32 + l31;
    float bb = b2[oc];
    int t0 = row * 64 + hr * 32;
    #pragma unroll
    for (int r = 0; r < 16; r++) {
        int tok = (r & 3) + 8 * (r >> 2) + 4 * half;
        h2[(size_t)(t0 + tok) * CDIM + oc] = acc[r] + bb;
    }
}

// ---------------- pooled partial sums ----------------
__global__ __launch_bounds__(192) void k_pool(const float* __restrict__ h2,
                                              float* __restrict__ part) {
    int c = threadIdx.x, b = blockIdx.x;
    float s = 0.f;
    for (int i = 0; i < 128; i++) s += h2[(size_t)(b * 128 + i) * CDIM + c];
    part[b * CDIM + c] = s;
}

// ---------------- channel attention MLP -> amask[192] ----------------
__global__ __launch_bounds__(192) void k_ca(const float* __restrict__ part,
                                            const float* __restrict__ ca1w,
                                            const float* __restrict__ ca1b,
                                            const float* __restrict__ ca2w,
                                            const float* __restrict__ ca2b,
                                            float* __restrict__ amask) {
    __shared__ float pooled[CDIM];
    __shared__ float hid[6];
    int c = threadIdx.x;
    float s = 0.f;
    for (int b = 0; b < 256; b++) s += part[b * CDIM + c];
    pooled[c] = s * (1.0f / 32768.0f);
    __syncthreads();
    if (c < 6) {
        float a = ca1b[c];
        for (int j = 0; j < CDIM; j++) a += ca1w[c * CDIM + j] * pooled[j];
        hid[c] = fmaxf(a, 0.f);
    }
    __syncthreads();
    float a = ca2b[c];
    for (int j = 0; j < 6; j++) a += ca2w[c * 6 + j] * hid[j];
    amask[c] = 1.0f / (1.0f + expf(-a));
}

// ---------------- qkv MFMA: 3 waves (q/k/v), 32 window-ordered tokens ----------------
__global__ __launch_bounds__(192) void k_qkvm(const __hip_bfloat16* __restrict__ xnbf,
                                              const __hip_bfloat16* __restrict__ qwb, // packed
                                              const float* __restrict__ qkvb,
                                              __hip_bfloat16* __restrict__ q,
                                              __hip_bfloat16* __restrict__ k,
                                              __hip_bfloat16* __restrict__ v) {
    __shared__ __align__(16) char xlds[32 * 384];
    __shared__ float tb[3][32][33];
    int tid = threadIdx.x;
    int wv = tid >> 6, lane = tid & 63;
    int half = lane >> 5, l31 = lane & 31;
    int t0 = blockIdx.x * 32;
    int wi = t0 >> 9;
    int wh_ = wi >> 3, ww_ = wi & 7;

    #pragma unroll
    for (int it = 0; it < 4; it++) {
        int e16 = it * 192 + tid;        // 0..767
        int tok = e16 / 24, cb = (e16 % 24) * 16;
        int n = (t0 + tok) & 511;
        int nd = n >> 6, nh = (n >> 3) & 7, nw = n & 7;
        int torig = (nd << 12) | ((wh_ * 8 + nh) << 6) | (ww_ * 8 + nw);
        short8v vdat = *(const short8v*)((const short*)xnbf + (size_t)torig * CDIM + (e16 % 24) * 8);
        *(short8v*)(xlds + tok * 384 + (cb ^ ((tok & 7) << 4))) = vdat;
    }
    __syncthreads();

    int akey = (l31 & 7) << 4;
    const char* xbase = xlds + l31 * 384;
    __hip_bfloat16* dstbase = (wv == 0) ? q : (wv == 1 ? k : v);
    float scale = (wv == 0) ? 0.17677669529663687f : 1.0f;

    for (int j = 0; j < 6; j++) {
        int ti = wv * 6 + j;
        f32x16 a0, a1;
        #pragma unroll
        for (int r = 0; r < 16; r++) { a0[r] = 0.f; a1[r] = 0.f; }
        const short* wbase = (const short*)qwb + ti * 6144 + half * 256 + l31 * 8;
        #pragma unroll
        for (int cg = 0; cg < 12; cg += 2) {
            short8v bf0 = *(const short8v*)(xbase + ((cg * 32 + half * 16) ^ akey));
            short8v bf1 = *(const short8v*)(xbase + (((cg + 1) * 32 + half * 16) ^ akey));
            short8v af0 = *(const short8v*)(wbase + cg * 512);
            short8v af1 = *(const short8v*)(wbase + (cg + 1) * 512);
            a0 = __builtin_amdgcn_mfma_f32_32x32x16_bf16(af0, bf0, a0, 0, 0, 0);
            a1 = __builtin_amdgcn_mfma_f32_32x32x16_bf16(af1, bf1, a1, 0, 0, 0);
        }
        #pragma unroll
        for (int r = 0; r < 16; r++) {
            int dl = (r & 3) + 8 * (r >> 2) + 4 * half;
            tb[wv][l31][dl] = a0[r] + a1[r];
        }
        asm volatile("s_waitcnt lgkmcnt(0)" ::: "memory");
        __builtin_amdgcn_sched_barrier(0);
        int tok = lane >> 1, d0 = (lane & 1) * 16;
        int n = (t0 + tok) & 511;
        __hip_bfloat16* dst = dstbase +
                              ((size_t)((wi * NHEAD + j) * NTOKW + n)) * HDIM + d0;
        const float* bp = qkvb + ti * 32 + d0;
        short8v o0, o1;
        #pragma unroll
        for (int i = 0; i < 8; i++)
            o0[i] = (short)bf16bits((tb[wv][tok][d0 + i] + bp[i]) * scale);
        #pragma unroll
        for (int i = 0; i < 8; i++)
            o1[i] = (short)bf16bits((tb[wv][tok][d0 + 8 + i] + bp[8 + i]) * scale);
        *(short8v*)((short*)dst) = o0;
        *(short8v*)((short*)dst + 8) = o1;
        asm volatile("s_waitcnt lgkmcnt(0)" ::: "memory");
        __builtin_amdgcn_sched_barrier(0);
    }
}

// ---------------- MFMA flash attention (bf16 output) ----------------
__global__ __launch_bounds__(256) void k_attn(const __hip_bfloat16* __restrict__ qh,
                                              const __hip_bfloat16* __restrict__ kh,
                                              const __hip_bfloat16* __restrict__ vh,
                                              const float* __restrict__ biasT,
                                              __hip_bfloat16* __restrict__ outbf) {
    __shared__ float ot[4][32][33];
    int wv = threadIdx.x >> 6, lane = threadIdx.x & 63;
    int tile = blockIdx.x * 4 + wv;
    int qt = tile & 15, wh = tile >> 4;
    int head = wh % NHEAD, wi = wh / NHEAD;
    int qb = qt * 32;
    int h = lane >> 5, ln31 = lane & 31;

    const unsigned short* qp = (const unsigned short*)qh + ((size_t)wh * NTOKW + qb + ln31) * HDIM;
    short8v qf0 = *(const short8v*)(qp + 8 * h);
    short8v qf1 = *(const short8v*)(qp + 16 + 8 * h);
    const unsigned short* kbase = (const unsigned short*)kh + (size_t)wh * NTOKW * HDIM;
    const unsigned short* vbase = (const unsigned short*)vh + (size_t)wh * NTOKW * HDIM;
    const float* bbase = biasT + (size_t)head * NTOKW * NTOKW + qb + ln31;

    f32x16 O;
    #pragma unroll
    for (int r = 0; r < 16; r++) O[r] = 0.f;
    float m = -1e30f, l = 0.f;

    for (int kb = 0; kb < NTOKW; kb += 32) {
        const unsigned short* kp = kbase + (size_t)(kb + ln31) * HDIM;
        short8v kf0 = *(const short8v*)(kp + 8 * h);
        short8v kf1 = *(const short8v*)(kp + 16 + 8 * h);
        f32x16 S;
        #pragma unroll
        for (int r = 0; r < 16; r++) S[r] = 0.f;
        S = __builtin_amdgcn_mfma_f32_32x32x16_bf16(kf0, qf0, S, 0, 0, 0);
        S = __builtin_amdgcn_mfma_f32_32x32x16_bf16(kf1, qf1, S, 0, 0, 0);

        float s[16];
        #pragma unroll
        for (int r = 0; r < 16; r++) {
            int key = (r & 3) + 8 * (r >> 2) + 4 * h;
            s[r] = S[r] + bbase[(size_t)(kb + key) * NTOKW];
        }
        float cm = s[0];
        #pragma unroll
        for (int r = 1; r < 16; r++) cm = fmaxf(cm, s[r]);
        cm = fmaxf(cm, __shfl_xor(cm, 32));
        float mn = fmaxf(m, cm);
        float scale = __expf(m - mn);
        float e[16]; float cs = 0.f;
        #pragma unroll
        for (int r = 0; r < 16; r++) { e[r] = __expf(s[r] - mn); cs += e[r]; }
        cs += __shfl_xor(cs, 32);
        l = l * scale + cs;
        m = mn;
        #pragma unroll
        for (int r = 0; r < 16; r++) O[r] *= scale;

        unsigned P[8], Qx[8];
        #pragma unroll
        for (int i = 0; i < 8; i++)
            P[i] = (unsigned)bf16bits(e[2 * i]) | ((unsigned)bf16bits(e[2 * i + 1]) << 16);
        #pragma unroll
        for (int i = 0; i < 8; i++) Qx[i] = __shfl_xor(P[i], 32);

        FragU p0, p1;
        p0.u[0] = h ? Qx[2] : P[0];  p0.u[1] = h ? Qx[3] : P[1];
        p0.u[2] = h ? P[2]  : Qx[0]; p0.u[3] = h ? P[3]  : Qx[1];
        p1.u[0] = h ? Qx[6] : P[4];  p1.u[1] = h ? Qx[7] : P[5];
        p1.u[2] = h ? P[6]  : Qx[4]; p1.u[3] = h ? P[7]  : Qx[5];

        const unsigned short* vp0 = vbase + (size_t)(kb + 8 * h) * HDIM + ln31;
        const unsigned short* vp1 = vbase + (size_t)(kb + 16 + 8 * h) * HDIM + ln31;
        short8v vf0, vf1;
        #pragma unroll
        for (int i = 0; i < 8; i++) {
            vf0[i] = (short)vp0[i * HDIM];
            vf1[i] = (short)vp1[i * HDIM];
        }
        O = __builtin_amdgcn_mfma_f32_32x32x16_bf16(vf0, p0.v, O, 0, 0, 0);
        O = __builtin_amdgcn_mfma_f32_32x32x16_bf16(vf1, p1.v, O, 0, 0, 0);
    }

    float invl = 1.0f / l;
    #pragma unroll
    for (int r = 0; r < 16; r++) {
        int d = (r & 3) + 8 * (r >> 2) + 4 * h;
        ot[wv][ln31][d] = O[r] * invl;
    }
    __syncthreads();
    int t2 = lane >> 1, c0 = (lane & 1) * 16;
    short* outp = (short*)outbf + ((size_t)(wi * NTOKW + qb + t2)) * CDIM + head * HDIM + c0;
    short8v s0, s1;
    #pragma unroll
    for (int i = 0; i < 8; i++) s0[i] = (short)bf16bits(ot[wv][t2][c0 + i]);
    #pragma unroll
    for (int i = 0; i < 8; i++) s1[i] = (short)bf16bits(ot[wv][t2][c0 + 8 + i]);
    *(short8v*)outp = s0;
    *(short8v*)(outp + 8) = s1;
}

// ---------------- proj MFMA + residual + conv merge + fused LN2 -> x2, ybf ----------------
__global__ __launch_bounds__(192) void k_projm(const __hip_bfloat16* __restrict__ attnbf,
                                               const __hip_bfloat16* __restrict__ pwb, // packed
                                               const float* __restrict__ pb,
                                               const float* __restrict__ x,
                                               const float* __restrict__ h2,
                                               const float* __restrict__ amask,
                                               const float* __restrict__ n2g,
                                               const float* __restrict__ n2b,
                                               float* __restrict__ x2,
                                               __hip_bfloat16* __restrict__ ybf) {
    __shared__ __align__(16) char alds[32 * 384];   // 12 KB
    __shared__ float xls[32][193];                  // 24.7 KB, stride-193 conflict-free
    int tid = threadIdx.x;
    int wv = tid >> 6, lane = tid & 63;
    int half = lane >> 5, l31 = lane & 31;
    int t0 = blockIdx.x * 32;
    int wi = t0 >> 9;
    int wh_ = wi >> 3, ww_ = wi & 7;

    const short* src = (const short*)attnbf + (size_t)t0 * CDIM;
    #pragma unroll
    for (int it = 0; it < 4; it++) {
        int e16 = it * 192 + tid;
        int tok = e16 / 24, cb = (e16 % 24) * 16;
        short8v vdat = *(const short8v*)(src + e16 * 8);
        *(short8v*)(alds + tok * 384 + (cb ^ ((tok & 7) << 4))) = vdat;
    }
    __syncthreads();

    int akey = (l31 & 7) << 4;
    const char* abase = alds + l31 * 384;

    for (int j = 0; j < 2; j++) {
        int ot = wv * 2 + j;
        f32x16 a0, a1;
        #pragma unroll
        for (int r = 0; r < 16; r++) { a0[r] = 0.f; a1[r] = 0.f; }
        const short* wbase = (const short*)pwb + ot * 6144 + half * 256 + l31 * 8;
        #pragma unroll
        for (int cg = 0; cg < 12; cg += 2) {
            short8v bf0 = *(const short8v*)(abase + ((cg * 32 + half * 16) ^ akey));
            short8v bf1 = *(const short8v*)(abase + (((cg + 1) * 32 + half * 16) ^ akey));
            short8v af0 = *(const short8v*)(wbase + cg * 512);
            short8v af1 = *(const short8v*)(wbase + (cg + 1) * 512);
            a0 = __builtin_amdgcn_mfma_f32_32x32x16_bf16(af0, bf0, a0, 0, 0, 0);
            a1 = __builtin_amdgcn_mfma_f32_32x32x16_bf16(af1, bf1, a1, 0, 0, 0);
        }
        #pragma unroll
        for (int r = 0; r < 16; r++) {
            int oc = (r & 3) + 8 * (r >> 2) + 4 * half;
            xls[l31][ot * 32 + oc] = a0[r] + a1[r];
        }
    }
    __syncthreads();

    // phase 2: residual merge -> x2 (global) and xls (final values for LN)
    #pragma unroll
    for (int it = 0; it < 8; it++) {
        int c4 = it * 192 + tid;            // 0..1535: 32 tok x 48 quads
        int tok = c4 / 48, cc = (c4 % 48) * 4;
        int n = (t0 + tok) & 511;
        int nd = n >> 6, nh = (n >> 3) & 7, nw = n & 7;
        int t = (nd << 12) | ((wh_ * 8 + nh) << 6) | (ww_ * 8 + nw);
        size_t idx = (size_t)t * CDIM + cc;
        float4 xv = *(const float4*)(x + idx);
        float4 hv = *(const float4*)(h2 + idx);
        float v0 = xv.x + xls[tok][cc + 0] + pb[cc + 0] + 0.01f * hv.x * amask[cc + 0];
        float v1 = xv.y + xls[tok][cc + 1] + pb[cc + 1] + 0.01f * hv.y * amask[cc + 1];
        float v2 = xv.z + xls[tok][cc + 2] + pb[cc + 2] + 0.01f * hv.z * amask[cc + 2];
        float v3 = xv.w + xls[tok][cc + 3] + pb[cc + 3] + 0.01f * hv.w * amask[cc + 3];
        float4 ov = {v0, v1, v2, v3};
        *(float4*)(x2 + idx) = ov;
        xls[tok][cc + 0] = v0; xls[tok][cc + 1] = v1;
        xls[tok][cc + 2] = v2; xls[tok][cc + 3] = v3;
    }
    __syncthreads();

    // phase 3: LN over xls rows -> ybf (bf16)
    for (int tok = wv; tok < 32; tok += 3) {
        float v0 = xls[tok][lane], v1 = xls[tok][lane + 64], v2 = xls[tok][lane + 128];
        float s = v0 + v1 + v2;
        for (int o = 32; o; o >>= 1) s += __shfl_xor(s, o);
        float mean = s * (1.0f / 192.0f);
        float d0 = v0 - mean, d1 = v1 - mean, d2 = v2 - mean;
        float vv = d0 * d0 + d1 * d1 + d2 * d2;
        for (int o = 32; o; o >>= 1) vv += __shfl_xor(vv, o);
        float inv = rsqrtf(vv * (1.0f / 192.0f) + 1e-5f);
        int n = (t0 + tok) & 511;
        int nd = n >> 6, nh = (n >> 3) & 7, nw = n & 7;
        int t = (nd << 12) | ((wh_ * 8 + nh) << 6) | (ww_ * 8 + nw);
        size_t base = (size_t)t * CDIM;
        ybf[base + lane]       = __float2bfloat16(d0 * inv * n2g[lane]       + n2b[lane]);
        ybf[base + lane + 64]  = __float2bfloat16(d1 * inv * n2g[lane + 64]  + n2b[lane + 64]);
        ybf[base + lane + 128] = __float2bfloat16(d2 * inv * n2g[lane + 128] + n2b[lane + 128]);
    }
}

// ---------------- fused MLP (MFMA): 4 waves, hc-split + LDS reduction ----------------
__global__ __launch_bounds__(256) void k_mlpm(const __hip_bfloat16* __restrict__ ybf,
                                              const __hip_bfloat16* __restrict__ w1b, // packed
                                              const float* __restrict__ b1,
                                              const __hip_bfloat16* __restrict__ w2b, // packed
                                              const float* __restrict__ b2,
                                              float* __restrict__ out) {
    __shared__ __align__(16) char ylds[32 * 384];       // 12 KB staging
    __shared__ __align__(16) float rbuf[6 * 32 * 32];   // 24 KB reduce/transpose
    int tid = threadIdx.x;
    int wv = tid >> 6, lane = tid & 63;
    int half = lane >> 5, l31 = lane & 31;
    int t0 = blockIdx.x * 32;

    const short* src = (const short*)ybf + (size_t)t0 * CDIM;
    #pragma unroll
    for (int it = 0; it < 3; it++) {
        int e16 = it * 256 + tid;      // 0..767
        int tok = e16 / 24, cb = (e16 % 24) * 16;
        short8v vdat = *(const short8v*)(src + e16 * 8);
        *(short8v*)(ylds + tok * 384 + (cb ^ ((tok & 7) << 4))) = vdat;
    }
    __syncthreads();

    int akey = (l31 & 7) << 4;
    const char* ybase = ylds + l31 * 384;

    f32x16 oacc[6];
    #pragma unroll
    for (int ot = 0; ot < 6; ot++)
        #pragma unroll
        for (int r = 0; r < 16; r++) oacc[ot][r] = 0.f;

    // each wave handles 6 of the 24 hidden chunks
    for (int j = 0; j < 6; j++) {
        int hc = wv * 6 + j;
        f32x16 h0, h1;
        #pragma unroll
        for (int r = 0; r < 16; r++) { h0[r] = 0.f; h1[r] = 0.f; }
        const short* w1base = (const short*)w1b + hc * 6144 + half * 256 + l31 * 8;
        #pragma unroll
        for (int cg = 0; cg < 12; cg += 2) {
            short8v bf0 = *(const short8v*)(ybase + ((cg * 32 + half * 16) ^ akey));
            short8v bf1 = *(const short8v*)(ybase + (((cg + 1) * 32 + half * 16) ^ akey));
            short8v af0 = *(const short8v*)(w1base + cg * 512);
            short8v af1 = *(const short8v*)(w1base + (cg + 1) * 512);
            h0 = __builtin_amdgcn_mfma_f32_32x32x16_bf16(af0, bf0, h0, 0, 0, 0);
            h1 = __builtin_amdgcn_mfma_f32_32x32x16_bf16(af1, bf1, h1, 0, 0, 0);
        }
        float e[16];
        #pragma unroll
        for (int r = 0; r < 16; r++) {
            int hid = (r & 3) + 8 * (r >> 2) + 4 * half;
            e[r] = gelu_fast(h0[r] + h1[r] + b1[hc * 32 + hid]);
        }
        unsigned P[8], Qx[8];
        #pragma unroll
        for (int i = 0; i < 8; i++)
            P[i] = (unsigned)bf16bits(e[2 * i]) | ((unsigned)bf16bits(e[2 * i + 1]) << 16);
        #pragma unroll
        for (int i = 0; i < 8; i++) Qx[i] = __shfl_xor(P[i], 32);
        FragU p0, p1;
        p0.u[0] = half ? Qx[2] : P[0];  p0.u[1] = half ? Qx[3] : P[1];
        p0.u[2] = half ? P[2]  : Qx[0]; p0.u[3] = half ? P[3]  : Qx[1];
        p1.u[0] = half ? Qx[6] : P[4];  p1.u[1] = half ? Qx[7] : P[5];
        p1.u[2] = half ? P[6]  : Qx[4]; p1.u[3] = half ? P[7]  : Qx[5];

        const short* w2base = (const short*)w2b + hc * 1024 + half * 256 + l31 * 8;
        #pragma unroll
        for (int ot = 0; ot < 6; ot++) {
            short8v a0 = *(const short8v*)(w2base + ot * 24576);
            short8v a1 = *(const short8v*)(w2base + ot * 24576 + 512);
            oacc[ot] = __builtin_amdgcn_mfma_f32_32x32x16_bf16(a0, p0.v, oacc[ot], 0, 0, 0);
            oacc[ot] = __builtin_amdgcn_mfma_f32_32x32x16_bf16(a1, p1.v, oacc[ot], 0, 0, 0);
        }
    }

    // barrier-sequenced float4 reduction into rbuf
    float4* rb4 = (float4*)rbuf;
    for (int w = 0; w < 4; w++) {
        if (wv == w) {
            #pragma unroll
            for (int ot = 0; ot < 6; ot++) {
                #pragma unroll
                for (int g = 0; g < 4; g++) {
                    float4 val = {oacc[ot][g * 4 + 0], oacc[ot][g * 4 + 1],
                                  oacc[ot][g * 4 + 2], oacc[ot][g * 4 + 3]};
                    int chunk = 2 * g + half;
                    float4* p = &rb4[(ot * 32 + l31) * 8 + (chunk ^ (l31 & 7))];
                    if (w == 0) *p = val;
                    else {
                        float4 o = *p;
                        o.x += val.x; o.y += val.y; o.z += val.z; o.w += val.w;
                        *p = o;
                    }
                }
            }
        }
        __syncthreads();
    }

    // final coalesced write: out += rbuf + b2
    #pragma unroll
    for (int i = 0; i < 6; i++) {
        int c4 = i * 256 + tid;
        int oc4 = c4 & 7;
        int tok = (c4 >> 3) & 31;
        int ot  = c4 >> 8;
        float4 vv = rb4[(ot * 32 + tok) * 8 + (oc4 ^ (tok & 7))];
        float* op = out + (size_t)(t0 + tok) * CDIM + ot * 32 + oc4 * 4;
        const float* bp = b2 + ot * 32 + oc4 * 4;
        op[0] += vv.x + bp[0];
        op[1] += vv.y + bp[1];
        op[2] += vv.z + bp[2];
        op[3] += vv.w + bp[3];
    }
}

// ---------------- launcher ----------------
extern "C" void kernel_launch(void* const* d_in, const int* in_sizes, int n_in,
                              void* d_out, int out_size, void* d_ws, size_t ws_size,
                              hipStream_t stream) {
    const float* x     = (const float*)d_in[0];
    const float* n1g   = (const float*)d_in[1];
    const float* n1b   = (const float*)d_in[2];
    const float* qkvw  = (const float*)d_in[3];
    const float* qkvb  = (const float*)d_in[4];
    const float* rpb   = (const float*)d_in[5];
    const float* projw = (const float*)d_in[6];
    const float* projb = (const float*)d_in[7];
    const float* c1w   = (const float*)d_in[8];
    const float* c1b   = (const float*)d_in[9];
    const float* c2w   = (const float*)d_in[10];
    const float* c2b   = (const float*)d_in[11];
    const float* ca1w  = (const float*)d_in[12];
    const float* ca1b  = (const float*)d_in[13];
    const float* ca2w  = (const float*)d_in[14];
    const float* ca2b  = (const float*)d_in[15];
    const float* n2g   = (const float*)d_in[16];
    const float* n2b   = (const float*)d_in[17];
    const float* fc1w  = (const float*)d_in[18];
    const float* fc1b  = (const float*)d_in[19];
    const float* fc2w  = (const float*)d_in[20];
    const float* fc2b  = (const float*)d_in[21];
    const int*   rpi   = (const int*)d_in[22];

    float* ws  = (float*)d_ws;
    float* out = (float*)d_out;

    __hip_bfloat16* attnbf = (__hip_bfloat16*)(ws + OFF_XN);
    __hip_bfloat16* qh   = (__hip_bfloat16*)(ws + OFF_QH);
    __hip_bfloat16* kb_  = (__hip_bfloat16*)(ws + OFF_KH);
    __hip_bfloat16* vb_  = (__hip_bfloat16*)(ws + OFF_VH);
    __hip_bfloat16* xnbf = (__hip_bfloat16*)(ws + OFF_Y);
    __hip_bfloat16* ybf  = (__hip_bfloat16*)(ws + OFF_YBF);
    __hip_bfloat16* h1bf = (__hip_bfloat16*)(ws + OFF_H1);
    float* h2    = ws + OFF_H2;
    float* part  = ws + OFF_PART;
    float* amask = ws + OFF_AMASK;
    float* biasT = ws + OFF_BIAST;
    __hip_bfloat16* w1p  = (__hip_bfloat16*)(ws + OFF_W1T);
    __hip_bfloat16* w2p  = (__hip_bfloat16*)(ws + OFF_W2T);
    __hip_bfloat16* qwb  = (__hip_bfloat16*)(ws + OFF_QKVT);
    __hip_bfloat16* pwb  = (__hip_bfloat16*)(ws + OFF_PROJT);
    __hip_bfloat16* w1b  = (__hip_bfloat16*)(ws + OFF_FC1T);
    __hip_bfloat16* w2b  = (__hip_bfloat16*)(ws + OFF_FC2T);

    // merged weight prep (1 dispatch) + bias table
    k_prep<<<(1105920 + 255) / 256, 256, 0, stream>>>(c1w, c2w, qkvw, projw, fc1w, fc2w,
                                                      w1p, w2p, qwb, pwb, w1b, w2b);
    k_bias<<<64, 256, 0, stream>>>(rpi, rpb, biasT);

    // LN1 (bf16 only)
    k_ln<<<LTOK / 4, 256, 0, stream>>>(x, n1g, n1b, (float*)nullptr, xnbf);
    // conv branch (MFMA)
    k_conv1m<<<512, 256, 0, stream>>>(xnbf, w1p, c1b, h1bf);
    k_conv2m<<<1024, 384, 0, stream>>>(h1bf, w2p, c2b, h2);
    k_pool<<<256, 192, 0, stream>>>(h2, part);
    k_ca<<<1, 192, 0, stream>>>(part, ca1w, ca1b, ca2w, ca2b, amask);
    // attention branch (MFMA)
    k_qkvm<<<LTOK / 32, 192, 0, stream>>>(xnbf, qwb, qkvb, qh, kb_, vb_);
    k_attn<<<(NWIN * NHEAD * 16) / 4, 256, 0, stream>>>(qh, kb_, vb_, biasT, attnbf);
    // proj + residual + conv merge + LN2 fused
    k_projm<<<LTOK / 32, 192, 0, stream>>>(attnbf, pwb, projb, x, h2, amask, n2g, n2b, out, ybf);
    // fused MFMA MLP
    k_mlpm<<<LTOK / 32, 256, 0, stream>>>(ybf, w1b, fc1b, w2b, fc2b, out);
}